// Round 14
// baseline (831.593 us; speedup 1.0000x reference)
//
#include <hip/hip_runtime.h>
#include <hip/hip_bf16.h>
#include <stdint.h>

#define B_   32768
#define JN   57
#define QSTR 256      // q row stride (228 padded to 256)

typedef _Float16 f16x8 __attribute__((ext_vector_type(8)));
typedef float    f32x4 __attribute__((ext_vector_type(4)));

__device__ __forceinline__ void split_f16(float v, _Float16& hi, _Float16& lo) {
  hi = (_Float16)v;
  lo = (_Float16)(v - (float)hi);
}

// ---------------- prep kernels ----------------
__global__ void prep_x2_kernel(const float* __restrict__ x, _Float16* __restrict__ xp) {
  long i = (long)blockIdx.x * 256 + threadIdx.x;   // over B_*192
  int row = (int)(i / 192), col = (int)(i % 192);
  float v = (col < 171) ? x[(long)row * 171 + col] : 0.f;
  _Float16 hi, lo; split_f16(v, hi, lo);
  xp[(long)row * 384 + col]       = hi;
  xp[(long)row * 384 + 192 + col] = lo;
}

__global__ void prep_w2_kernel(const float* __restrict__ w, _Float16* __restrict__ wf,
                               int Ksrc, int Kpad, int Nsrc) {
  long i = (long)blockIdx.x * 256 + threadIdx.x;   // over Ndst*Kpad
  int n = (int)(i / Kpad), k = (int)(i % Kpad);
  float v = (k < Ksrc && n < Nsrc) ? w[(long)k * Nsrc + n] : 0.f;
  _Float16 hi, lo; split_f16(v, hi, lo);
  wf[(long)n * (2 * Kpad) + k]        = hi;
  wf[(long)n * (2 * Kpad) + Kpad + k] = lo;
}

__global__ void prep_b4_kernel(const float* __restrict__ b, float* __restrict__ bp) {
  int i = threadIdx.x;  // 256 threads
  bp[i] = (i < 228) ? b[i] : 0.f;
}

// ---------------- 128² split-f16 GEMM (m97 structure) — layers 1 and 4 ----------------
template<int EPI>
__global__ __launch_bounds__(256)
void gemm_hl(const _Float16* __restrict__ A, const _Float16* __restrict__ Bt,
             const float* __restrict__ bias, void* __restrict__ Cout,
             int M, int N, int Kp)
{
  __shared__ __align__(16) _Float16 As[128 * 64];
  __shared__ __align__(16) _Float16 Bs[128 * 64];
  const int lda = 2 * Kp;
  const int T = Kp >> 6;
  const int tiles_n = N >> 7;
  const int cpx  = gridDim.x >> 3;
  const int virt = (blockIdx.x & 7) * cpx + (blockIdx.x >> 3);
  const int bm = virt / tiles_n;
  const int bn = virt % tiles_n;
  const int tid  = threadIdx.x;
  const int wave = tid >> 6;
  const int lane = tid & 63;

  const int srow = wave * 8 + (lane >> 3);
  const int scol = (((lane & 7) ^ (lane >> 3)) * 8);
  const long abase = (long)bm * 128;
  const long bbase = (long)bn * 128;

  f32x4 acc[4][4] = {};

  const int wm = (wave >> 1) * 64;
  const int wn = (wave & 1) * 64;
  const int lr = lane & 15;
  const int ch0 = (((lane >> 4) ^ (lane & 7)) * 8);
  const int ch1 = (((4 + (lane >> 4)) ^ (lane & 7)) * 8);

  for (int ph = 0; ph < 3; ++ph) {
    const int aoff = (ph == 2) ? Kp : 0;
    const int boff = (ph == 1) ? Kp : 0;
    for (int u = 0; u < T; ++u) {
#pragma unroll
      for (int i = 0; i < 4; i++) {
        const _Float16* asrc = A  + (abase + i * 32 + srow) * (long)lda + (aoff + u * 64 + scol);
        const _Float16* bsrc = Bt + (bbase + i * 32 + srow) * (long)lda + (boff + u * 64 + scol);
        __builtin_amdgcn_global_load_lds(
            (const __attribute__((address_space(1))) void*)asrc,
            (__attribute__((address_space(3))) void*)(As + (i * 256 + wave * 64) * 8),
            16, 0, 0);
        __builtin_amdgcn_global_load_lds(
            (const __attribute__((address_space(1))) void*)bsrc,
            (__attribute__((address_space(3))) void*)(Bs + (i * 256 + wave * 64) * 8),
            16, 0, 0);
      }
      __syncthreads();

#pragma unroll
      for (int ks = 0; ks < 2; ks++) {
        const int ch = ks ? ch1 : ch0;
        f16x8 af[4], bfr[4];
#pragma unroll
        for (int m = 0; m < 4; m++)
          af[m] = *(const f16x8*)(As + (wm + m * 16 + lr) * 64 + ch);
#pragma unroll
        for (int n = 0; n < 4; n++)
          bfr[n] = *(const f16x8*)(Bs + (wn + n * 16 + lr) * 64 + ch);
#pragma unroll
        for (int m = 0; m < 4; m++)
#pragma unroll
          for (int n = 0; n < 4; n++)
            acc[m][n] = __builtin_amdgcn_mfma_f32_16x16x32_f16(af[m], bfr[n], acc[m][n], 0, 0, 0);
      }
      __syncthreads();
    }
  }

  const int crow0 = bm * 128 + wm + (lane >> 4) * 4;
  const int ccol0 = bn * 128 + wn + lr;
#pragma unroll
  for (int n = 0; n < 4; n++) {
    const int col = ccol0 + n * 16;
    const float bv = bias[col];
#pragma unroll
    for (int m = 0; m < 4; m++) {
#pragma unroll
      for (int r = 0; r < 4; r++) {
        float v = acc[m][n][r] + bv;
        const long row = crow0 + m * 16 + r;
        if (EPI == 0) {
          v = (v >= 0.f) ? v : 0.01f * v;
          _Float16 hi, lo; split_f16(v, hi, lo);
          _Float16* C = (_Float16*)Cout;
          C[row * (long)(2 * N) + col]     = hi;
          C[row * (long)(2 * N) + N + col] = lo;
        } else {
          ((float*)Cout)[row * (long)N + col] = v;
        }
      }
    }
  }
}

// ---------------- 128² 4-phase split-f16 GEMM — R9 discipline + 2 blocks/CU ----------------
// The untested cell of the {prefetch-discipline x co-residency} matrix:
//  - gemm_hl: co-resident (64KB) but vmcnt(0)-drain per K-step  -> 311us
//  - gemm256: R9 prefetch ledger but 128KB LDS -> 1 block/CU convoy -> 250us
// This kernel: 256 thr = 4 waves (2x2), per-wave 64x64 out (acc[4][4]=64 regs,
// fits the 256-reg budget easily), BK=64, 2 LDS slots = 64KB -> 2 blocks/CU.
// The co-resident block's MFMA covers this block's vmcnt/barrier/ds-latency.
// Per K-tile, 2 phases (R9 vmcnt ledger, 4 loads/thread per tile):
//  Q1: stage bA(4) [out 12] ; vmcnt(4) [a landed] ; bar ; reads ks0 ; 16 MFMA
//  Q2: stage bB(4) [out  8] ;                       bar ; reads ks1 ; 16 MFMA
template<int EPI>
__global__ __launch_bounds__(256, 2)
void gemm128p(const _Float16* __restrict__ Ag, const _Float16* __restrict__ Bt,
              const float* __restrict__ bias, void* __restrict__ Cout,
              int M, int N, int Kp)
{
  __shared__ __align__(16) _Float16 As[2][128 * 64];
  __shared__ __align__(16) _Float16 Bs[2][128 * 64];
  const int lda = 2 * Kp;
  const int T  = Kp >> 6;
  const int NT = 3 * T;
  const int NI = NT >> 1;
  const int tiles_n = N >> 7;
  const int cpx  = gridDim.x >> 3;
  const int virt = (blockIdx.x & 7) * cpx + (blockIdx.x >> 3);
  const int bm = virt / tiles_n;
  const int bn = virt % tiles_n;
  const int tid  = threadIdx.x;
  const int wave = tid >> 6;
  const int lane = tid & 63;

  const long abase = (long)bm * 128;
  const long bbase = (long)bn * 128;
  // staging: 4 instrs/operand/tile; instr L covers idx=tid+L*256 in 0..1023:
  // row = idx>>3, chunk = idx&7, source col pre-swizzled by row&7; dst linear.
  const int wm = (wave >> 1) * 64;
  const int wn = (wave & 1) * 64;
  const int lr = lane & 15;

  f32x4 acc[4][4] = {};

  auto stageA = [&](int t, int s) {
    const int ph = t / T, u = t - ph * T;
    const long ko = ((ph == 2) ? (long)Kp : 0) + u * 64;
#pragma unroll
    for (int L = 0; L < 4; ++L) {
      const int idx = tid + L * 256;
      const int row = idx >> 3, ck = idx & 7;
      const _Float16* src = Ag + (abase + row) * (long)lda + ko + (ck ^ (row & 7)) * 8;
      __builtin_amdgcn_global_load_lds(
          (const __attribute__((address_space(1))) void*)src,
          (__attribute__((address_space(3))) void*)&As[s][idx * 8], 16, 0, 0);
    }
  };
  auto stageB = [&](int t, int s) {
    const int ph = t / T, u = t - ph * T;
    const long ko = ((ph == 1) ? (long)Kp : 0) + u * 64;
#pragma unroll
    for (int L = 0; L < 4; ++L) {
      const int idx = tid + L * 256;
      const int row = idx >> 3, ck = idx & 7;
      const _Float16* src = Bt + (bbase + row) * (long)lda + ko + (ck ^ (row & 7)) * 8;
      __builtin_amdgcn_global_load_lds(
          (const __attribute__((address_space(1))) void*)src,
          (__attribute__((address_space(3))) void*)&Bs[s][idx * 8], 16, 0, 0);
    }
  };

  // phase: stage(4) -> [vmcnt(4)] -> barrier -> 8 ds_reads -> 16 MFMA
#define PH(slot, ks, WAITV, ...)                                                  \
  do {                                                                            \
    __VA_ARGS__;                                                                  \
    if (WAITV) asm volatile("s_waitcnt vmcnt(4)" ::: "memory");                   \
    __builtin_amdgcn_s_barrier();                                                 \
    const int ch = (((ks) * 4 + (lane >> 4)) ^ (lane & 7)) * 8;                   \
    f16x8 af[4], bfr[4];                                                          \
    _Pragma("unroll")                                                             \
    for (int mi = 0; mi < 4; ++mi)                                                \
      af[mi] = *(const f16x8*)&As[slot][(wm + mi * 16 + lr) * 64 + ch];           \
    _Pragma("unroll")                                                             \
    for (int n = 0; n < 4; ++n)                                                   \
      bfr[n] = *(const f16x8*)&Bs[slot][(wn + n * 16 + lr) * 64 + ch];            \
    __builtin_amdgcn_s_setprio(1);                                                \
    _Pragma("unroll")                                                             \
    for (int mi = 0; mi < 4; ++mi)                                                \
      _Pragma("unroll")                                                           \
      for (int n = 0; n < 4; ++n)                                                 \
        acc[mi][n] = __builtin_amdgcn_mfma_f32_16x16x32_f16(                      \
            af[mi], bfr[n], acc[mi][n], 0, 0, 0);                                 \
    __builtin_amdgcn_s_setprio(0);                                                \
  } while (0)

  // prologue: tile 0 -> S0 (8 loads/thread outstanding)
  stageA(0, 0); stageB(0, 0);

  for (int i = 0; i < NI; ++i) {
    const int b = 2 * i + 1;
    const int c = (2 * i + 2 < NT) ? 2 * i + 2 : 0;   // tail: harmless re-stage
    PH(0, 0, 1, stageA(b, 1));
    PH(0, 1, 0, stageB(b, 1));
    PH(1, 0, 1, stageA(c, 0));
    PH(1, 1, 0, stageB(c, 0));
  }
  asm volatile("s_waitcnt vmcnt(0)" ::: "memory");

#undef PH

  // epilogue: C/D layout col=lane&15, row=(lane>>4)*4+reg
  const int crow0 = bm * 128 + wm + (lane >> 4) * 4;
  const int ccol0 = bn * 128 + wn + lr;
#pragma unroll
  for (int n = 0; n < 4; n++) {
    const int col = ccol0 + n * 16;
    const float bv = bias[col];
#pragma unroll
    for (int m = 0; m < 4; m++) {
#pragma unroll
      for (int r = 0; r < 4; r++) {
        float v = acc[m][n][r] + bv;
        const long row = crow0 + m * 16 + r;
        if (EPI == 0) {
          v = (v >= 0.f) ? v : 0.01f * v;
          _Float16 hi, lo; split_f16(v, hi, lo);
          _Float16* C = (_Float16*)Cout;
          C[row * (long)(2 * N) + col]     = hi;
          C[row * (long)(2 * N) + N + col] = lo;
        } else {
          ((float*)Cout)[row * (long)N + col] = v;
        }
      }
    }
  }
}

// ---------------- quat -> rotmat, write rot (d_out) + Lf (ws, f32) ----------------
__global__ void quat_rot_kernel(const float* __restrict__ q, const float* __restrict__ offs,
                                float* __restrict__ rot, float* __restrict__ Lf)
{
  const int s = blockIdx.x * 256 + threadIdx.x;
  const int j = blockIdx.y;
  const float* qp = q + (long)s * QSTR + j * 4;
  float qw = qp[0], qx = qp[1], qy = qp[2], qz = qp[3];
  float n = sqrtf(qw * qw + qx * qx + qy * qy + qz * qz);
  n = fmaxf(n, 1e-8f);
  float inv = 1.f / n;
  qw *= inv; qx *= inv; qy *= inv; qz *= inv;
  const float xx = qx * qx, yy = qy * qy, zz = qz * qz;
  const float xy = qx * qy, xz = qx * qz, yz = qy * qz;
  const float xw = qx * qw, yw = qy * qw, zw = qz * qw;
  const float r00 = 1.f - 2.f * (yy + zz), r01 = 2.f * (xy - zw), r02 = 2.f * (xz + yw);
  const float r10 = 2.f * (xy + zw), r11 = 1.f - 2.f * (xx + zz), r12 = 2.f * (yz - xw);
  const float r20 = 2.f * (xz - yw), r21 = 2.f * (yz + xw), r22 = 1.f - 2.f * (xx + yy);

  float4* ro = (float4*)(rot + ((long)s * JN + j) * 16);
  ro[0] = make_float4(r00, r01, r02, 0.f);
  ro[1] = make_float4(r10, r11, r12, 0.f);
  ro[2] = make_float4(r20, r21, r22, 0.f);
  ro[3] = make_float4(0.f, 0.f, 0.f, 1.f);

  const float tx = offs[j * 3 + 0], ty = offs[j * 3 + 1], tz = offs[j * 3 + 2];
  float* L = Lf + (long)j * 12 * B_ + s;
  L[0L * B_]  = r00; L[1L * B_]  = r01; L[2L * B_]  = r02; L[3L * B_]  = tx;
  L[4L * B_]  = r10; L[5L * B_]  = r11; L[6L * B_]  = r12; L[7L * B_]  = ty;
  L[8L * B_]  = r20; L[9L * B_]  = r21; L[10L * B_] = r22; L[11L * B_] = tz;
}

// ---------------- forward kinematics (all fp32) ----------------
struct FkParams { int par[JN]; unsigned long long childmask; };

__global__ void fk_kernel(const float* __restrict__ Lf, float* __restrict__ Gt,
                          float* __restrict__ pose, FkParams P)
{
  const int s = blockIdx.x * 256 + threadIdx.x;
  float G[12];
#pragma unroll
  for (int e = 0; e < 12; e++) G[e] = Lf[(long)e * B_ + s];
  if (P.childmask & 1ull) {
#pragma unroll
    for (int e = 0; e < 12; e++) Gt[(long)e * B_ + s] = G[e];
  }
  pose[(long)s * (JN * 3) + 0] = G[3];
  pose[(long)s * (JN * 3) + 1] = G[7];
  pose[(long)s * (JN * 3) + 2] = G[11];

  for (int j = 1; j < JN; j++) {
    const int p = P.par[j];
    float Pm[12];
    if (p == j - 1) {
#pragma unroll
      for (int e = 0; e < 12; e++) Pm[e] = G[e];
    } else {
#pragma unroll
      for (int e = 0; e < 12; e++) Pm[e] = Gt[((long)p * 12 + e) * B_ + s];
    }
    float L[12];
#pragma unroll
    for (int e = 0; e < 12; e++) L[e] = Lf[((long)j * 12 + e) * B_ + s];
#pragma unroll
    for (int r = 0; r < 3; r++) {
#pragma unroll
      for (int c = 0; c < 4; c++) {
        float v = Pm[r * 4 + 0] * L[0 * 4 + c] + Pm[r * 4 + 1] * L[1 * 4 + c]
                + Pm[r * 4 + 2] * L[2 * 4 + c];
        if (c == 3) v += Pm[r * 4 + 3];
        G[r * 4 + c] = v;
      }
    }
    if ((P.childmask >> j) & 1ull) {
#pragma unroll
      for (int e = 0; e < 12; e++) Gt[((long)j * 12 + e) * B_ + s] = G[e];
    }
    pose[(long)s * (JN * 3) + j * 3 + 0] = G[3];
    pose[(long)s * (JN * 3) + j * 3 + 1] = G[7];
    pose[(long)s * (JN * 3) + j * 3 + 2] = G[11];
  }
}

// ---------------- host: replicate np.random.default_rng(7) parents ----------------
static void compute_parents(int* par, unsigned long long* childmask)
{
  uint32_t pool[4];
  uint32_t hc = 0x43b0d7e5u;                       // INIT_A
  auto hashmix = [&hc](uint32_t v) {
    v ^= hc; hc *= 0x931e8875u; v *= hc; v ^= v >> 16; return v;
  };
  auto mix = [](uint32_t x, uint32_t y) {
    uint32_t r = 0xca01f9ddu * x - 0x4973f715u * y;
    r ^= r >> 16;
    return r;
  };
  const uint32_t entropy[1] = {7u};
  for (int i = 0; i < 4; i++) pool[i] = hashmix(i < 1 ? entropy[i] : 0u);
  for (int si = 0; si < 4; si++)
    for (int di = 0; di < 4; di++)
      if (si != di) pool[di] = mix(pool[di], hashmix(pool[si]));
  uint32_t gs[8];
  uint32_t hb = 0x8b51f9ddu;                       // INIT_B
  for (int i = 0; i < 8; i++) {
    uint32_t dv = pool[i & 3];
    dv ^= hb; hb *= 0x58f38dedu; dv *= hb; dv ^= dv >> 16;
    gs[i] = dv;
  }
  uint64_t sw0 = (uint64_t)gs[0] | ((uint64_t)gs[1] << 32);
  uint64_t sw1 = (uint64_t)gs[2] | ((uint64_t)gs[3] << 32);
  uint64_t iw0 = (uint64_t)gs[4] | ((uint64_t)gs[5] << 32);
  uint64_t iw1 = (uint64_t)gs[6] | ((uint64_t)gs[7] << 32);
  const __uint128_t MULT = (((__uint128_t)0x2360ed051fc65da4ULL) << 64) | 0x4385df649fccf645ULL;
  __uint128_t inc = ((((__uint128_t)iw0 << 64) | iw1) << 1) | 1;
  __uint128_t state = 0;
  state = state * MULT + inc;
  state += (((__uint128_t)sw0) << 64) | sw1;
  state = state * MULT + inc;
  bool has32 = false; uint32_t buf32 = 0;
  auto next64 = [&]() {
    state = state * MULT + inc;
    uint64_t hi = (uint64_t)(state >> 64), lo = (uint64_t)state;
    uint32_t rot = (uint32_t)(state >> 122);
    uint64_t x = hi ^ lo;
    return (x >> rot) | (x << ((64u - rot) & 63u));
  };
  auto next32 = [&]() -> uint32_t {
    if (has32) { has32 = false; return buf32; }
    uint64_t v = next64();
    has32 = true; buf32 = (uint32_t)(v >> 32);
    return (uint32_t)v;
  };
  par[0] = -1;
  for (int j = 1; j < JN; j++) {
    uint32_t rng = (uint32_t)(j - 1);
    if (rng == 0) { par[j] = 0; continue; }
    uint32_t rng_excl = rng + 1;
    uint64_t m = (uint64_t)next32() * (uint64_t)rng_excl;
    uint32_t leftover = (uint32_t)m;
    if (leftover < rng_excl) {
      uint32_t threshold = (uint32_t)((0x100000000ULL - rng_excl) % rng_excl);
      while (leftover < threshold) {
        m = (uint64_t)next32() * (uint64_t)rng_excl;
        leftover = (uint32_t)m;
      }
    }
    par[j] = (int)(m >> 32);
  }
  unsigned long long cm = 0;
  for (int j = 1; j < JN; j++) cm |= 1ull << par[j];
  *childmask = cm;
}

// ---------------- launch ----------------
extern "C" void kernel_launch(void* const* d_in, const int* in_sizes, int n_in,
                              void* d_out, int out_size, void* d_ws, size_t ws_size,
                              hipStream_t stream)
{
  const float* in_seq = (const float*)d_in[0];
  const float* w1 = (const float*)d_in[1];
  const float* b1 = (const float*)d_in[2];
  const float* w2 = (const float*)d_in[3];
  const float* b2 = (const float*)d_in[4];
  const float* w3 = (const float*)d_in[5];
  const float* b3 = (const float*)d_in[6];
  const float* w4 = (const float*)d_in[7];
  const float* b4 = (const float*)d_in[8];
  const float* offs = (const float*)d_in[9];

  char* pR1 = (char*)d_ws;
  char* pR2 = pR1 + 35390464;
  char* pR3 = pR2 + 134217728;
  _Float16* x2  = (_Float16*)pR1;
  _Float16* w1f = (_Float16*)(pR1 + 25165824);
  _Float16* w2f = (_Float16*)(pR1 + 25165824 + 786432);
  _Float16* w3f = (_Float16*)(pR1 + 25165824 + 786432 + 4194304);
  _Float16* w4f = (_Float16*)(pR1 + 25165824 + 786432 + 2 * 4194304);
  float*    b4p = (float*)(pR1 + 25165824 + 786432 + 2 * 4194304 + 1048576);
  float*    q   = (float*)pR1;            // overwrites x2/w1f/w2f/w3f only
  _Float16* h1  = (_Float16*)pR2;
  _Float16* h3  = (_Float16*)pR2;
  float*    Gt  = (float*)pR2;
  _Float16* h2  = (_Float16*)pR3;
  float*    Lf  = (float*)pR3;

  float* pose = (float*)d_out;                        // [B_,57,3]
  float* rot  = (float*)d_out + (long)B_ * JN * 3;    // [B_,57,4,4]

  // prep
  prep_x2_kernel<<<(B_ * 192) / 256, 256, 0, stream>>>(in_seq, x2);
  prep_w2_kernel<<<(1024 * 192) / 256, 256, 0, stream>>>(w1, w1f, 171, 192, 1024);
  prep_w2_kernel<<<(1024 * 1024) / 256, 256, 0, stream>>>(w2, w2f, 1024, 1024, 1024);
  prep_w2_kernel<<<(1024 * 1024) / 256, 256, 0, stream>>>(w3, w3f, 1024, 1024, 1024);
  prep_w2_kernel<<<(256 * 1024) / 256, 256, 0, stream>>>(w4, w4f, 1024, 1024, 228);
  prep_b4_kernel<<<1, 256, 0, stream>>>(b4, b4p);

  // MLP (split-f16, virtual 3K)
  gemm_hl<0><<<(B_ / 128) * (1024 / 128), 256, 0, stream>>>(x2, w1f, b1, h1, B_, 1024, 192);
  gemm128p<0><<<(B_ / 128) * (1024 / 128), 256, 0, stream>>>(h1, w2f, b2, h2, B_, 1024, 1024);
  gemm128p<0><<<(B_ / 128) * (1024 / 128), 256, 0, stream>>>(h2, w3f, b3, h3, B_, 1024, 1024);
  gemm_hl<1><<<(B_ / 128) * (QSTR / 128), 256, 0, stream>>>(h3, w4f, b4p, q, B_, QSTR, 1024);

  // epilogue
  quat_rot_kernel<<<dim3(B_ / 256, JN), 256, 0, stream>>>(q, offs, rot, Lf);

  FkParams P;
  compute_parents(P.par, &P.childmask);
  fk_kernel<<<B_ / 256, 256, 0, stream>>>(Lf, Gt, pose, P);
}

// Round 15
// 775.155 us; speedup vs baseline: 1.0728x; 1.0728x over previous
//
#include <hip/hip_runtime.h>
#include <hip/hip_bf16.h>
#include <stdint.h>

#define B_   32768
#define JN   57
#define QSTR 256      // q row stride (228 padded to 256)

typedef _Float16 f16x8 __attribute__((ext_vector_type(8)));
typedef float    f32x4 __attribute__((ext_vector_type(4)));

__device__ __forceinline__ void split_f16(float v, _Float16& hi, _Float16& lo) {
  hi = (_Float16)v;
  lo = (_Float16)(v - (float)hi);
}

// ---------------- prep kernels ----------------
__global__ void prep_x2_kernel(const float* __restrict__ x, _Float16* __restrict__ xp) {
  long i = (long)blockIdx.x * 256 + threadIdx.x;   // over B_*192
  int row = (int)(i / 192), col = (int)(i % 192);
  float v = (col < 171) ? x[(long)row * 171 + col] : 0.f;
  _Float16 hi, lo; split_f16(v, hi, lo);
  xp[(long)row * 384 + col]       = hi;
  xp[(long)row * 384 + 192 + col] = lo;
}

__global__ void prep_w2_kernel(const float* __restrict__ w, _Float16* __restrict__ wf,
                               int Ksrc, int Kpad, int Nsrc) {
  long i = (long)blockIdx.x * 256 + threadIdx.x;   // over Ndst*Kpad
  int n = (int)(i / Kpad), k = (int)(i % Kpad);
  float v = (k < Ksrc && n < Nsrc) ? w[(long)k * Nsrc + n] : 0.f;
  _Float16 hi, lo; split_f16(v, hi, lo);
  wf[(long)n * (2 * Kpad) + k]        = hi;
  wf[(long)n * (2 * Kpad) + Kpad + k] = lo;
}

__global__ void prep_b4_kernel(const float* __restrict__ b, float* __restrict__ bp) {
  int i = threadIdx.x;  // 256 threads
  bp[i] = (i < 228) ? b[i] : 0.f;
}

// ---------------- 128² split-f16 GEMM (m97 structure) — layer 1 only ----------------
template<int EPI>
__global__ __launch_bounds__(256)
void gemm_hl(const _Float16* __restrict__ A, const _Float16* __restrict__ Bt,
             const float* __restrict__ bias, void* __restrict__ Cout,
             int M, int N, int Kp)
{
  __shared__ __align__(16) _Float16 As[128 * 64];
  __shared__ __align__(16) _Float16 Bs[128 * 64];
  const int lda = 2 * Kp;
  const int T = Kp >> 6;
  const int tiles_n = N >> 7;
  const int cpx  = gridDim.x >> 3;
  const int virt = (blockIdx.x & 7) * cpx + (blockIdx.x >> 3);
  const int bm = virt / tiles_n;
  const int bn = virt % tiles_n;
  const int tid  = threadIdx.x;
  const int wave = tid >> 6;
  const int lane = tid & 63;

  const int srow = wave * 8 + (lane >> 3);
  const int scol = (((lane & 7) ^ (lane >> 3)) * 8);
  const long abase = (long)bm * 128;
  const long bbase = (long)bn * 128;

  f32x4 acc[4][4] = {};

  const int wm = (wave >> 1) * 64;
  const int wn = (wave & 1) * 64;
  const int lr = lane & 15;
  const int ch0 = (((lane >> 4) ^ (lane & 7)) * 8);
  const int ch1 = (((4 + (lane >> 4)) ^ (lane & 7)) * 8);

  for (int ph = 0; ph < 3; ++ph) {
    const int aoff = (ph == 2) ? Kp : 0;
    const int boff = (ph == 1) ? Kp : 0;
    for (int u = 0; u < T; ++u) {
#pragma unroll
      for (int i = 0; i < 4; i++) {
        const _Float16* asrc = A  + (abase + i * 32 + srow) * (long)lda + (aoff + u * 64 + scol);
        const _Float16* bsrc = Bt + (bbase + i * 32 + srow) * (long)lda + (boff + u * 64 + scol);
        __builtin_amdgcn_global_load_lds(
            (const __attribute__((address_space(1))) void*)asrc,
            (__attribute__((address_space(3))) void*)(As + (i * 256 + wave * 64) * 8),
            16, 0, 0);
        __builtin_amdgcn_global_load_lds(
            (const __attribute__((address_space(1))) void*)bsrc,
            (__attribute__((address_space(3))) void*)(Bs + (i * 256 + wave * 64) * 8),
            16, 0, 0);
      }
      __syncthreads();

#pragma unroll
      for (int ks = 0; ks < 2; ks++) {
        const int ch = ks ? ch1 : ch0;
        f16x8 af[4], bfr[4];
#pragma unroll
        for (int m = 0; m < 4; m++)
          af[m] = *(const f16x8*)(As + (wm + m * 16 + lr) * 64 + ch);
#pragma unroll
        for (int n = 0; n < 4; n++)
          bfr[n] = *(const f16x8*)(Bs + (wn + n * 16 + lr) * 64 + ch);
#pragma unroll
        for (int m = 0; m < 4; m++)
#pragma unroll
          for (int n = 0; n < 4; n++)
            acc[m][n] = __builtin_amdgcn_mfma_f32_16x16x32_f16(af[m], bfr[n], acc[m][n], 0, 0, 0);
      }
      __syncthreads();
    }
  }

  const int crow0 = bm * 128 + wm + (lane >> 4) * 4;
  const int ccol0 = bn * 128 + wn + lr;
#pragma unroll
  for (int n = 0; n < 4; n++) {
    const int col = ccol0 + n * 16;
    const float bv = bias[col];
#pragma unroll
    for (int m = 0; m < 4; m++) {
#pragma unroll
      for (int r = 0; r < 4; r++) {
        float v = acc[m][n][r] + bv;
        const long row = crow0 + m * 16 + r;
        if (EPI == 0) {
          v = (v >= 0.f) ? v : 0.01f * v;
          _Float16 hi, lo; split_f16(v, hi, lo);
          _Float16* C = (_Float16*)Cout;
          C[row * (long)(2 * N) + col]     = hi;
          C[row * (long)(2 * N) + N + col] = lo;
        } else {
          ((float*)Cout)[row * (long)N + col] = v;
        }
      }
    }
  }
}

// ---------------- 256² 4-phase split-f16 GEMM — B-dedup schedule (best measured) ----------------
// 512 thr = 8 waves (2M x 4N), per-wave 128x64 out. BK=64, 2 LDS slots (128KB).
// acc[8][4] f32x4 = 128 AGPRs/lane -> REQUIRES the 256-reg budget of
// __launch_bounds__(512,2); min-waves=4 forces a 128-reg cap and spills the
// accumulator to scratch (R11: 10x regression). Do not raise.
// Structure-space exploration (R7-R14): drain(311us), 8ph-m201(298),
// 8ph-deep-prefetch(268), THIS(249), 128²-2blk/CU(277), BK32-4blk(spill).
// All neighbors regress — local optimum at 249us/dispatch, MfmaUtil 36%.
// Sync ledger (per wave, in-order vmcnt): prologue issues a(8).
//  Q1: stage bA(4) [out 12] ; vmcnt(4) [a landed] ; bar ; reads S0 ks0 ; MFMA
//  Q2: stage bB(4) [out  8] ;                       bar ; reads S0 ks1 ; MFMA
//  Q3: stage cA(4) [out 12] ; vmcnt(4) [b landed] ; bar ; reads S1 ks0 ; MFMA
//  Q4: stage cB(4) [out  8] ;                       bar ; reads S1 ks1 ; MFMA
template<int EPI>
__global__ __launch_bounds__(512, 2)
void gemm256(const _Float16* __restrict__ Ag, const _Float16* __restrict__ Bt,
             const float* __restrict__ bias, void* __restrict__ Cout,
             int M, int N, int Kp)
{
  __shared__ __align__(16) _Float16 As[2][256 * 64];
  __shared__ __align__(16) _Float16 Bs[2][256 * 64];
  const int lda = 2 * Kp;
  const int T  = Kp >> 6;
  const int NT = 3 * T;
  const int NI = NT >> 1;
  const int tiles_n = N >> 8;
  const int cpx  = gridDim.x >> 3;
  const int virt = (blockIdx.x & 7) * cpx + (blockIdx.x >> 3);
  const int bm = virt / tiles_n;
  const int bn = virt % tiles_n;
  const int tid  = threadIdx.x;
  const int wid  = tid >> 6;
  const int lane = tid & 63;

  const long abase = (long)bm * 256;
  const long bbase = (long)bn * 256;
  const int scol = (((lane & 7) ^ ((tid >> 3) & 7)) * 8);

  const int wm = (wid >> 2) * 128;
  const int wn = (wid & 3) * 64;
  const int lr = lane & 15;

  f32x4 acc[8][4] = {};

  auto stageA = [&](int t, int s, int h) {
    const int ph = t / T, u = t - ph * T;
    const long ko = ((ph == 2) ? (long)Kp : 0) + u * 64 + scol;
    const _Float16* src = Ag + (abase + h * 128 + (tid >> 3)) * (long)lda + ko;
    const _Float16* dst = &As[s][h * 8192 + tid * 8];
    __builtin_amdgcn_global_load_lds(
        (const __attribute__((address_space(1))) void*)src,
        (__attribute__((address_space(3))) void*)dst, 16, 0, 0);
    __builtin_amdgcn_global_load_lds(
        (const __attribute__((address_space(1))) void*)(src + 64 * (long)lda),
        (__attribute__((address_space(3))) void*)(dst + 4096), 16, 0, 0);
  };
  auto stageB = [&](int t, int s, int h) {
    const int ph = t / T, u = t - ph * T;
    const long ko = ((ph == 1) ? (long)Kp : 0) + u * 64 + scol;
    const _Float16* src = Bt + (bbase + h * 128 + (tid >> 3)) * (long)lda + ko;
    const _Float16* dst = &Bs[s][h * 8192 + tid * 8];
    __builtin_amdgcn_global_load_lds(
        (const __attribute__((address_space(1))) void*)src,
        (__attribute__((address_space(3))) void*)dst, 16, 0, 0);
    __builtin_amdgcn_global_load_lds(
        (const __attribute__((address_space(1))) void*)(src + 64 * (long)lda),
        (__attribute__((address_space(3))) void*)(dst + 4096), 16, 0, 0);
  };

  // phase: stage -> [vmcnt(4)] -> barrier -> 12 ds_reads -> 32 MFMA
#define PH(slot, ks, WAITV, ...)                                                  \
  do {                                                                            \
    __VA_ARGS__;                                                                  \
    if (WAITV) asm volatile("s_waitcnt vmcnt(4)" ::: "memory");                   \
    __builtin_amdgcn_s_barrier();                                                 \
    const int ch = (((ks) * 4 + (lane >> 4)) ^ (lane & 7)) * 8;                   \
    f16x8 af[8], bfr[4];                                                          \
    _Pragma("unroll")                                                             \
    for (int mi = 0; mi < 8; ++mi)                                                \
      af[mi] = *(const f16x8*)&As[slot][(wm + mi * 16 + lr) * 64 + ch];           \
    _Pragma("unroll")                                                             \
    for (int n = 0; n < 4; ++n)                                                   \
      bfr[n] = *(const f16x8*)&Bs[slot][(wn + n * 16 + lr) * 64 + ch];            \
    __builtin_amdgcn_s_setprio(1);                                                \
    _Pragma("unroll")                                                             \
    for (int mi = 0; mi < 8; ++mi)                                                \
      _Pragma("unroll")                                                           \
      for (int n = 0; n < 4; ++n)                                                 \
        acc[mi][n] = __builtin_amdgcn_mfma_f32_16x16x32_f16(                      \
            af[mi], bfr[n], acc[mi][n], 0, 0, 0);                                 \
    __builtin_amdgcn_s_setprio(0);                                                \
  } while (0)

  // prologue: full tile 0 -> S0 (8 loads/thread outstanding)
  stageA(0, 0, 0); stageA(0, 0, 1); stageB(0, 0, 0); stageB(0, 0, 1);

  for (int i = 0; i < NI; ++i) {
    const int b = 2 * i + 1;
    const int c = (2 * i + 2 < NT) ? 2 * i + 2 : 0;   // tail: harmless re-stage
    PH(0, 0, 1, stageA(b, 1, 0); stageA(b, 1, 1));
    PH(0, 1, 0, stageB(b, 1, 0); stageB(b, 1, 1));
    PH(1, 0, 1, stageA(c, 0, 0); stageA(c, 0, 1));
    PH(1, 1, 0, stageB(c, 0, 0); stageB(c, 0, 1));
  }
  asm volatile("s_waitcnt vmcnt(0)" ::: "memory");

#undef PH

  // epilogue: C/D layout col=lane&15, row=(lane>>4)*4+reg
  const int crow0 = bm * 256 + wm + (lane >> 4) * 4;
  const int ccol0 = bn * 256 + wn + lr;
#pragma unroll
  for (int n = 0; n < 4; n++) {
    const int col = ccol0 + n * 16;
    const float bv = bias[col];
#pragma unroll
    for (int m = 0; m < 8; m++) {
#pragma unroll
      for (int r = 0; r < 4; r++) {
        float v = acc[m][n][r] + bv;
        const long row = crow0 + m * 16 + r;
        if (EPI == 0) {
          v = (v >= 0.f) ? v : 0.01f * v;
          _Float16 hi, lo; split_f16(v, hi, lo);
          _Float16* C = (_Float16*)Cout;
          C[row * (long)(2 * N) + col]     = hi;
          C[row * (long)(2 * N) + N + col] = lo;
        } else {
          ((float*)Cout)[row * (long)N + col] = v;
        }
      }
    }
  }
}

// ---------------- quat -> rotmat, write rot (d_out) + Lf (ws, f32) ----------------
__global__ void quat_rot_kernel(const float* __restrict__ q, const float* __restrict__ offs,
                                float* __restrict__ rot, float* __restrict__ Lf)
{
  const int s = blockIdx.x * 256 + threadIdx.x;
  const int j = blockIdx.y;
  const float* qp = q + (long)s * QSTR + j * 4;
  float qw = qp[0], qx = qp[1], qy = qp[2], qz = qp[3];
  float n = sqrtf(qw * qw + qx * qx + qy * qy + qz * qz);
  n = fmaxf(n, 1e-8f);
  float inv = 1.f / n;
  qw *= inv; qx *= inv; qy *= inv; qz *= inv;
  const float xx = qx * qx, yy = qy * qy, zz = qz * qz;
  const float xy = qx * qy, xz = qx * qz, yz = qy * qz;
  const float xw = qx * qw, yw = qy * qw, zw = qz * qw;
  const float r00 = 1.f - 2.f * (yy + zz), r01 = 2.f * (xy - zw), r02 = 2.f * (xz + yw);
  const float r10 = 2.f * (xy + zw), r11 = 1.f - 2.f * (xx + zz), r12 = 2.f * (yz - xw);
  const float r20 = 2.f * (xz - yw), r21 = 2.f * (yz + xw), r22 = 1.f - 2.f * (xx + yy);

  float4* ro = (float4*)(rot + ((long)s * JN + j) * 16);
  ro[0] = make_float4(r00, r01, r02, 0.f);
  ro[1] = make_float4(r10, r11, r12, 0.f);
  ro[2] = make_float4(r20, r21, r22, 0.f);
  ro[3] = make_float4(0.f, 0.f, 0.f, 1.f);

  const float tx = offs[j * 3 + 0], ty = offs[j * 3 + 1], tz = offs[j * 3 + 2];
  float* L = Lf + (long)j * 12 * B_ + s;
  L[0L * B_]  = r00; L[1L * B_]  = r01; L[2L * B_]  = r02; L[3L * B_]  = tx;
  L[4L * B_]  = r10; L[5L * B_]  = r11; L[6L * B_]  = r12; L[7L * B_]  = ty;
  L[8L * B_]  = r20; L[9L * B_]  = r21; L[10L * B_] = r22; L[11L * B_] = tz;
}

// ---------------- forward kinematics (all fp32) ----------------
struct FkParams { int par[JN]; unsigned long long childmask; };

__global__ void fk_kernel(const float* __restrict__ Lf, float* __restrict__ Gt,
                          float* __restrict__ pose, FkParams P)
{
  const int s = blockIdx.x * 256 + threadIdx.x;
  float G[12];
#pragma unroll
  for (int e = 0; e < 12; e++) G[e] = Lf[(long)e * B_ + s];
  if (P.childmask & 1ull) {
#pragma unroll
    for (int e = 0; e < 12; e++) Gt[(long)e * B_ + s] = G[e];
  }
  pose[(long)s * (JN * 3) + 0] = G[3];
  pose[(long)s * (JN * 3) + 1] = G[7];
  pose[(long)s * (JN * 3) + 2] = G[11];

  for (int j = 1; j < JN; j++) {
    const int p = P.par[j];
    float Pm[12];
    if (p == j - 1) {
#pragma unroll
      for (int e = 0; e < 12; e++) Pm[e] = G[e];
    } else {
#pragma unroll
      for (int e = 0; e < 12; e++) Pm[e] = Gt[((long)p * 12 + e) * B_ + s];
    }
    float L[12];
#pragma unroll
    for (int e = 0; e < 12; e++) L[e] = Lf[((long)j * 12 + e) * B_ + s];
#pragma unroll
    for (int r = 0; r < 3; r++) {
#pragma unroll
      for (int c = 0; c < 4; c++) {
        float v = Pm[r * 4 + 0] * L[0 * 4 + c] + Pm[r * 4 + 1] * L[1 * 4 + c]
                + Pm[r * 4 + 2] * L[2 * 4 + c];
        if (c == 3) v += Pm[r * 4 + 3];
        G[r * 4 + c] = v;
      }
    }
    if ((P.childmask >> j) & 1ull) {
#pragma unroll
      for (int e = 0; e < 12; e++) Gt[((long)j * 12 + e) * B_ + s] = G[e];
    }
    pose[(long)s * (JN * 3) + j * 3 + 0] = G[3];
    pose[(long)s * (JN * 3) + j * 3 + 1] = G[7];
    pose[(long)s * (JN * 3) + j * 3 + 2] = G[11];
  }
}

// ---------------- host: replicate np.random.default_rng(7) parents ----------------
static void compute_parents(int* par, unsigned long long* childmask)
{
  uint32_t pool[4];
  uint32_t hc = 0x43b0d7e5u;                       // INIT_A
  auto hashmix = [&hc](uint32_t v) {
    v ^= hc; hc *= 0x931e8875u; v *= hc; v ^= v >> 16; return v;
  };
  auto mix = [](uint32_t x, uint32_t y) {
    uint32_t r = 0xca01f9ddu * x - 0x4973f715u * y;
    r ^= r >> 16;
    return r;
  };
  const uint32_t entropy[1] = {7u};
  for (int i = 0; i < 4; i++) pool[i] = hashmix(i < 1 ? entropy[i] : 0u);
  for (int si = 0; si < 4; si++)
    for (int di = 0; di < 4; di++)
      if (si != di) pool[di] = mix(pool[di], hashmix(pool[si]));
  uint32_t gs[8];
  uint32_t hb = 0x8b51f9ddu;                       // INIT_B
  for (int i = 0; i < 8; i++) {
    uint32_t dv = pool[i & 3];
    dv ^= hb; hb *= 0x58f38dedu; dv *= hb; dv ^= dv >> 16;
    gs[i] = dv;
  }
  uint64_t sw0 = (uint64_t)gs[0] | ((uint64_t)gs[1] << 32);
  uint64_t sw1 = (uint64_t)gs[2] | ((uint64_t)gs[3] << 32);
  uint64_t iw0 = (uint64_t)gs[4] | ((uint64_t)gs[5] << 32);
  uint64_t iw1 = (uint64_t)gs[6] | ((uint64_t)gs[7] << 32);
  const __uint128_t MULT = (((__uint128_t)0x2360ed051fc65da4ULL) << 64) | 0x4385df649fccf645ULL;
  __uint128_t inc = ((((__uint128_t)iw0 << 64) | iw1) << 1) | 1;
  __uint128_t state = 0;
  state = state * MULT + inc;
  state += (((__uint128_t)sw0) << 64) | sw1;
  state = state * MULT + inc;
  bool has32 = false; uint32_t buf32 = 0;
  auto next64 = [&]() {
    state = state * MULT + inc;
    uint64_t hi = (uint64_t)(state >> 64), lo = (uint64_t)state;
    uint32_t rot = (uint32_t)(state >> 122);
    uint64_t x = hi ^ lo;
    return (x >> rot) | (x << ((64u - rot) & 63u));
  };
  auto next32 = [&]() -> uint32_t {
    if (has32) { has32 = false; return buf32; }
    uint64_t v = next64();
    has32 = true; buf32 = (uint32_t)(v >> 32);
    return (uint32_t)v;
  };
  par[0] = -1;
  for (int j = 1; j < JN; j++) {
    uint32_t rng = (uint32_t)(j - 1);
    if (rng == 0) { par[j] = 0; continue; }
    uint32_t rng_excl = rng + 1;
    uint64_t m = (uint64_t)next32() * (uint64_t)rng_excl;
    uint32_t leftover = (uint32_t)m;
    if (leftover < rng_excl) {
      uint32_t threshold = (uint32_t)((0x100000000ULL - rng_excl) % rng_excl);
      while (leftover < threshold) {
        m = (uint64_t)next32() * (uint64_t)rng_excl;
        leftover = (uint32_t)m;
      }
    }
    par[j] = (int)(m >> 32);
  }
  unsigned long long cm = 0;
  for (int j = 1; j < JN; j++) cm |= 1ull << par[j];
  *childmask = cm;
}

// ---------------- launch ----------------
extern "C" void kernel_launch(void* const* d_in, const int* in_sizes, int n_in,
                              void* d_out, int out_size, void* d_ws, size_t ws_size,
                              hipStream_t stream)
{
  const float* in_seq = (const float*)d_in[0];
  const float* w1 = (const float*)d_in[1];
  const float* b1 = (const float*)d_in[2];
  const float* w2 = (const float*)d_in[3];
  const float* b2 = (const float*)d_in[4];
  const float* w3 = (const float*)d_in[5];
  const float* b3 = (const float*)d_in[6];
  const float* w4 = (const float*)d_in[7];
  const float* b4 = (const float*)d_in[8];
  const float* offs = (const float*)d_in[9];

  char* pR1 = (char*)d_ws;
  char* pR2 = pR1 + 35390464;
  char* pR3 = pR2 + 134217728;
  _Float16* x2  = (_Float16*)pR1;
  _Float16* w1f = (_Float16*)(pR1 + 25165824);
  _Float16* w2f = (_Float16*)(pR1 + 25165824 + 786432);
  _Float16* w3f = (_Float16*)(pR1 + 25165824 + 786432 + 4194304);
  _Float16* w4f = (_Float16*)(pR1 + 25165824 + 786432 + 2 * 4194304);
  float*    b4p = (float*)(pR1 + 25165824 + 786432 + 2 * 4194304 + 1048576);
  float*    q   = (float*)pR1;            // overwrites x2/w1f/w2f/w3f only
  _Float16* h1  = (_Float16*)pR2;
  _Float16* h3  = (_Float16*)pR2;
  float*    Gt  = (float*)pR2;
  _Float16* h2  = (_Float16*)pR3;
  float*    Lf  = (float*)pR3;

  float* pose = (float*)d_out;                        // [B_,57,3]
  float* rot  = (float*)d_out + (long)B_ * JN * 3;    // [B_,57,4,4]

  // prep
  prep_x2_kernel<<<(B_ * 192) / 256, 256, 0, stream>>>(in_seq, x2);
  prep_w2_kernel<<<(1024 * 192) / 256, 256, 0, stream>>>(w1, w1f, 171, 192, 1024);
  prep_w2_kernel<<<(1024 * 1024) / 256, 256, 0, stream>>>(w2, w2f, 1024, 1024, 1024);
  prep_w2_kernel<<<(1024 * 1024) / 256, 256, 0, stream>>>(w3, w3f, 1024, 1024, 1024);
  prep_w2_kernel<<<(256 * 1024) / 256, 256, 0, stream>>>(w4, w4f, 1024, 1024, 228);
  prep_b4_kernel<<<1, 256, 0, stream>>>(b4, b4p);

  // MLP (split-f16, virtual 3K)
  gemm_hl<0><<<(B_ / 128) * (1024 / 128), 256, 0, stream>>>(x2, w1f, b1, h1, B_, 1024, 192);
  gemm256<0><<<(B_ / 256) * (1024 / 256), 512, 0, stream>>>(h1, w2f, b2, h2, B_, 1024, 1024);
  gemm256<0><<<(B_ / 256) * (1024 / 256), 512, 0, stream>>>(h2, w3f, b3, h3, B_, 1024, 1024);
  gemm256<1><<<(B_ / 256) * (QSTR / 256), 512, 0, stream>>>(h3, w4f, b4p, q, B_, QSTR, 1024);

  // epilogue
  quat_rot_kernel<<<dim3(B_ / 256, JN), 256, 0, stream>>>(q, offs, rot, Lf);

  FkParams P;
  compute_parents(P.par, &P.childmask);
  fk_kernel<<<B_ / 256, 256, 0, stream>>>(Lf, Gt, pose, P);
}

// Round 16
// 737.339 us; speedup vs baseline: 1.1278x; 1.0513x over previous
//
#include <hip/hip_runtime.h>
#include <hip/hip_bf16.h>
#include <stdint.h>

#define B_   32768
#define JN   57
#define QSTR 256      // q row stride (228 padded to 256)

typedef _Float16 f16x8 __attribute__((ext_vector_type(8)));
typedef float    f32x4 __attribute__((ext_vector_type(4)));

__device__ __forceinline__ void split_f16(float v, _Float16& hi, _Float16& lo) {
  hi = (_Float16)v;
  lo = (_Float16)(v - (float)hi);
}

// ---------------- prep kernels ----------------
__global__ void prep_x2_kernel(const float* __restrict__ x, _Float16* __restrict__ xp) {
  long i = (long)blockIdx.x * 256 + threadIdx.x;   // over B_*192
  int row = (int)(i / 192), col = (int)(i % 192);
  float v = (col < 171) ? x[(long)row * 171 + col] : 0.f;
  _Float16 hi, lo; split_f16(v, hi, lo);
  xp[(long)row * 384 + col]       = hi;
  xp[(long)row * 384 + 192 + col] = lo;
}

__global__ void prep_w2_kernel(const float* __restrict__ w, _Float16* __restrict__ wf,
                               int Ksrc, int Kpad, int Nsrc) {
  long i = (long)blockIdx.x * 256 + threadIdx.x;   // over Ndst*Kpad
  int n = (int)(i / Kpad), k = (int)(i % Kpad);
  float v = (k < Ksrc && n < Nsrc) ? w[(long)k * Nsrc + n] : 0.f;
  _Float16 hi, lo; split_f16(v, hi, lo);
  wf[(long)n * (2 * Kpad) + k]        = hi;
  wf[(long)n * (2 * Kpad) + Kpad + k] = lo;
}

__global__ void prep_b4_kernel(const float* __restrict__ b, float* __restrict__ bp) {
  int i = threadIdx.x;  // 256 threads
  bp[i] = (i < 228) ? b[i] : 0.f;
}

// ---------------- 128² split-f16 GEMM (m97 structure) — layer 1 only ----------------
template<int EPI>
__global__ __launch_bounds__(256)
void gemm_hl(const _Float16* __restrict__ A, const _Float16* __restrict__ Bt,
             const float* __restrict__ bias, void* __restrict__ Cout,
             int M, int N, int Kp)
{
  __shared__ __align__(16) _Float16 As[128 * 64];
  __shared__ __align__(16) _Float16 Bs[128 * 64];
  const int lda = 2 * Kp;
  const int T = Kp >> 6;
  const int tiles_n = N >> 7;
  const int cpx  = gridDim.x >> 3;
  const int virt = (blockIdx.x & 7) * cpx + (blockIdx.x >> 3);
  const int bm = virt / tiles_n;
  const int bn = virt % tiles_n;
  const int tid  = threadIdx.x;
  const int wave = tid >> 6;
  const int lane = tid & 63;

  const int srow = wave * 8 + (lane >> 3);
  const int scol = (((lane & 7) ^ (lane >> 3)) * 8);
  const long abase = (long)bm * 128;
  const long bbase = (long)bn * 128;

  f32x4 acc[4][4] = {};

  const int wm = (wave >> 1) * 64;
  const int wn = (wave & 1) * 64;
  const int lr = lane & 15;
  const int ch0 = (((lane >> 4) ^ (lane & 7)) * 8);
  const int ch1 = (((4 + (lane >> 4)) ^ (lane & 7)) * 8);

  for (int ph = 0; ph < 3; ++ph) {
    const int aoff = (ph == 2) ? Kp : 0;
    const int boff = (ph == 1) ? Kp : 0;
    for (int u = 0; u < T; ++u) {
#pragma unroll
      for (int i = 0; i < 4; i++) {
        const _Float16* asrc = A  + (abase + i * 32 + srow) * (long)lda + (aoff + u * 64 + scol);
        const _Float16* bsrc = Bt + (bbase + i * 32 + srow) * (long)lda + (boff + u * 64 + scol);
        __builtin_amdgcn_global_load_lds(
            (const __attribute__((address_space(1))) void*)asrc,
            (__attribute__((address_space(3))) void*)(As + (i * 256 + wave * 64) * 8),
            16, 0, 0);
        __builtin_amdgcn_global_load_lds(
            (const __attribute__((address_space(1))) void*)bsrc,
            (__attribute__((address_space(3))) void*)(Bs + (i * 256 + wave * 64) * 8),
            16, 0, 0);
      }
      __syncthreads();

#pragma unroll
      for (int ks = 0; ks < 2; ks++) {
        const int ch = ks ? ch1 : ch0;
        f16x8 af[4], bfr[4];
#pragma unroll
        for (int m = 0; m < 4; m++)
          af[m] = *(const f16x8*)(As + (wm + m * 16 + lr) * 64 + ch);
#pragma unroll
        for (int n = 0; n < 4; n++)
          bfr[n] = *(const f16x8*)(Bs + (wn + n * 16 + lr) * 64 + ch);
#pragma unroll
        for (int m = 0; m < 4; m++)
#pragma unroll
          for (int n = 0; n < 4; n++)
            acc[m][n] = __builtin_amdgcn_mfma_f32_16x16x32_f16(af[m], bfr[n], acc[m][n], 0, 0, 0);
      }
      __syncthreads();
    }
  }

  const int crow0 = bm * 128 + wm + (lane >> 4) * 4;
  const int ccol0 = bn * 128 + wn + lr;
#pragma unroll
  for (int n = 0; n < 4; n++) {
    const int col = ccol0 + n * 16;
    const float bv = bias[col];
#pragma unroll
    for (int m = 0; m < 4; m++) {
#pragma unroll
      for (int r = 0; r < 4; r++) {
        float v = acc[m][n][r] + bv;
        const long row = crow0 + m * 16 + r;
        if (EPI == 0) {
          v = (v >= 0.f) ? v : 0.01f * v;
          _Float16 hi, lo; split_f16(v, hi, lo);
          _Float16* C = (_Float16*)Cout;
          C[row * (long)(2 * N) + col]     = hi;
          C[row * (long)(2 * N) + N + col] = lo;
        } else {
          ((float*)Cout)[row * (long)N + col] = v;
        }
      }
    }
  }
}

// ---------------- 256² 4-phase split-f16 GEMM — B-dedup schedule (best measured) ----------------
// 512 thr = 8 waves (2M x 4N), per-wave 128x64 out. BK=64, 2 LDS slots (128KB).
// acc[8][4] f32x4 = 128 AGPRs/lane -> REQUIRES the 256-reg budget of
// __launch_bounds__(512,2); min-waves=4 forces a 128-reg cap and spills the
// accumulator to scratch (R11: 10x regression). Do not raise.
// Structure-space exploration (R7-R14): drain(311us), 8ph-m201(298),
// 8ph-deep-prefetch(268), THIS(249), 128²-2blk/CU(277), BK32-4blk(spill).
// All neighbors regress — local optimum at 249us/dispatch, MfmaUtil 36%.
template<int EPI>
__global__ __launch_bounds__(512, 2)
void gemm256(const _Float16* __restrict__ Ag, const _Float16* __restrict__ Bt,
             const float* __restrict__ bias, void* __restrict__ Cout,
             int M, int N, int Kp)
{
  __shared__ __align__(16) _Float16 As[2][256 * 64];
  __shared__ __align__(16) _Float16 Bs[2][256 * 64];
  const int lda = 2 * Kp;
  const int T  = Kp >> 6;
  const int NT = 3 * T;
  const int NI = NT >> 1;
  const int tiles_n = N >> 8;
  const int cpx  = gridDim.x >> 3;
  const int virt = (blockIdx.x & 7) * cpx + (blockIdx.x >> 3);
  const int bm = virt / tiles_n;
  const int bn = virt % tiles_n;
  const int tid  = threadIdx.x;
  const int wid  = tid >> 6;
  const int lane = tid & 63;

  const long abase = (long)bm * 256;
  const long bbase = (long)bn * 256;
  const int scol = (((lane & 7) ^ ((tid >> 3) & 7)) * 8);

  const int wm = (wid >> 2) * 128;
  const int wn = (wid & 3) * 64;
  const int lr = lane & 15;

  f32x4 acc[8][4] = {};

  auto stageA = [&](int t, int s, int h) {
    const int ph = t / T, u = t - ph * T;
    const long ko = ((ph == 2) ? (long)Kp : 0) + u * 64 + scol;
    const _Float16* src = Ag + (abase + h * 128 + (tid >> 3)) * (long)lda + ko;
    const _Float16* dst = &As[s][h * 8192 + tid * 8];
    __builtin_amdgcn_global_load_lds(
        (const __attribute__((address_space(1))) void*)src,
        (__attribute__((address_space(3))) void*)dst, 16, 0, 0);
    __builtin_amdgcn_global_load_lds(
        (const __attribute__((address_space(1))) void*)(src + 64 * (long)lda),
        (__attribute__((address_space(3))) void*)(dst + 4096), 16, 0, 0);
  };
  auto stageB = [&](int t, int s, int h) {
    const int ph = t / T, u = t - ph * T;
    const long ko = ((ph == 1) ? (long)Kp : 0) + u * 64 + scol;
    const _Float16* src = Bt + (bbase + h * 128 + (tid >> 3)) * (long)lda + ko;
    const _Float16* dst = &Bs[s][h * 8192 + tid * 8];
    __builtin_amdgcn_global_load_lds(
        (const __attribute__((address_space(1))) void*)src,
        (__attribute__((address_space(3))) void*)dst, 16, 0, 0);
    __builtin_amdgcn_global_load_lds(
        (const __attribute__((address_space(1))) void*)(src + 64 * (long)lda),
        (__attribute__((address_space(3))) void*)(dst + 4096), 16, 0, 0);
  };

  // phase: stage -> [vmcnt(4)] -> barrier -> 12 ds_reads -> 32 MFMA
#define PH(slot, ks, WAITV, ...)                                                  \
  do {                                                                            \
    __VA_ARGS__;                                                                  \
    if (WAITV) asm volatile("s_waitcnt vmcnt(4)" ::: "memory");                   \
    __builtin_amdgcn_s_barrier();                                                 \
    const int ch = (((ks) * 4 + (lane >> 4)) ^ (lane & 7)) * 8;                   \
    f16x8 af[8], bfr[4];                                                          \
    _Pragma("unroll")                                                             \
    for (int mi = 0; mi < 8; ++mi)                                                \
      af[mi] = *(const f16x8*)&As[slot][(wm + mi * 16 + lr) * 64 + ch];           \
    _Pragma("unroll")                                                             \
    for (int n = 0; n < 4; ++n)                                                   \
      bfr[n] = *(const f16x8*)&Bs[slot][(wn + n * 16 + lr) * 64 + ch];            \
    __builtin_amdgcn_s_setprio(1);                                                \
    _Pragma("unroll")                                                             \
    for (int mi = 0; mi < 8; ++mi)                                                \
      _Pragma("unroll")                                                           \
      for (int n = 0; n < 4; ++n)                                                 \
        acc[mi][n] = __builtin_amdgcn_mfma_f32_16x16x32_f16(                      \
            af[mi], bfr[n], acc[mi][n], 0, 0, 0);                                 \
    __builtin_amdgcn_s_setprio(0);                                                \
  } while (0)

  // prologue: full tile 0 -> S0 (8 loads/thread outstanding)
  stageA(0, 0, 0); stageA(0, 0, 1); stageB(0, 0, 0); stageB(0, 0, 1);

  for (int i = 0; i < NI; ++i) {
    const int b = 2 * i + 1;
    const int c = (2 * i + 2 < NT) ? 2 * i + 2 : 0;   // tail: harmless re-stage
    PH(0, 0, 1, stageA(b, 1, 0); stageA(b, 1, 1));
    PH(0, 1, 0, stageB(b, 1, 0); stageB(b, 1, 1));
    PH(1, 0, 1, stageA(c, 0, 0); stageA(c, 0, 1));
    PH(1, 1, 0, stageB(c, 0, 0); stageB(c, 0, 1));
  }
  asm volatile("s_waitcnt vmcnt(0)" ::: "memory");

#undef PH

  // epilogue: C/D layout col=lane&15, row=(lane>>4)*4+reg
  const int crow0 = bm * 256 + wm + (lane >> 4) * 4;
  const int ccol0 = bn * 256 + wn + lr;
#pragma unroll
  for (int n = 0; n < 4; n++) {
    const int col = ccol0 + n * 16;
    const float bv = bias[col];
#pragma unroll
    for (int m = 0; m < 8; m++) {
#pragma unroll
      for (int r = 0; r < 4; r++) {
        float v = acc[m][n][r] + bv;
        const long row = crow0 + m * 16 + r;
        if (EPI == 0) {
          v = (v >= 0.f) ? v : 0.01f * v;
          _Float16 hi, lo; split_f16(v, hi, lo);
          _Float16* C = (_Float16*)Cout;
          C[row * (long)(2 * N) + col]     = hi;
          C[row * (long)(2 * N) + N + col] = lo;
        } else {
          ((float*)Cout)[row * (long)N + col] = v;
        }
      }
    }
  }
}

// ---------------- fused quat->rotmat + forward kinematics ----------------
// One thread per sample; q staged per-block through LDS in 4 chunks of 64 cols
// (coalesced global reads; LDS rows padded to 65 floats -> conflict-free scalar
// reads). Eliminates the Lf round-trip (quat wrote 89.6MB, fk read it back).
// FK logic identical to the previous fk_kernel (G regs + global Gt scratch).
struct FkParams { int par[JN]; unsigned long long childmask; };

__global__ __launch_bounds__(256)
void quat_fk_kernel(const float* __restrict__ q, const float* __restrict__ offs,
                    float* __restrict__ rot, float* __restrict__ Gt,
                    float* __restrict__ pose, FkParams P)
{
  __shared__ float qs[256][65];                 // 66,560 B
  const int tid = threadIdx.x;
  const int s0  = blockIdx.x * 256;
  const int s   = s0 + tid;

  float G[12];

  for (int c = 0; c < 4; ++c) {
    __syncthreads();                            // prev chunk fully consumed
    // stage cols [c*64, c*64+64) for 256 rows; consecutive tid -> consecutive col
    for (int idx = tid; idx < 256 * 64; idx += 256) {
      const int r = idx >> 6, col = idx & 63;
      qs[r][col] = q[(long)(s0 + r) * QSTR + c * 64 + col];  // rows padded to 256 cols
    }
    __syncthreads();
    const int jlo = c * 16;
    const int jhi = (c == 3) ? JN : jlo + 16;
    for (int j = jlo; j < jhi; ++j) {
      const int cb = j * 4 - c * 64;
      float qw = qs[tid][cb + 0], qx = qs[tid][cb + 1];
      float qy = qs[tid][cb + 2], qz = qs[tid][cb + 3];
      float n = sqrtf(qw * qw + qx * qx + qy * qy + qz * qz);
      n = fmaxf(n, 1e-8f);
      const float inv = 1.f / n;
      qw *= inv; qx *= inv; qy *= inv; qz *= inv;
      const float xx = qx * qx, yy = qy * qy, zz = qz * qz;
      const float xy = qx * qy, xz = qx * qz, yz = qy * qz;
      const float xw = qx * qw, yw = qy * qw, zw = qz * qw;
      float L[12];
      L[0] = 1.f - 2.f * (yy + zz); L[1] = 2.f * (xy - zw); L[2]  = 2.f * (xz + yw);
      L[4] = 2.f * (xy + zw); L[5] = 1.f - 2.f * (xx + zz); L[6]  = 2.f * (yz - xw);
      L[8] = 2.f * (xz - yw); L[9] = 2.f * (yz + xw); L[10] = 1.f - 2.f * (xx + yy);

      float4* ro = (float4*)(rot + ((long)s * JN + j) * 16);
      ro[0] = make_float4(L[0], L[1], L[2],  0.f);
      ro[1] = make_float4(L[4], L[5], L[6],  0.f);
      ro[2] = make_float4(L[8], L[9], L[10], 0.f);
      ro[3] = make_float4(0.f, 0.f, 0.f, 1.f);

      L[3]  = offs[j * 3 + 0];
      L[7]  = offs[j * 3 + 1];
      L[11] = offs[j * 3 + 2];

      // FK step
      if (j == 0) {
#pragma unroll
        for (int e = 0; e < 12; e++) G[e] = L[e];
      } else {
        const int p = P.par[j];                 // scalar -> uniform branch
        float Pm[12];
        if (p == j - 1) {
#pragma unroll
          for (int e = 0; e < 12; e++) Pm[e] = G[e];
        } else {
#pragma unroll
          for (int e = 0; e < 12; e++) Pm[e] = Gt[((long)p * 12 + e) * B_ + s];
        }
#pragma unroll
        for (int r = 0; r < 3; r++) {
#pragma unroll
          for (int cc = 0; cc < 4; cc++) {
            float v = Pm[r * 4 + 0] * L[0 * 4 + cc] + Pm[r * 4 + 1] * L[1 * 4 + cc]
                    + Pm[r * 4 + 2] * L[2 * 4 + cc];
            if (cc == 3) v += Pm[r * 4 + 3];
            G[r * 4 + cc] = v;
          }
        }
      }
      if ((P.childmask >> j) & 1ull) {
#pragma unroll
        for (int e = 0; e < 12; e++) Gt[((long)j * 12 + e) * B_ + s] = G[e];
      }
      pose[(long)s * (JN * 3) + j * 3 + 0] = G[3];
      pose[(long)s * (JN * 3) + j * 3 + 1] = G[7];
      pose[(long)s * (JN * 3) + j * 3 + 2] = G[11];
    }
  }
}

// ---------------- host: replicate np.random.default_rng(7) parents ----------------
static void compute_parents(int* par, unsigned long long* childmask)
{
  uint32_t pool[4];
  uint32_t hc = 0x43b0d7e5u;                       // INIT_A
  auto hashmix = [&hc](uint32_t v) {
    v ^= hc; hc *= 0x931e8875u; v *= hc; v ^= v >> 16; return v;
  };
  auto mix = [](uint32_t x, uint32_t y) {
    uint32_t r = 0xca01f9ddu * x - 0x4973f715u * y;
    r ^= r >> 16;
    return r;
  };
  const uint32_t entropy[1] = {7u};
  for (int i = 0; i < 4; i++) pool[i] = hashmix(i < 1 ? entropy[i] : 0u);
  for (int si = 0; si < 4; si++)
    for (int di = 0; di < 4; di++)
      if (si != di) pool[di] = mix(pool[di], hashmix(pool[si]));
  uint32_t gs[8];
  uint32_t hb = 0x8b51f9ddu;                       // INIT_B
  for (int i = 0; i < 8; i++) {
    uint32_t dv = pool[i & 3];
    dv ^= hb; hb *= 0x58f38dedu; dv *= hb; dv ^= dv >> 16;
    gs[i] = dv;
  }
  uint64_t sw0 = (uint64_t)gs[0] | ((uint64_t)gs[1] << 32);
  uint64_t sw1 = (uint64_t)gs[2] | ((uint64_t)gs[3] << 32);
  uint64_t iw0 = (uint64_t)gs[4] | ((uint64_t)gs[5] << 32);
  uint64_t iw1 = (uint64_t)gs[6] | ((uint64_t)gs[7] << 32);
  const __uint128_t MULT = (((__uint128_t)0x2360ed051fc65da4ULL) << 64) | 0x4385df649fccf645ULL;
  __uint128_t inc = ((((__uint128_t)iw0 << 64) | iw1) << 1) | 1;
  __uint128_t state = 0;
  state = state * MULT + inc;
  state += (((__uint128_t)sw0) << 64) | sw1;
  state = state * MULT + inc;
  bool has32 = false; uint32_t buf32 = 0;
  auto next64 = [&]() {
    state = state * MULT + inc;
    uint64_t hi = (uint64_t)(state >> 64), lo = (uint64_t)state;
    uint32_t rot = (uint32_t)(state >> 122);
    uint64_t x = hi ^ lo;
    return (x >> rot) | (x << ((64u - rot) & 63u));
  };
  auto next32 = [&]() -> uint32_t {
    if (has32) { has32 = false; return buf32; }
    uint64_t v = next64();
    has32 = true; buf32 = (uint32_t)(v >> 32);
    return (uint32_t)v;
  };
  par[0] = -1;
  for (int j = 1; j < JN; j++) {
    uint32_t rng = (uint32_t)(j - 1);
    if (rng == 0) { par[j] = 0; continue; }
    uint32_t rng_excl = rng + 1;
    uint64_t m = (uint64_t)next32() * (uint64_t)rng_excl;
    uint32_t leftover = (uint32_t)m;
    if (leftover < rng_excl) {
      uint32_t threshold = (uint32_t)((0x100000000ULL - rng_excl) % rng_excl);
      while (leftover < threshold) {
        m = (uint64_t)next32() * (uint64_t)rng_excl;
        leftover = (uint32_t)m;
      }
    }
    par[j] = (int)(m >> 32);
  }
  unsigned long long cm = 0;
  for (int j = 1; j < JN; j++) cm |= 1ull << par[j];
  *childmask = cm;
}

// ---------------- launch ----------------
extern "C" void kernel_launch(void* const* d_in, const int* in_sizes, int n_in,
                              void* d_out, int out_size, void* d_ws, size_t ws_size,
                              hipStream_t stream)
{
  const float* in_seq = (const float*)d_in[0];
  const float* w1 = (const float*)d_in[1];
  const float* b1 = (const float*)d_in[2];
  const float* w2 = (const float*)d_in[3];
  const float* b2 = (const float*)d_in[4];
  const float* w3 = (const float*)d_in[5];
  const float* b3 = (const float*)d_in[6];
  const float* w4 = (const float*)d_in[7];
  const float* b4 = (const float*)d_in[8];
  const float* offs = (const float*)d_in[9];

  char* pR1 = (char*)d_ws;
  char* pR2 = pR1 + 35390464;
  char* pR3 = pR2 + 134217728;
  _Float16* x2  = (_Float16*)pR1;
  _Float16* w1f = (_Float16*)(pR1 + 25165824);
  _Float16* w2f = (_Float16*)(pR1 + 25165824 + 786432);
  _Float16* w3f = (_Float16*)(pR1 + 25165824 + 786432 + 4194304);
  _Float16* w4f = (_Float16*)(pR1 + 25165824 + 786432 + 2 * 4194304);
  float*    b4p = (float*)(pR1 + 25165824 + 786432 + 2 * 4194304 + 1048576);
  float*    q   = (float*)pR1;            // overwrites x2/w1f/w2f/w3f only
  _Float16* h1  = (_Float16*)pR2;
  _Float16* h3  = (_Float16*)pR2;
  float*    Gt  = (float*)pR2;            // h1/h3 dead after L4
  _Float16* h2  = (_Float16*)pR3;

  float* pose = (float*)d_out;                        // [B_,57,3]
  float* rot  = (float*)d_out + (long)B_ * JN * 3;    // [B_,57,4,4]

  // prep
  prep_x2_kernel<<<(B_ * 192) / 256, 256, 0, stream>>>(in_seq, x2);
  prep_w2_kernel<<<(1024 * 192) / 256, 256, 0, stream>>>(w1, w1f, 171, 192, 1024);
  prep_w2_kernel<<<(1024 * 1024) / 256, 256, 0, stream>>>(w2, w2f, 1024, 1024, 1024);
  prep_w2_kernel<<<(1024 * 1024) / 256, 256, 0, stream>>>(w3, w3f, 1024, 1024, 1024);
  prep_w2_kernel<<<(256 * 1024) / 256, 256, 0, stream>>>(w4, w4f, 1024, 1024, 228);
  prep_b4_kernel<<<1, 256, 0, stream>>>(b4, b4p);

  // MLP (split-f16, virtual 3K)
  gemm_hl<0><<<(B_ / 128) * (1024 / 128), 256, 0, stream>>>(x2, w1f, b1, h1, B_, 1024, 192);
  gemm256<0><<<(B_ / 256) * (1024 / 256), 512, 0, stream>>>(h1, w2f, b2, h2, B_, 1024, 1024);
  gemm256<0><<<(B_ / 256) * (1024 / 256), 512, 0, stream>>>(h2, w3f, b3, h3, B_, 1024, 1024);
  gemm256<1><<<(B_ / 256) * (QSTR / 256), 512, 0, stream>>>(h3, w4f, b4p, q, B_, QSTR, 1024);

  // fused epilogue (quat->rot + FK), no Lf round-trip
  FkParams P;
  compute_parents(P.par, &P.childmask);
  quat_fk_kernel<<<B_ / 256, 256, 0, stream>>>(q, offs, rot, Gt, pose, P);
}

// Round 17
// 732.056 us; speedup vs baseline: 1.1360x; 1.0072x over previous
//
#include <hip/hip_runtime.h>
#include <hip/hip_bf16.h>
#include <stdint.h>

#define B_   32768
#define JN   57
#define QSTR 256      // q row stride (228 padded to 256)

typedef _Float16 f16x8 __attribute__((ext_vector_type(8)));
typedef float    f32x4 __attribute__((ext_vector_type(4)));

__device__ __forceinline__ void split_f16(float v, _Float16& hi, _Float16& lo) {
  hi = (_Float16)v;
  lo = (_Float16)(v - (float)hi);
}

// ---------------- prep kernels ----------------
__global__ void prep_x2_kernel(const float* __restrict__ x, _Float16* __restrict__ xp) {
  long i = (long)blockIdx.x * 256 + threadIdx.x;   // over B_*192
  int row = (int)(i / 192), col = (int)(i % 192);
  float v = (col < 171) ? x[(long)row * 171 + col] : 0.f;
  _Float16 hi, lo; split_f16(v, hi, lo);
  xp[(long)row * 384 + col]       = hi;
  xp[(long)row * 384 + 192 + col] = lo;
}

__global__ void prep_w2_kernel(const float* __restrict__ w, _Float16* __restrict__ wf,
                               int Ksrc, int Kpad, int Nsrc) {
  long i = (long)blockIdx.x * 256 + threadIdx.x;   // over Ndst*Kpad
  int n = (int)(i / Kpad), k = (int)(i % Kpad);
  float v = (k < Ksrc && n < Nsrc) ? w[(long)k * Nsrc + n] : 0.f;
  _Float16 hi, lo; split_f16(v, hi, lo);
  wf[(long)n * (2 * Kpad) + k]        = hi;
  wf[(long)n * (2 * Kpad) + Kpad + k] = lo;
}

__global__ void prep_b4_kernel(const float* __restrict__ b, float* __restrict__ bp) {
  int i = threadIdx.x;  // 256 threads
  bp[i] = (i < 228) ? b[i] : 0.f;
}

// ---------------- 128² split-f16 GEMM (m97 structure) — layer 1 only ----------------
template<int EPI>
__global__ __launch_bounds__(256)
void gemm_hl(const _Float16* __restrict__ A, const _Float16* __restrict__ Bt,
             const float* __restrict__ bias, void* __restrict__ Cout,
             int M, int N, int Kp)
{
  __shared__ __align__(16) _Float16 As[128 * 64];
  __shared__ __align__(16) _Float16 Bs[128 * 64];
  const int lda = 2 * Kp;
  const int T = Kp >> 6;
  const int tiles_n = N >> 7;
  const int cpx  = gridDim.x >> 3;
  const int virt = (blockIdx.x & 7) * cpx + (blockIdx.x >> 3);
  const int bm = virt / tiles_n;
  const int bn = virt % tiles_n;
  const int tid  = threadIdx.x;
  const int wave = tid >> 6;
  const int lane = tid & 63;

  const int srow = wave * 8 + (lane >> 3);
  const int scol = (((lane & 7) ^ (lane >> 3)) * 8);
  const long abase = (long)bm * 128;
  const long bbase = (long)bn * 128;

  f32x4 acc[4][4] = {};

  const int wm = (wave >> 1) * 64;
  const int wn = (wave & 1) * 64;
  const int lr = lane & 15;
  const int ch0 = (((lane >> 4) ^ (lane & 7)) * 8);
  const int ch1 = (((4 + (lane >> 4)) ^ (lane & 7)) * 8);

  for (int ph = 0; ph < 3; ++ph) {
    const int aoff = (ph == 2) ? Kp : 0;
    const int boff = (ph == 1) ? Kp : 0;
    for (int u = 0; u < T; ++u) {
#pragma unroll
      for (int i = 0; i < 4; i++) {
        const _Float16* asrc = A  + (abase + i * 32 + srow) * (long)lda + (aoff + u * 64 + scol);
        const _Float16* bsrc = Bt + (bbase + i * 32 + srow) * (long)lda + (boff + u * 64 + scol);
        __builtin_amdgcn_global_load_lds(
            (const __attribute__((address_space(1))) void*)asrc,
            (__attribute__((address_space(3))) void*)(As + (i * 256 + wave * 64) * 8),
            16, 0, 0);
        __builtin_amdgcn_global_load_lds(
            (const __attribute__((address_space(1))) void*)bsrc,
            (__attribute__((address_space(3))) void*)(Bs + (i * 256 + wave * 64) * 8),
            16, 0, 0);
      }
      __syncthreads();

#pragma unroll
      for (int ks = 0; ks < 2; ks++) {
        const int ch = ks ? ch1 : ch0;
        f16x8 af[4], bfr[4];
#pragma unroll
        for (int m = 0; m < 4; m++)
          af[m] = *(const f16x8*)(As + (wm + m * 16 + lr) * 64 + ch);
#pragma unroll
        for (int n = 0; n < 4; n++)
          bfr[n] = *(const f16x8*)(Bs + (wn + n * 16 + lr) * 64 + ch);
#pragma unroll
        for (int m = 0; m < 4; m++)
#pragma unroll
          for (int n = 0; n < 4; n++)
            acc[m][n] = __builtin_amdgcn_mfma_f32_16x16x32_f16(af[m], bfr[n], acc[m][n], 0, 0, 0);
      }
      __syncthreads();
    }
  }

  const int crow0 = bm * 128 + wm + (lane >> 4) * 4;
  const int ccol0 = bn * 128 + wn + lr;
#pragma unroll
  for (int n = 0; n < 4; n++) {
    const int col = ccol0 + n * 16;
    const float bv = bias[col];
#pragma unroll
    for (int m = 0; m < 4; m++) {
#pragma unroll
      for (int r = 0; r < 4; r++) {
        float v = acc[m][n][r] + bv;
        const long row = crow0 + m * 16 + r;
        if (EPI == 0) {
          v = (v >= 0.f) ? v : 0.01f * v;
          _Float16 hi, lo; split_f16(v, hi, lo);
          _Float16* C = (_Float16*)Cout;
          C[row * (long)(2 * N) + col]     = hi;
          C[row * (long)(2 * N) + N + col] = lo;
        } else {
          ((float*)Cout)[row * (long)N + col] = v;
        }
      }
    }
  }
}

// ---------------- 256² 4-phase split-f16 GEMM — B-dedup schedule (best measured) ----------------
// 512 thr = 8 waves (2M x 4N), per-wave 128x64 out. BK=64, 2 LDS slots (128KB).
// acc[8][4] f32x4 = 128 AGPRs/lane -> REQUIRES the 256-reg budget of
// __launch_bounds__(512,2); min-waves=4 spills the accumulator (R11). Do not raise.
// Structure-space exploration (R7-R14): all neighbors regress — local optimum
// at ~250us/dispatch (2 rounds of 256 blocks), MfmaUtil 36%.
template<int EPI>
__global__ __launch_bounds__(512, 2)
void gemm256(const _Float16* __restrict__ Ag, const _Float16* __restrict__ Bt,
             const float* __restrict__ bias, void* __restrict__ Cout,
             int M, int N, int Kp)
{
  __shared__ __align__(16) _Float16 As[2][256 * 64];
  __shared__ __align__(16) _Float16 Bs[2][256 * 64];
  const int lda = 2 * Kp;
  const int T  = Kp >> 6;
  const int NT = 3 * T;
  const int NI = NT >> 1;
  const int tiles_n = N >> 8;
  const int cpx  = gridDim.x >> 3;
  const int virt = (blockIdx.x & 7) * cpx + (blockIdx.x >> 3);
  const int bm = virt / tiles_n;
  const int bn = virt % tiles_n;
  const int tid  = threadIdx.x;
  const int wid  = tid >> 6;
  const int lane = tid & 63;

  const long abase = (long)bm * 256;
  const long bbase = (long)bn * 256;
  const int scol = (((lane & 7) ^ ((tid >> 3) & 7)) * 8);

  const int wm = (wid >> 2) * 128;
  const int wn = (wid & 3) * 64;
  const int lr = lane & 15;

  f32x4 acc[8][4] = {};

  auto stageA = [&](int t, int s, int h) {
    const int ph = t / T, u = t - ph * T;
    const long ko = ((ph == 2) ? (long)Kp : 0) + u * 64 + scol;
    const _Float16* src = Ag + (abase + h * 128 + (tid >> 3)) * (long)lda + ko;
    const _Float16* dst = &As[s][h * 8192 + tid * 8];
    __builtin_amdgcn_global_load_lds(
        (const __attribute__((address_space(1))) void*)src,
        (__attribute__((address_space(3))) void*)dst, 16, 0, 0);
    __builtin_amdgcn_global_load_lds(
        (const __attribute__((address_space(1))) void*)(src + 64 * (long)lda),
        (__attribute__((address_space(3))) void*)(dst + 4096), 16, 0, 0);
  };
  auto stageB = [&](int t, int s, int h) {
    const int ph = t / T, u = t - ph * T;
    const long ko = ((ph == 1) ? (long)Kp : 0) + u * 64 + scol;
    const _Float16* src = Bt + (bbase + h * 128 + (tid >> 3)) * (long)lda + ko;
    const _Float16* dst = &Bs[s][h * 8192 + tid * 8];
    __builtin_amdgcn_global_load_lds(
        (const __attribute__((address_space(1))) void*)src,
        (__attribute__((address_space(3))) void*)dst, 16, 0, 0);
    __builtin_amdgcn_global_load_lds(
        (const __attribute__((address_space(1))) void*)(src + 64 * (long)lda),
        (__attribute__((address_space(3))) void*)(dst + 4096), 16, 0, 0);
  };

  // phase: stage -> [vmcnt(4)] -> barrier -> 12 ds_reads -> 32 MFMA
#define PH(slot, ks, WAITV, ...)                                                  \
  do {                                                                            \
    __VA_ARGS__;                                                                  \
    if (WAITV) asm volatile("s_waitcnt vmcnt(4)" ::: "memory");                   \
    __builtin_amdgcn_s_barrier();                                                 \
    const int ch = (((ks) * 4 + (lane >> 4)) ^ (lane & 7)) * 8;                   \
    f16x8 af[8], bfr[4];                                                          \
    _Pragma("unroll")                                                             \
    for (int mi = 0; mi < 8; ++mi)                                                \
      af[mi] = *(const f16x8*)&As[slot][(wm + mi * 16 + lr) * 64 + ch];           \
    _Pragma("unroll")                                                             \
    for (int n = 0; n < 4; ++n)                                                   \
      bfr[n] = *(const f16x8*)&Bs[slot][(wn + n * 16 + lr) * 64 + ch];            \
    __builtin_amdgcn_s_setprio(1);                                                \
    _Pragma("unroll")                                                             \
    for (int mi = 0; mi < 8; ++mi)                                                \
      _Pragma("unroll")                                                           \
      for (int n = 0; n < 4; ++n)                                                 \
        acc[mi][n] = __builtin_amdgcn_mfma_f32_16x16x32_f16(                      \
            af[mi], bfr[n], acc[mi][n], 0, 0, 0);                                 \
    __builtin_amdgcn_s_setprio(0);                                                \
  } while (0)

  // prologue: full tile 0 -> S0 (8 loads/thread outstanding)
  stageA(0, 0, 0); stageA(0, 0, 1); stageB(0, 0, 0); stageB(0, 0, 1);

  for (int i = 0; i < NI; ++i) {
    const int b = 2 * i + 1;
    const int c = (2 * i + 2 < NT) ? 2 * i + 2 : 0;   // tail: harmless re-stage
    PH(0, 0, 1, stageA(b, 1, 0); stageA(b, 1, 1));
    PH(0, 1, 0, stageB(b, 1, 0); stageB(b, 1, 1));
    PH(1, 0, 1, stageA(c, 0, 0); stageA(c, 0, 1));
    PH(1, 1, 0, stageB(c, 0, 0); stageB(c, 0, 1));
  }
  asm volatile("s_waitcnt vmcnt(0)" ::: "memory");

#undef PH

  // epilogue: C/D layout col=lane&15, row=(lane>>4)*4+reg
  const int crow0 = bm * 256 + wm + (lane >> 4) * 4;
  const int ccol0 = bn * 256 + wn + lr;
#pragma unroll
  for (int n = 0; n < 4; n++) {
    const int col = ccol0 + n * 16;
    const float bv = bias[col];
#pragma unroll
    for (int m = 0; m < 8; m++) {
#pragma unroll
      for (int r = 0; r < 4; r++) {
        float v = acc[m][n][r] + bv;
        const long row = crow0 + m * 16 + r;
        if (EPI == 0) {
          v = (v >= 0.f) ? v : 0.01f * v;
          _Float16 hi, lo; split_f16(v, hi, lo);
          _Float16* C = (_Float16*)Cout;
          C[row * (long)(2 * N) + col]     = hi;
          C[row * (long)(2 * N) + N + col] = lo;
        } else {
          ((float*)Cout)[row * (long)N + col] = v;
        }
      }
    }
  }
}

// ---------------- 128² 4-phase split-f16 GEMM — R9 discipline, 2 blocks/CU ----------------
// (R14-verified, absmax 0.0039.) 256 thr = 4 waves (2x2), per-wave 64x64 out,
// BK=64, 2 LDS slots = 64KB -> 2 blocks/CU. Per-round wall ~69us (R14: 277us =
// 4 co-resident rounds). Used for L4 (N=256): 512 blocks = 1 round — fixes the
// gemm256-L4 under-grid (128 blocks on 256 CUs, ~125us for 1/4 the FLOPs).
template<int EPI>
__global__ __launch_bounds__(256, 2)
void gemm128p(const _Float16* __restrict__ Ag, const _Float16* __restrict__ Bt,
              const float* __restrict__ bias, void* __restrict__ Cout,
              int M, int N, int Kp)
{
  __shared__ __align__(16) _Float16 As[2][128 * 64];
  __shared__ __align__(16) _Float16 Bs[2][128 * 64];
  const int lda = 2 * Kp;
  const int T  = Kp >> 6;
  const int NT = 3 * T;
  const int NI = NT >> 1;
  const int tiles_n = N >> 7;
  const int cpx  = gridDim.x >> 3;
  const int virt = (blockIdx.x & 7) * cpx + (blockIdx.x >> 3);
  const int bm = virt / tiles_n;
  const int bn = virt % tiles_n;
  const int tid  = threadIdx.x;
  const int wave = tid >> 6;
  const int lane = tid & 63;

  const long abase = (long)bm * 128;
  const long bbase = (long)bn * 128;
  const int wm = (wave >> 1) * 64;
  const int wn = (wave & 1) * 64;
  const int lr = lane & 15;

  f32x4 acc[4][4] = {};

  auto stageA = [&](int t, int s) {
    const int ph = t / T, u = t - ph * T;
    const long ko = ((ph == 2) ? (long)Kp : 0) + u * 64;
#pragma unroll
    for (int L = 0; L < 4; ++L) {
      const int idx = tid + L * 256;
      const int row = idx >> 3, ck = idx & 7;
      const _Float16* src = Ag + (abase + row) * (long)lda + ko + (ck ^ (row & 7)) * 8;
      __builtin_amdgcn_global_load_lds(
          (const __attribute__((address_space(1))) void*)src,
          (__attribute__((address_space(3))) void*)&As[s][idx * 8], 16, 0, 0);
    }
  };
  auto stageB = [&](int t, int s) {
    const int ph = t / T, u = t - ph * T;
    const long ko = ((ph == 1) ? (long)Kp : 0) + u * 64;
#pragma unroll
    for (int L = 0; L < 4; ++L) {
      const int idx = tid + L * 256;
      const int row = idx >> 3, ck = idx & 7;
      const _Float16* src = Bt + (bbase + row) * (long)lda + ko + (ck ^ (row & 7)) * 8;
      __builtin_amdgcn_global_load_lds(
          (const __attribute__((address_space(1))) void*)src,
          (__attribute__((address_space(3))) void*)&Bs[s][idx * 8], 16, 0, 0);
    }
  };

  // phase: stage(4) -> [vmcnt(4)] -> barrier -> 8 ds_reads -> 16 MFMA
#define PH(slot, ks, WAITV, ...)                                                  \
  do {                                                                            \
    __VA_ARGS__;                                                                  \
    if (WAITV) asm volatile("s_waitcnt vmcnt(4)" ::: "memory");                   \
    __builtin_amdgcn_s_barrier();                                                 \
    const int ch = (((ks) * 4 + (lane >> 4)) ^ (lane & 7)) * 8;                   \
    f16x8 af[4], bfr[4];                                                          \
    _Pragma("unroll")                                                             \
    for (int mi = 0; mi < 4; ++mi)                                                \
      af[mi] = *(const f16x8*)&As[slot][(wm + mi * 16 + lr) * 64 + ch];           \
    _Pragma("unroll")                                                             \
    for (int n = 0; n < 4; ++n)                                                   \
      bfr[n] = *(const f16x8*)&Bs[slot][(wn + n * 16 + lr) * 64 + ch];            \
    __builtin_amdgcn_s_setprio(1);                                                \
    _Pragma("unroll")                                                             \
    for (int mi = 0; mi < 4; ++mi)                                                \
      _Pragma("unroll")                                                           \
      for (int n = 0; n < 4; ++n)                                                 \
        acc[mi][n] = __builtin_amdgcn_mfma_f32_16x16x32_f16(                      \
            af[mi], bfr[n], acc[mi][n], 0, 0, 0);                                 \
    __builtin_amdgcn_s_setprio(0);                                                \
  } while (0)

  // prologue: tile 0 -> S0 (8 loads/thread outstanding)
  stageA(0, 0); stageB(0, 0);

  for (int i = 0; i < NI; ++i) {
    const int b = 2 * i + 1;
    const int c = (2 * i + 2 < NT) ? 2 * i + 2 : 0;   // tail: harmless re-stage
    PH(0, 0, 1, stageA(b, 1));
    PH(0, 1, 0, stageB(b, 1));
    PH(1, 0, 1, stageA(c, 0));
    PH(1, 1, 0, stageB(c, 0));
  }
  asm volatile("s_waitcnt vmcnt(0)" ::: "memory");

#undef PH

  // epilogue: C/D layout col=lane&15, row=(lane>>4)*4+reg
  const int crow0 = bm * 128 + wm + (lane >> 4) * 4;
  const int ccol0 = bn * 128 + wn + lr;
#pragma unroll
  for (int n = 0; n < 4; n++) {
    const int col = ccol0 + n * 16;
    const float bv = bias[col];
#pragma unroll
    for (int m = 0; m < 4; m++) {
#pragma unroll
      for (int r = 0; r < 4; r++) {
        float v = acc[m][n][r] + bv;
        const long row = crow0 + m * 16 + r;
        if (EPI == 0) {
          v = (v >= 0.f) ? v : 0.01f * v;
          _Float16 hi, lo; split_f16(v, hi, lo);
          _Float16* C = (_Float16*)Cout;
          C[row * (long)(2 * N) + col]     = hi;
          C[row * (long)(2 * N) + N + col] = lo;
        } else {
          ((float*)Cout)[row * (long)N + col] = v;
        }
      }
    }
  }
}

// ---------------- fused quat->rotmat + forward kinematics ----------------
struct FkParams { int par[JN]; unsigned long long childmask; };

__global__ __launch_bounds__(256)
void quat_fk_kernel(const float* __restrict__ q, const float* __restrict__ offs,
                    float* __restrict__ rot, float* __restrict__ Gt,
                    float* __restrict__ pose, FkParams P)
{
  __shared__ float qs[256][65];                 // 66,560 B
  const int tid = threadIdx.x;
  const int s0  = blockIdx.x * 256;
  const int s   = s0 + tid;

  float G[12];

  for (int c = 0; c < 4; ++c) {
    __syncthreads();                            // prev chunk fully consumed
    for (int idx = tid; idx < 256 * 64; idx += 256) {
      const int r = idx >> 6, col = idx & 63;
      qs[r][col] = q[(long)(s0 + r) * QSTR + c * 64 + col];
    }
    __syncthreads();
    const int jlo = c * 16;
    const int jhi = (c == 3) ? JN : jlo + 16;
    for (int j = jlo; j < jhi; ++j) {
      const int cb = j * 4 - c * 64;
      float qw = qs[tid][cb + 0], qx = qs[tid][cb + 1];
      float qy = qs[tid][cb + 2], qz = qs[tid][cb + 3];
      float n = sqrtf(qw * qw + qx * qx + qy * qy + qz * qz);
      n = fmaxf(n, 1e-8f);
      const float inv = 1.f / n;
      qw *= inv; qx *= inv; qy *= inv; qz *= inv;
      const float xx = qx * qx, yy = qy * qy, zz = qz * qz;
      const float xy = qx * qy, xz = qx * qz, yz = qy * qz;
      const float xw = qx * qw, yw = qy * qw, zw = qz * qw;
      float L[12];
      L[0] = 1.f - 2.f * (yy + zz); L[1] = 2.f * (xy - zw); L[2]  = 2.f * (xz + yw);
      L[4] = 2.f * (xy + zw); L[5] = 1.f - 2.f * (xx + zz); L[6]  = 2.f * (yz - xw);
      L[8] = 2.f * (xz - yw); L[9] = 2.f * (yz + xw); L[10] = 1.f - 2.f * (xx + yy);

      float4* ro = (float4*)(rot + ((long)s * JN + j) * 16);
      ro[0] = make_float4(L[0], L[1], L[2],  0.f);
      ro[1] = make_float4(L[4], L[5], L[6],  0.f);
      ro[2] = make_float4(L[8], L[9], L[10], 0.f);
      ro[3] = make_float4(0.f, 0.f, 0.f, 1.f);

      L[3]  = offs[j * 3 + 0];
      L[7]  = offs[j * 3 + 1];
      L[11] = offs[j * 3 + 2];

      if (j == 0) {
#pragma unroll
        for (int e = 0; e < 12; e++) G[e] = L[e];
      } else {
        const int p = P.par[j];                 // scalar -> uniform branch
        float Pm[12];
        if (p == j - 1) {
#pragma unroll
          for (int e = 0; e < 12; e++) Pm[e] = G[e];
        } else {
#pragma unroll
          for (int e = 0; e < 12; e++) Pm[e] = Gt[((long)p * 12 + e) * B_ + s];
        }
#pragma unroll
        for (int r = 0; r < 3; r++) {
#pragma unroll
          for (int cc = 0; cc < 4; cc++) {
            float v = Pm[r * 4 + 0] * L[0 * 4 + cc] + Pm[r * 4 + 1] * L[1 * 4 + cc]
                    + Pm[r * 4 + 2] * L[2 * 4 + cc];
            if (cc == 3) v += Pm[r * 4 + 3];
            G[r * 4 + cc] = v;
          }
        }
      }
      if ((P.childmask >> j) & 1ull) {
#pragma unroll
        for (int e = 0; e < 12; e++) Gt[((long)j * 12 + e) * B_ + s] = G[e];
      }
      pose[(long)s * (JN * 3) + j * 3 + 0] = G[3];
      pose[(long)s * (JN * 3) + j * 3 + 1] = G[7];
      pose[(long)s * (JN * 3) + j * 3 + 2] = G[11];
    }
  }
}

// ---------------- host: replicate np.random.default_rng(7) parents ----------------
static void compute_parents(int* par, unsigned long long* childmask)
{
  uint32_t pool[4];
  uint32_t hc = 0x43b0d7e5u;                       // INIT_A
  auto hashmix = [&hc](uint32_t v) {
    v ^= hc; hc *= 0x931e8875u; v *= hc; v ^= v >> 16; return v;
  };
  auto mix = [](uint32_t x, uint32_t y) {
    uint32_t r = 0xca01f9ddu * x - 0x4973f715u * y;
    r ^= r >> 16;
    return r;
  };
  const uint32_t entropy[1] = {7u};
  for (int i = 0; i < 4; i++) pool[i] = hashmix(i < 1 ? entropy[i] : 0u);
  for (int si = 0; si < 4; si++)
    for (int di = 0; di < 4; di++)
      if (si != di) pool[di] = mix(pool[di], hashmix(pool[si]));
  uint32_t gs[8];
  uint32_t hb = 0x8b51f9ddu;                       // INIT_B
  for (int i = 0; i < 8; i++) {
    uint32_t dv = pool[i & 3];
    dv ^= hb; hb *= 0x58f38dedu; dv *= hb; dv ^= dv >> 16;
    gs[i] = dv;
  }
  uint64_t sw0 = (uint64_t)gs[0] | ((uint64_t)gs[1] << 32);
  uint64_t sw1 = (uint64_t)gs[2] | ((uint64_t)gs[3] << 32);
  uint64_t iw0 = (uint64_t)gs[4] | ((uint64_t)gs[5] << 32);
  uint64_t iw1 = (uint64_t)gs[6] | ((uint64_t)gs[7] << 32);
  const __uint128_t MULT = (((__uint128_t)0x2360ed051fc65da4ULL) << 64) | 0x4385df649fccf645ULL;
  __uint128_t inc = ((((__uint128_t)iw0 << 64) | iw1) << 1) | 1;
  __uint128_t state = 0;
  state = state * MULT + inc;
  state += (((__uint128_t)sw0) << 64) | sw1;
  state = state * MULT + inc;
  bool has32 = false; uint32_t buf32 = 0;
  auto next64 = [&]() {
    state = state * MULT + inc;
    uint64_t hi = (uint64_t)(state >> 64), lo = (uint64_t)state;
    uint32_t rot = (uint32_t)(state >> 122);
    uint64_t x = hi ^ lo;
    return (x >> rot) | (x << ((64u - rot) & 63u));
  };
  auto next32 = [&]() -> uint32_t {
    if (has32) { has32 = false; return buf32; }
    uint64_t v = next64();
    has32 = true; buf32 = (uint32_t)(v >> 32);
    return (uint32_t)v;
  };
  par[0] = -1;
  for (int j = 1; j < JN; j++) {
    uint32_t rng = (uint32_t)(j - 1);
    if (rng == 0) { par[j] = 0; continue; }
    uint32_t rng_excl = rng + 1;
    uint64_t m = (uint64_t)next32() * (uint64_t)rng_excl;
    uint32_t leftover = (uint32_t)m;
    if (leftover < rng_excl) {
      uint32_t threshold = (uint32_t)((0x100000000ULL - rng_excl) % rng_excl);
      while (leftover < threshold) {
        m = (uint64_t)next32() * (uint64_t)rng_excl;
        leftover = (uint32_t)m;
      }
    }
    par[j] = (int)(m >> 32);
  }
  unsigned long long cm = 0;
  for (int j = 1; j < JN; j++) cm |= 1ull << par[j];
  *childmask = cm;
}

// ---------------- launch ----------------
extern "C" void kernel_launch(void* const* d_in, const int* in_sizes, int n_in,
                              void* d_out, int out_size, void* d_ws, size_t ws_size,
                              hipStream_t stream)
{
  const float* in_seq = (const float*)d_in[0];
  const float* w1 = (const float*)d_in[1];
  const float* b1 = (const float*)d_in[2];
  const float* w2 = (const float*)d_in[3];
  const float* b2 = (const float*)d_in[4];
  const float* w3 = (const float*)d_in[5];
  const float* b3 = (const float*)d_in[6];
  const float* w4 = (const float*)d_in[7];
  const float* b4 = (const float*)d_in[8];
  const float* offs = (const float*)d_in[9];

  char* pR1 = (char*)d_ws;
  char* pR2 = pR1 + 35390464;
  char* pR3 = pR2 + 134217728;
  _Float16* x2  = (_Float16*)pR1;
  _Float16* w1f = (_Float16*)(pR1 + 25165824);
  _Float16* w2f = (_Float16*)(pR1 + 25165824 + 786432);
  _Float16* w3f = (_Float16*)(pR1 + 25165824 + 786432 + 4194304);
  _Float16* w4f = (_Float16*)(pR1 + 25165824 + 786432 + 2 * 4194304);
  float*    b4p = (float*)(pR1 + 25165824 + 786432 + 2 * 4194304 + 1048576);
  float*    q   = (float*)pR1;            // overwrites x2/w1f/w2f/w3f only
  _Float16* h1  = (_Float16*)pR2;
  _Float16* h3  = (_Float16*)pR2;
  float*    Gt  = (float*)pR2;            // h1/h3 dead after L4
  _Float16* h2  = (_Float16*)pR3;

  float* pose = (float*)d_out;                        // [B_,57,3]
  float* rot  = (float*)d_out + (long)B_ * JN * 3;    // [B_,57,4,4]

  // prep
  prep_x2_kernel<<<(B_ * 192) / 256, 256, 0, stream>>>(in_seq, x2);
  prep_w2_kernel<<<(1024 * 192) / 256, 256, 0, stream>>>(w1, w1f, 171, 192, 1024);
  prep_w2_kernel<<<(1024 * 1024) / 256, 256, 0, stream>>>(w2, w2f, 1024, 1024, 1024);
  prep_w2_kernel<<<(1024 * 1024) / 256, 256, 0, stream>>>(w3, w3f, 1024, 1024, 1024);
  prep_w2_kernel<<<(256 * 1024) / 256, 256, 0, stream>>>(w4, w4f, 1024, 1024, 228);
  prep_b4_kernel<<<1, 256, 0, stream>>>(b4, b4p);

  // MLP (split-f16, virtual 3K)
  gemm_hl<0><<<(B_ / 128) * (1024 / 128), 256, 0, stream>>>(x2, w1f, b1, h1, B_, 1024, 192);
  gemm256<0><<<(B_ / 256) * (1024 / 256), 512, 0, stream>>>(h1, w2f, b2, h2, B_, 1024, 1024);
  gemm256<0><<<(B_ / 256) * (1024 / 256), 512, 0, stream>>>(h2, w3f, b3, h3, B_, 1024, 1024);
  gemm128p<1><<<(B_ / 128) * (QSTR / 128), 256, 0, stream>>>(h3, w4f, b4p, q, B_, QSTR, 1024);

  // fused epilogue (quat->rot + FK), no Lf round-trip
  FkParams P;
  compute_parents(P.par, &P.childmask);
  quat_fk_kernel<<<B_ / 256, 256, 0, stream>>>(q, offs, rot, Gt, pose, P);
}

// Round 18
// 635.316 us; speedup vs baseline: 1.3089x; 1.1523x over previous
//
#include <hip/hip_runtime.h>
#include <hip/hip_bf16.h>
#include <stdint.h>

#define B_   32768
#define JN   57
#define QSTR 256      // q row stride (228 padded to 256)

typedef _Float16 f16x8 __attribute__((ext_vector_type(8)));
typedef float    f32x4 __attribute__((ext_vector_type(4)));

__device__ __forceinline__ void split_f16(float v, _Float16& hi, _Float16& lo) {
  hi = (_Float16)v;
  lo = (_Float16)(v - (float)hi);
}

// ---------------- prep kernels ----------------
__global__ void prep_x2_kernel(const float* __restrict__ x, _Float16* __restrict__ xp) {
  long i = (long)blockIdx.x * 256 + threadIdx.x;   // over B_*192
  int row = (int)(i / 192), col = (int)(i % 192);
  float v = (col < 171) ? x[(long)row * 171 + col] : 0.f;
  _Float16 hi, lo; split_f16(v, hi, lo);
  xp[(long)row * 384 + col]       = hi;
  xp[(long)row * 384 + 192 + col] = lo;
}

__global__ void prep_w2_kernel(const float* __restrict__ w, _Float16* __restrict__ wf,
                               int Ksrc, int Kpad, int Nsrc) {
  long i = (long)blockIdx.x * 256 + threadIdx.x;   // over Ndst*Kpad
  int n = (int)(i / Kpad), k = (int)(i % Kpad);
  float v = (k < Ksrc && n < Nsrc) ? w[(long)k * Nsrc + n] : 0.f;
  _Float16 hi, lo; split_f16(v, hi, lo);
  wf[(long)n * (2 * Kpad) + k]        = hi;
  wf[(long)n * (2 * Kpad) + Kpad + k] = lo;
}

__global__ void prep_b4_kernel(const float* __restrict__ b, float* __restrict__ bp) {
  int i = threadIdx.x;  // 256 threads
  bp[i] = (i < 228) ? b[i] : 0.f;
}

// ---------------- 128² split-f16 GEMM (m97 structure) — layer 1 only ----------------
template<int EPI>
__global__ __launch_bounds__(256)
void gemm_hl(const _Float16* __restrict__ A, const _Float16* __restrict__ Bt,
             const float* __restrict__ bias, void* __restrict__ Cout,
             int M, int N, int Kp)
{
  __shared__ __align__(16) _Float16 As[128 * 64];
  __shared__ __align__(16) _Float16 Bs[128 * 64];
  const int lda = 2 * Kp;
  const int T = Kp >> 6;
  const int tiles_n = N >> 7;
  const int cpx  = gridDim.x >> 3;
  const int virt = (blockIdx.x & 7) * cpx + (blockIdx.x >> 3);
  const int bm = virt / tiles_n;
  const int bn = virt % tiles_n;
  const int tid  = threadIdx.x;
  const int wave = tid >> 6;
  const int lane = tid & 63;

  const int srow = wave * 8 + (lane >> 3);
  const int scol = (((lane & 7) ^ (lane >> 3)) * 8);
  const long abase = (long)bm * 128;
  const long bbase = (long)bn * 128;

  f32x4 acc[4][4] = {};

  const int wm = (wave >> 1) * 64;
  const int wn = (wave & 1) * 64;
  const int lr = lane & 15;
  const int ch0 = (((lane >> 4) ^ (lane & 7)) * 8);
  const int ch1 = (((4 + (lane >> 4)) ^ (lane & 7)) * 8);

  for (int ph = 0; ph < 3; ++ph) {
    const int aoff = (ph == 2) ? Kp : 0;
    const int boff = (ph == 1) ? Kp : 0;
    for (int u = 0; u < T; ++u) {
#pragma unroll
      for (int i = 0; i < 4; i++) {
        const _Float16* asrc = A  + (abase + i * 32 + srow) * (long)lda + (aoff + u * 64 + scol);
        const _Float16* bsrc = Bt + (bbase + i * 32 + srow) * (long)lda + (boff + u * 64 + scol);
        __builtin_amdgcn_global_load_lds(
            (const __attribute__((address_space(1))) void*)asrc,
            (__attribute__((address_space(3))) void*)(As + (i * 256 + wave * 64) * 8),
            16, 0, 0);
        __builtin_amdgcn_global_load_lds(
            (const __attribute__((address_space(1))) void*)bsrc,
            (__attribute__((address_space(3))) void*)(Bs + (i * 256 + wave * 64) * 8),
            16, 0, 0);
      }
      __syncthreads();

#pragma unroll
      for (int ks = 0; ks < 2; ks++) {
        const int ch = ks ? ch1 : ch0;
        f16x8 af[4], bfr[4];
#pragma unroll
        for (int m = 0; m < 4; m++)
          af[m] = *(const f16x8*)(As + (wm + m * 16 + lr) * 64 + ch);
#pragma unroll
        for (int n = 0; n < 4; n++)
          bfr[n] = *(const f16x8*)(Bs + (wn + n * 16 + lr) * 64 + ch);
#pragma unroll
        for (int m = 0; m < 4; m++)
#pragma unroll
          for (int n = 0; n < 4; n++)
            acc[m][n] = __builtin_amdgcn_mfma_f32_16x16x32_f16(af[m], bfr[n], acc[m][n], 0, 0, 0);
      }
      __syncthreads();
    }
  }

  const int crow0 = bm * 128 + wm + (lane >> 4) * 4;
  const int ccol0 = bn * 128 + wn + lr;
#pragma unroll
  for (int n = 0; n < 4; n++) {
    const int col = ccol0 + n * 16;
    const float bv = bias[col];
#pragma unroll
    for (int m = 0; m < 4; m++) {
#pragma unroll
      for (int r = 0; r < 4; r++) {
        float v = acc[m][n][r] + bv;
        const long row = crow0 + m * 16 + r;
        if (EPI == 0) {
          v = (v >= 0.f) ? v : 0.01f * v;
          _Float16 hi, lo; split_f16(v, hi, lo);
          _Float16* C = (_Float16*)Cout;
          C[row * (long)(2 * N) + col]     = hi;
          C[row * (long)(2 * N) + N + col] = lo;
        } else {
          ((float*)Cout)[row * (long)N + col] = v;
        }
      }
    }
  }
}

// ---------------- 256² 4-phase split-f16 GEMM — B-dedup schedule (best measured) ----------------
// 512 thr = 8 waves (2M x 4N), per-wave 128x64 out. BK=64, 2 LDS slots (128KB).
// acc[8][4] f32x4 = 128 AGPRs/lane -> REQUIRES the 256-reg budget of
// __launch_bounds__(512,2); min-waves=4 spills the accumulator (R11). Do not raise.
// PLANES: 3 = full split (AhBh+AhBl+AlBh); 2 drops AlBh -> activations are
// effectively plain-f16 (2^-12), weights stay split-exact. Used for hidden
// layers L2/L3 where the propagated error (~1e-4 sigma in q) fits the margin.
template<int EPI, int PLANES>
__global__ __launch_bounds__(512, 2)
void gemm256(const _Float16* __restrict__ Ag, const _Float16* __restrict__ Bt,
             const float* __restrict__ bias, void* __restrict__ Cout,
             int M, int N, int Kp)
{
  __shared__ __align__(16) _Float16 As[2][256 * 64];
  __shared__ __align__(16) _Float16 Bs[2][256 * 64];
  const int lda = 2 * Kp;
  const int T  = Kp >> 6;
  const int NT = PLANES * T;
  const int NI = NT >> 1;
  const int tiles_n = N >> 8;
  const int cpx  = gridDim.x >> 3;
  const int virt = (blockIdx.x & 7) * cpx + (blockIdx.x >> 3);
  const int bm = virt / tiles_n;
  const int bn = virt % tiles_n;
  const int tid  = threadIdx.x;
  const int wid  = tid >> 6;
  const int lane = tid & 63;

  const long abase = (long)bm * 256;
  const long bbase = (long)bn * 256;
  const int scol = (((lane & 7) ^ ((tid >> 3) & 7)) * 8);

  const int wm = (wid >> 2) * 128;
  const int wn = (wid & 3) * 64;
  const int lr = lane & 15;

  f32x4 acc[8][4] = {};

  auto stageA = [&](int t, int s, int h) {
    const int ph = t / T, u = t - ph * T;
    const long ko = ((ph == 2) ? (long)Kp : 0) + u * 64 + scol;
    const _Float16* src = Ag + (abase + h * 128 + (tid >> 3)) * (long)lda + ko;
    const _Float16* dst = &As[s][h * 8192 + tid * 8];
    __builtin_amdgcn_global_load_lds(
        (const __attribute__((address_space(1))) void*)src,
        (__attribute__((address_space(3))) void*)dst, 16, 0, 0);
    __builtin_amdgcn_global_load_lds(
        (const __attribute__((address_space(1))) void*)(src + 64 * (long)lda),
        (__attribute__((address_space(3))) void*)(dst + 4096), 16, 0, 0);
  };
  auto stageB = [&](int t, int s, int h) {
    const int ph = t / T, u = t - ph * T;
    const long ko = ((ph == 1) ? (long)Kp : 0) + u * 64 + scol;
    const _Float16* src = Bt + (bbase + h * 128 + (tid >> 3)) * (long)lda + ko;
    const _Float16* dst = &Bs[s][h * 8192 + tid * 8];
    __builtin_amdgcn_global_load_lds(
        (const __attribute__((address_space(1))) void*)src,
        (__attribute__((address_space(3))) void*)dst, 16, 0, 0);
    __builtin_amdgcn_global_load_lds(
        (const __attribute__((address_space(1))) void*)(src + 64 * (long)lda),
        (__attribute__((address_space(3))) void*)(dst + 4096), 16, 0, 0);
  };

  // phase: stage -> [vmcnt(4)] -> barrier -> 12 ds_reads -> 32 MFMA
#define PH(slot, ks, WAITV, ...)                                                  \
  do {                                                                            \
    __VA_ARGS__;                                                                  \
    if (WAITV) asm volatile("s_waitcnt vmcnt(4)" ::: "memory");                   \
    __builtin_amdgcn_s_barrier();                                                 \
    const int ch = (((ks) * 4 + (lane >> 4)) ^ (lane & 7)) * 8;                   \
    f16x8 af[8], bfr[4];                                                          \
    _Pragma("unroll")                                                             \
    for (int mi = 0; mi < 8; ++mi)                                                \
      af[mi] = *(const f16x8*)&As[slot][(wm + mi * 16 + lr) * 64 + ch];           \
    _Pragma("unroll")                                                             \
    for (int n = 0; n < 4; ++n)                                                   \
      bfr[n] = *(const f16x8*)&Bs[slot][(wn + n * 16 + lr) * 64 + ch];            \
    __builtin_amdgcn_s_setprio(1);                                                \
    _Pragma("unroll")                                                             \
    for (int mi = 0; mi < 8; ++mi)                                                \
      _Pragma("unroll")                                                           \
      for (int n = 0; n < 4; ++n)                                                 \
        acc[mi][n] = __builtin_amdgcn_mfma_f32_16x16x32_f16(                      \
            af[mi], bfr[n], acc[mi][n], 0, 0, 0);                                 \
    __builtin_amdgcn_s_setprio(0);                                                \
  } while (0)

  // prologue: full tile 0 -> S0 (8 loads/thread outstanding)
  stageA(0, 0, 0); stageA(0, 0, 1); stageB(0, 0, 0); stageB(0, 0, 1);

  for (int i = 0; i < NI; ++i) {
    const int b = 2 * i + 1;
    const int c = (2 * i + 2 < NT) ? 2 * i + 2 : 0;   // tail: harmless re-stage
    PH(0, 0, 1, stageA(b, 1, 0); stageA(b, 1, 1));
    PH(0, 1, 0, stageB(b, 1, 0); stageB(b, 1, 1));
    PH(1, 0, 1, stageA(c, 0, 0); stageA(c, 0, 1));
    PH(1, 1, 0, stageB(c, 0, 0); stageB(c, 0, 1));
  }
  asm volatile("s_waitcnt vmcnt(0)" ::: "memory");

#undef PH

  // epilogue: C/D layout col=lane&15, row=(lane>>4)*4+reg
  const int crow0 = bm * 256 + wm + (lane >> 4) * 4;
  const int ccol0 = bn * 256 + wn + lr;
#pragma unroll
  for (int n = 0; n < 4; n++) {
    const int col = ccol0 + n * 16;
    const float bv = bias[col];
#pragma unroll
    for (int m = 0; m < 8; m++) {
#pragma unroll
      for (int r = 0; r < 4; r++) {
        float v = acc[m][n][r] + bv;
        const long row = crow0 + m * 16 + r;
        if (EPI == 0) {
          v = (v >= 0.f) ? v : 0.01f * v;
          _Float16 hi, lo; split_f16(v, hi, lo);
          _Float16* C = (_Float16*)Cout;
          C[row * (long)(2 * N) + col]     = hi;
          C[row * (long)(2 * N) + N + col] = lo;
        } else {
          ((float*)Cout)[row * (long)N + col] = v;
        }
      }
    }
  }
}

// ---------------- 128² 4-phase split-f16 GEMM — R9 discipline, 2 blocks/CU ----------------
// (R14-verified.) Used for L4 (N=256): 512 blocks = 1 co-resident round.
// Kept at full 3 planes: L4's output q is directly normalized (worst-quat
// amplification ~60x) — precision budget reserved here.
template<int EPI>
__global__ __launch_bounds__(256, 2)
void gemm128p(const _Float16* __restrict__ Ag, const _Float16* __restrict__ Bt,
              const float* __restrict__ bias, void* __restrict__ Cout,
              int M, int N, int Kp)
{
  __shared__ __align__(16) _Float16 As[2][128 * 64];
  __shared__ __align__(16) _Float16 Bs[2][128 * 64];
  const int lda = 2 * Kp;
  const int T  = Kp >> 6;
  const int NT = 3 * T;
  const int NI = NT >> 1;
  const int tiles_n = N >> 7;
  const int cpx  = gridDim.x >> 3;
  const int virt = (blockIdx.x & 7) * cpx + (blockIdx.x >> 3);
  const int bm = virt / tiles_n;
  const int bn = virt % tiles_n;
  const int tid  = threadIdx.x;
  const int wave = tid >> 6;
  const int lane = tid & 63;

  const long abase = (long)bm * 128;
  const long bbase = (long)bn * 128;
  const int wm = (wave >> 1) * 64;
  const int wn = (wave & 1) * 64;
  const int lr = lane & 15;

  f32x4 acc[4][4] = {};

  auto stageA = [&](int t, int s) {
    const int ph = t / T, u = t - ph * T;
    const long ko = ((ph == 2) ? (long)Kp : 0) + u * 64;
#pragma unroll
    for (int L = 0; L < 4; ++L) {
      const int idx = tid + L * 256;
      const int row = idx >> 3, ck = idx & 7;
      const _Float16* src = Ag + (abase + row) * (long)lda + ko + (ck ^ (row & 7)) * 8;
      __builtin_amdgcn_global_load_lds(
          (const __attribute__((address_space(1))) void*)src,
          (__attribute__((address_space(3))) void*)&As[s][idx * 8], 16, 0, 0);
    }
  };
  auto stageB = [&](int t, int s) {
    const int ph = t / T, u = t - ph * T;
    const long ko = ((ph == 1) ? (long)Kp : 0) + u * 64;
#pragma unroll
    for (int L = 0; L < 4; ++L) {
      const int idx = tid + L * 256;
      const int row = idx >> 3, ck = idx & 7;
      const _Float16* src = Bt + (bbase + row) * (long)lda + ko + (ck ^ (row & 7)) * 8;
      __builtin_amdgcn_global_load_lds(
          (const __attribute__((address_space(1))) void*)src,
          (__attribute__((address_space(3))) void*)&Bs[s][idx * 8], 16, 0, 0);
    }
  };

  // phase: stage(4) -> [vmcnt(4)] -> barrier -> 8 ds_reads -> 16 MFMA
#define PH(slot, ks, WAITV, ...)                                                  \
  do {                                                                            \
    __VA_ARGS__;                                                                  \
    if (WAITV) asm volatile("s_waitcnt vmcnt(4)" ::: "memory");                   \
    __builtin_amdgcn_s_barrier();                                                 \
    const int ch = (((ks) * 4 + (lane >> 4)) ^ (lane & 7)) * 8;                   \
    f16x8 af[4], bfr[4];                                                          \
    _Pragma("unroll")                                                             \
    for (int mi = 0; mi < 4; ++mi)                                                \
      af[mi] = *(const f16x8*)&As[slot][(wm + mi * 16 + lr) * 64 + ch];           \
    _Pragma("unroll")                                                             \
    for (int n = 0; n < 4; ++n)                                                   \
      bfr[n] = *(const f16x8*)&Bs[slot][(wn + n * 16 + lr) * 64 + ch];            \
    __builtin_amdgcn_s_setprio(1);                                                \
    _Pragma("unroll")                                                             \
    for (int mi = 0; mi < 4; ++mi)                                                \
      _Pragma("unroll")                                                           \
      for (int n = 0; n < 4; ++n)                                                 \
        acc[mi][n] = __builtin_amdgcn_mfma_f32_16x16x32_f16(                      \
            af[mi], bfr[n], acc[mi][n], 0, 0, 0);                                 \
    __builtin_amdgcn_s_setprio(0);                                                \
  } while (0)

  // prologue: tile 0 -> S0 (8 loads/thread outstanding)
  stageA(0, 0); stageB(0, 0);

  for (int i = 0; i < NI; ++i) {
    const int b = 2 * i + 1;
    const int c = (2 * i + 2 < NT) ? 2 * i + 2 : 0;   // tail: harmless re-stage
    PH(0, 0, 1, stageA(b, 1));
    PH(0, 1, 0, stageB(b, 1));
    PH(1, 0, 1, stageA(c, 0));
    PH(1, 1, 0, stageB(c, 0));
  }
  asm volatile("s_waitcnt vmcnt(0)" ::: "memory");

#undef PH

  // epilogue: C/D layout col=lane&15, row=(lane>>4)*4+reg
  const int crow0 = bm * 128 + wm + (lane >> 4) * 4;
  const int ccol0 = bn * 128 + wn + lr;
#pragma unroll
  for (int n = 0; n < 4; n++) {
    const int col = ccol0 + n * 16;
    const float bv = bias[col];
#pragma unroll
    for (int m = 0; m < 4; m++) {
#pragma unroll
      for (int r = 0; r < 4; r++) {
        float v = acc[m][n][r] + bv;
        const long row = crow0 + m * 16 + r;
        if (EPI == 0) {
          v = (v >= 0.f) ? v : 0.01f * v;
          _Float16 hi, lo; split_f16(v, hi, lo);
          _Float16* C = (_Float16*)Cout;
          C[row * (long)(2 * N) + col]     = hi;
          C[row * (long)(2 * N) + N + col] = lo;
        } else {
          ((float*)Cout)[row * (long)N + col] = v;
        }
      }
    }
  }
}

// ---------------- fused quat->rotmat + forward kinematics ----------------
struct FkParams { int par[JN]; unsigned long long childmask; };

__global__ __launch_bounds__(256)
void quat_fk_kernel(const float* __restrict__ q, const float* __restrict__ offs,
                    float* __restrict__ rot, float* __restrict__ Gt,
                    float* __restrict__ pose, FkParams P)
{
  __shared__ float qs[256][65];                 // 66,560 B
  const int tid = threadIdx.x;
  const int s0  = blockIdx.x * 256;
  const int s   = s0 + tid;

  float G[12];

  for (int c = 0; c < 4; ++c) {
    __syncthreads();                            // prev chunk fully consumed
    for (int idx = tid; idx < 256 * 64; idx += 256) {
      const int r = idx >> 6, col = idx & 63;
      qs[r][col] = q[(long)(s0 + r) * QSTR + c * 64 + col];
    }
    __syncthreads();
    const int jlo = c * 16;
    const int jhi = (c == 3) ? JN : jlo + 16;
    for (int j = jlo; j < jhi; ++j) {
      const int cb = j * 4 - c * 64;
      float qw = qs[tid][cb + 0], qx = qs[tid][cb + 1];
      float qy = qs[tid][cb + 2], qz = qs[tid][cb + 3];
      float n = sqrtf(qw * qw + qx * qx + qy * qy + qz * qz);
      n = fmaxf(n, 1e-8f);
      const float inv = 1.f / n;
      qw *= inv; qx *= inv; qy *= inv; qz *= inv;
      const float xx = qx * qx, yy = qy * qy, zz = qz * qz;
      const float xy = qx * qy, xz = qx * qz, yz = qy * qz;
      const float xw = qx * qw, yw = qy * qw, zw = qz * qw;
      float L[12];
      L[0] = 1.f - 2.f * (yy + zz); L[1] = 2.f * (xy - zw); L[2]  = 2.f * (xz + yw);
      L[4] = 2.f * (xy + zw); L[5] = 1.f - 2.f * (xx + zz); L[6]  = 2.f * (yz - xw);
      L[8] = 2.f * (xz - yw); L[9] = 2.f * (yz + xw); L[10] = 1.f - 2.f * (xx + yy);

      float4* ro = (float4*)(rot + ((long)s * JN + j) * 16);
      ro[0] = make_float4(L[0], L[1], L[2],  0.f);
      ro[1] = make_float4(L[4], L[5], L[6],  0.f);
      ro[2] = make_float4(L[8], L[9], L[10], 0.f);
      ro[3] = make_float4(0.f, 0.f, 0.f, 1.f);

      L[3]  = offs[j * 3 + 0];
      L[7]  = offs[j * 3 + 1];
      L[11] = offs[j * 3 + 2];

      if (j == 0) {
#pragma unroll
        for (int e = 0; e < 12; e++) G[e] = L[e];
      } else {
        const int p = P.par[j];                 // scalar -> uniform branch
        float Pm[12];
        if (p == j - 1) {
#pragma unroll
          for (int e = 0; e < 12; e++) Pm[e] = G[e];
        } else {
#pragma unroll
          for (int e = 0; e < 12; e++) Pm[e] = Gt[((long)p * 12 + e) * B_ + s];
        }
#pragma unroll
        for (int r = 0; r < 3; r++) {
#pragma unroll
          for (int cc = 0; cc < 4; cc++) {
            float v = Pm[r * 4 + 0] * L[0 * 4 + cc] + Pm[r * 4 + 1] * L[1 * 4 + cc]
                    + Pm[r * 4 + 2] * L[2 * 4 + cc];
            if (cc == 3) v += Pm[r * 4 + 3];
            G[r * 4 + cc] = v;
          }
        }
      }
      if ((P.childmask >> j) & 1ull) {
#pragma unroll
        for (int e = 0; e < 12; e++) Gt[((long)j * 12 + e) * B_ + s] = G[e];
      }
      pose[(long)s * (JN * 3) + j * 3 + 0] = G[3];
      pose[(long)s * (JN * 3) + j * 3 + 1] = G[7];
      pose[(long)s * (JN * 3) + j * 3 + 2] = G[11];
    }
  }
}

// ---------------- host: replicate np.random.default_rng(7) parents ----------------
static void compute_parents(int* par, unsigned long long* childmask)
{
  uint32_t pool[4];
  uint32_t hc = 0x43b0d7e5u;                       // INIT_A
  auto hashmix = [&hc](uint32_t v) {
    v ^= hc; hc *= 0x931e8875u; v *= hc; v ^= v >> 16; return v;
  };
  auto mix = [](uint32_t x, uint32_t y) {
    uint32_t r = 0xca01f9ddu * x - 0x4973f715u * y;
    r ^= r >> 16;
    return r;
  };
  const uint32_t entropy[1] = {7u};
  for (int i = 0; i < 4; i++) pool[i] = hashmix(i < 1 ? entropy[i] : 0u);
  for (int si = 0; si < 4; si++)
    for (int di = 0; di < 4; di++)
      if (si != di) pool[di] = mix(pool[di], hashmix(pool[si]));
  uint32_t gs[8];
  uint32_t hb = 0x8b51f9ddu;                       // INIT_B
  for (int i = 0; i < 8; i++) {
    uint32_t dv = pool[i & 3];
    dv ^= hb; hb *= 0x58f38dedu; dv *= hb; dv ^= dv >> 16;
    gs[i] = dv;
  }
  uint64_t sw0 = (uint64_t)gs[0] | ((uint64_t)gs[1] << 32);
  uint64_t sw1 = (uint64_t)gs[2] | ((uint64_t)gs[3] << 32);
  uint64_t iw0 = (uint64_t)gs[4] | ((uint64_t)gs[5] << 32);
  uint64_t iw1 = (uint64_t)gs[6] | ((uint64_t)gs[7] << 32);
  const __uint128_t MULT = (((__uint128_t)0x2360ed051fc65da4ULL) << 64) | 0x4385df649fccf645ULL;
  __uint128_t inc = ((((__uint128_t)iw0 << 64) | iw1) << 1) | 1;
  __uint128_t state = 0;
  state = state * MULT + inc;
  state += (((__uint128_t)sw0) << 64) | sw1;
  state = state * MULT + inc;
  bool has32 = false; uint32_t buf32 = 0;
  auto next64 = [&]() {
    state = state * MULT + inc;
    uint64_t hi = (uint64_t)(state >> 64), lo = (uint64_t)state;
    uint32_t rot = (uint32_t)(state >> 122);
    uint64_t x = hi ^ lo;
    return (x >> rot) | (x << ((64u - rot) & 63u));
  };
  auto next32 = [&]() -> uint32_t {
    if (has32) { has32 = false; return buf32; }
    uint64_t v = next64();
    has32 = true; buf32 = (uint32_t)(v >> 32);
    return (uint32_t)v;
  };
  par[0] = -1;
  for (int j = 1; j < JN; j++) {
    uint32_t rng = (uint32_t)(j - 1);
    if (rng == 0) { par[j] = 0; continue; }
    uint32_t rng_excl = rng + 1;
    uint64_t m = (uint64_t)next32() * (uint64_t)rng_excl;
    uint32_t leftover = (uint32_t)m;
    if (leftover < rng_excl) {
      uint32_t threshold = (uint32_t)((0x100000000ULL - rng_excl) % rng_excl);
      while (leftover < threshold) {
        m = (uint64_t)next32() * (uint64_t)rng_excl;
        leftover = (uint32_t)m;
      }
    }
    par[j] = (int)(m >> 32);
  }
  unsigned long long cm = 0;
  for (int j = 1; j < JN; j++) cm |= 1ull << par[j];
  *childmask = cm;
}

// ---------------- launch ----------------
extern "C" void kernel_launch(void* const* d_in, const int* in_sizes, int n_in,
                              void* d_out, int out_size, void* d_ws, size_t ws_size,
                              hipStream_t stream)
{
  const float* in_seq = (const float*)d_in[0];
  const float* w1 = (const float*)d_in[1];
  const float* b1 = (const float*)d_in[2];
  const float* w2 = (const float*)d_in[3];
  const float* b2 = (const float*)d_in[4];
  const float* w3 = (const float*)d_in[5];
  const float* b3 = (const float*)d_in[6];
  const float* w4 = (const float*)d_in[7];
  const float* b4 = (const float*)d_in[8];
  const float* offs = (const float*)d_in[9];

  char* pR1 = (char*)d_ws;
  char* pR2 = pR1 + 35390464;
  char* pR3 = pR2 + 134217728;
  _Float16* x2  = (_Float16*)pR1;
  _Float16* w1f = (_Float16*)(pR1 + 25165824);
  _Float16* w2f = (_Float16*)(pR1 + 25165824 + 786432);
  _Float16* w3f = (_Float16*)(pR1 + 25165824 + 786432 + 4194304);
  _Float16* w4f = (_Float16*)(pR1 + 25165824 + 786432 + 2 * 4194304);
  float*    b4p = (float*)(pR1 + 25165824 + 786432 + 2 * 4194304 + 1048576);
  float*    q   = (float*)pR1;            // overwrites x2/w1f/w2f/w3f only
  _Float16* h1  = (_Float16*)pR2;
  _Float16* h3  = (_Float16*)pR2;
  float*    Gt  = (float*)pR2;            // h1/h3 dead after L4
  _Float16* h2  = (_Float16*)pR3;

  float* pose = (float*)d_out;                        // [B_,57,3]
  float* rot  = (float*)d_out + (long)B_ * JN * 3;    // [B_,57,4,4]

  // prep
  prep_x2_kernel<<<(B_ * 192) / 256, 256, 0, stream>>>(in_seq, x2);
  prep_w2_kernel<<<(1024 * 192) / 256, 256, 0, stream>>>(w1, w1f, 171, 192, 1024);
  prep_w2_kernel<<<(1024 * 1024) / 256, 256, 0, stream>>>(w2, w2f, 1024, 1024, 1024);
  prep_w2_kernel<<<(1024 * 1024) / 256, 256, 0, stream>>>(w3, w3f, 1024, 1024, 1024);
  prep_w2_kernel<<<(256 * 1024) / 256, 256, 0, stream>>>(w4, w4f, 1024, 1024, 228);
  prep_b4_kernel<<<1, 256, 0, stream>>>(b4, b4p);

  // MLP: L1 full 3-plane, L2/L3 2-plane (f16 activations x split weights),
  // L4 full 3-plane (q feeds normalization — precision-critical)
  gemm_hl<0><<<(B_ / 128) * (1024 / 128), 256, 0, stream>>>(x2, w1f, b1, h1, B_, 1024, 192);
  gemm256<0, 2><<<(B_ / 256) * (1024 / 256), 512, 0, stream>>>(h1, w2f, b2, h2, B_, 1024, 1024);
  gemm256<0, 2><<<(B_ / 256) * (1024 / 256), 512, 0, stream>>>(h2, w3f, b3, h3, B_, 1024, 1024);
  gemm128p<1><<<(B_ / 128) * (QSTR / 128), 256, 0, stream>>>(h3, w4f, b4p, q, B_, QSTR, 1024);

  // fused epilogue (quat->rot + FK), no Lf round-trip
  FkParams P;
  compute_parents(P.par, &P.childmask);
  quat_fk_kernel<<<B_ / 256, 256, 0, stream>>>(q, offs, rot, Gt, pose, P);
}

// Round 19
// 547.671 us; speedup vs baseline: 1.5184x; 1.1600x over previous
//
#include <hip/hip_runtime.h>
#include <hip/hip_bf16.h>
#include <stdint.h>

#define B_   32768
#define JN   57
#define QSTR 256      // q row stride (228 padded to 256)

typedef _Float16 f16x8 __attribute__((ext_vector_type(8)));
typedef float    f32x4 __attribute__((ext_vector_type(4)));

__device__ __forceinline__ void split_f16(float v, _Float16& hi, _Float16& lo) {
  hi = (_Float16)v;
  lo = (_Float16)(v - (float)hi);
}

// ---------------- prep kernels ----------------
__global__ void prep_x2_kernel(const float* __restrict__ x, _Float16* __restrict__ xp) {
  long i = (long)blockIdx.x * 256 + threadIdx.x;   // over B_*192
  int row = (int)(i / 192), col = (int)(i % 192);
  float v = (col < 171) ? x[(long)row * 171 + col] : 0.f;
  _Float16 hi, lo; split_f16(v, hi, lo);
  xp[(long)row * 384 + col]       = hi;
  xp[(long)row * 384 + 192 + col] = lo;
}

__global__ void prep_w2_kernel(const float* __restrict__ w, _Float16* __restrict__ wf,
                               int Ksrc, int Kpad, int Nsrc) {
  long i = (long)blockIdx.x * 256 + threadIdx.x;   // over Ndst*Kpad
  int n = (int)(i / Kpad), k = (int)(i % Kpad);
  float v = (k < Ksrc && n < Nsrc) ? w[(long)k * Nsrc + n] : 0.f;
  _Float16 hi, lo; split_f16(v, hi, lo);
  wf[(long)n * (2 * Kpad) + k]        = hi;
  wf[(long)n * (2 * Kpad) + Kpad + k] = lo;
}

__global__ void prep_b4_kernel(const float* __restrict__ b, float* __restrict__ bp) {
  int i = threadIdx.x;  // 256 threads
  bp[i] = (i < 228) ? b[i] : 0.f;
}

// ---------------- 128² split-f16 GEMM (m97 structure) — layer 1 only ----------------
// WLO: write the lo plane of the split output. L1 feeds a 2-plane consumer
// (L2 reads only A-hi), so its lo plane is dead -> WLO=0 halves C-writes.
template<int EPI, int WLO>
__global__ __launch_bounds__(256)
void gemm_hl(const _Float16* __restrict__ A, const _Float16* __restrict__ Bt,
             const float* __restrict__ bias, void* __restrict__ Cout,
             int M, int N, int Kp)
{
  __shared__ __align__(16) _Float16 As[128 * 64];
  __shared__ __align__(16) _Float16 Bs[128 * 64];
  const int lda = 2 * Kp;
  const int T = Kp >> 6;
  const int tiles_n = N >> 7;
  const int cpx  = gridDim.x >> 3;
  const int virt = (blockIdx.x & 7) * cpx + (blockIdx.x >> 3);
  const int bm = virt / tiles_n;
  const int bn = virt % tiles_n;
  const int tid  = threadIdx.x;
  const int wave = tid >> 6;
  const int lane = tid & 63;

  const int srow = wave * 8 + (lane >> 3);
  const int scol = (((lane & 7) ^ (lane >> 3)) * 8);
  const long abase = (long)bm * 128;
  const long bbase = (long)bn * 128;

  f32x4 acc[4][4] = {};

  const int wm = (wave >> 1) * 64;
  const int wn = (wave & 1) * 64;
  const int lr = lane & 15;
  const int ch0 = (((lane >> 4) ^ (lane & 7)) * 8);
  const int ch1 = (((4 + (lane >> 4)) ^ (lane & 7)) * 8);

  for (int ph = 0; ph < 3; ++ph) {
    const int aoff = (ph == 2) ? Kp : 0;
    const int boff = (ph == 1) ? Kp : 0;
    for (int u = 0; u < T; ++u) {
#pragma unroll
      for (int i = 0; i < 4; i++) {
        const _Float16* asrc = A  + (abase + i * 32 + srow) * (long)lda + (aoff + u * 64 + scol);
        const _Float16* bsrc = Bt + (bbase + i * 32 + srow) * (long)lda + (boff + u * 64 + scol);
        __builtin_amdgcn_global_load_lds(
            (const __attribute__((address_space(1))) void*)asrc,
            (__attribute__((address_space(3))) void*)(As + (i * 256 + wave * 64) * 8),
            16, 0, 0);
        __builtin_amdgcn_global_load_lds(
            (const __attribute__((address_space(1))) void*)bsrc,
            (__attribute__((address_space(3))) void*)(Bs + (i * 256 + wave * 64) * 8),
            16, 0, 0);
      }
      __syncthreads();

#pragma unroll
      for (int ks = 0; ks < 2; ks++) {
        const int ch = ks ? ch1 : ch0;
        f16x8 af[4], bfr[4];
#pragma unroll
        for (int m = 0; m < 4; m++)
          af[m] = *(const f16x8*)(As + (wm + m * 16 + lr) * 64 + ch);
#pragma unroll
        for (int n = 0; n < 4; n++)
          bfr[n] = *(const f16x8*)(Bs + (wn + n * 16 + lr) * 64 + ch);
#pragma unroll
        for (int m = 0; m < 4; m++)
#pragma unroll
          for (int n = 0; n < 4; n++)
            acc[m][n] = __builtin_amdgcn_mfma_f32_16x16x32_f16(af[m], bfr[n], acc[m][n], 0, 0, 0);
      }
      __syncthreads();
    }
  }

  const int crow0 = bm * 128 + wm + (lane >> 4) * 4;
  const int ccol0 = bn * 128 + wn + lr;
#pragma unroll
  for (int n = 0; n < 4; n++) {
    const int col = ccol0 + n * 16;
    const float bv = bias[col];
#pragma unroll
    for (int m = 0; m < 4; m++) {
#pragma unroll
      for (int r = 0; r < 4; r++) {
        float v = acc[m][n][r] + bv;
        const long row = crow0 + m * 16 + r;
        if (EPI == 0) {
          v = (v >= 0.f) ? v : 0.01f * v;
          _Float16 hi, lo; split_f16(v, hi, lo);
          _Float16* C = (_Float16*)Cout;
          C[row * (long)(2 * N) + col] = hi;
          if (WLO) C[row * (long)(2 * N) + N + col] = lo;
        } else {
          ((float*)Cout)[row * (long)N + col] = v;
        }
      }
    }
  }
}

// ---------------- 256² 4-phase split-f16 GEMM — B-dedup schedule (best measured) ----------------
// 512 thr = 8 waves (2M x 4N), per-wave 128x64 out. BK=64, 2 LDS slots (128KB).
// acc[8][4] f32x4 = 128 AGPRs/lane -> REQUIRES the 256-reg budget of
// __launch_bounds__(512,2); min-waves=4 spills the accumulator (R11). Do not raise.
// PLANES: 3 = full split; 2 drops AlBh -> activations effectively f16,
// weights stay split-exact (hidden layers; measured absmax 0.0156 < 0.0264).
// WLO: write lo plane of split output (0 when the consumer is 2-plane).
template<int EPI, int PLANES, int WLO>
__global__ __launch_bounds__(512, 2)
void gemm256(const _Float16* __restrict__ Ag, const _Float16* __restrict__ Bt,
             const float* __restrict__ bias, void* __restrict__ Cout,
             int M, int N, int Kp)
{
  __shared__ __align__(16) _Float16 As[2][256 * 64];
  __shared__ __align__(16) _Float16 Bs[2][256 * 64];
  const int lda = 2 * Kp;
  const int T  = Kp >> 6;
  const int NT = PLANES * T;
  const int NI = NT >> 1;
  const int tiles_n = N >> 8;
  const int cpx  = gridDim.x >> 3;
  const int virt = (blockIdx.x & 7) * cpx + (blockIdx.x >> 3);
  const int bm = virt / tiles_n;
  const int bn = virt % tiles_n;
  const int tid  = threadIdx.x;
  const int wid  = tid >> 6;
  const int lane = tid & 63;

  const long abase = (long)bm * 256;
  const long bbase = (long)bn * 256;
  const int scol = (((lane & 7) ^ ((tid >> 3) & 7)) * 8);

  const int wm = (wid >> 2) * 128;
  const int wn = (wid & 3) * 64;
  const int lr = lane & 15;

  f32x4 acc[8][4] = {};

  auto stageA = [&](int t, int s, int h) {
    const int ph = t / T, u = t - ph * T;
    const long ko = ((ph == 2) ? (long)Kp : 0) + u * 64 + scol;
    const _Float16* src = Ag + (abase + h * 128 + (tid >> 3)) * (long)lda + ko;
    const _Float16* dst = &As[s][h * 8192 + tid * 8];
    __builtin_amdgcn_global_load_lds(
        (const __attribute__((address_space(1))) void*)src,
        (__attribute__((address_space(3))) void*)dst, 16, 0, 0);
    __builtin_amdgcn_global_load_lds(
        (const __attribute__((address_space(1))) void*)(src + 64 * (long)lda),
        (__attribute__((address_space(3))) void*)(dst + 4096), 16, 0, 0);
  };
  auto stageB = [&](int t, int s, int h) {
    const int ph = t / T, u = t - ph * T;
    const long ko = ((ph == 1) ? (long)Kp : 0) + u * 64 + scol;
    const _Float16* src = Bt + (bbase + h * 128 + (tid >> 3)) * (long)lda + ko;
    const _Float16* dst = &Bs[s][h * 8192 + tid * 8];
    __builtin_amdgcn_global_load_lds(
        (const __attribute__((address_space(1))) void*)src,
        (__attribute__((address_space(3))) void*)dst, 16, 0, 0);
    __builtin_amdgcn_global_load_lds(
        (const __attribute__((address_space(1))) void*)(src + 64 * (long)lda),
        (__attribute__((address_space(3))) void*)(dst + 4096), 16, 0, 0);
  };

  // phase: stage -> [vmcnt(4)] -> barrier -> 12 ds_reads -> 32 MFMA
#define PH(slot, ks, WAITV, ...)                                                  \
  do {                                                                            \
    __VA_ARGS__;                                                                  \
    if (WAITV) asm volatile("s_waitcnt vmcnt(4)" ::: "memory");                   \
    __builtin_amdgcn_s_barrier();                                                 \
    const int ch = (((ks) * 4 + (lane >> 4)) ^ (lane & 7)) * 8;                   \
    f16x8 af[8], bfr[4];                                                          \
    _Pragma("unroll")                                                             \
    for (int mi = 0; mi < 8; ++mi)                                                \
      af[mi] = *(const f16x8*)&As[slot][(wm + mi * 16 + lr) * 64 + ch];           \
    _Pragma("unroll")                                                             \
    for (int n = 0; n < 4; ++n)                                                   \
      bfr[n] = *(const f16x8*)&Bs[slot][(wn + n * 16 + lr) * 64 + ch];            \
    __builtin_amdgcn_s_setprio(1);                                                \
    _Pragma("unroll")                                                             \
    for (int mi = 0; mi < 8; ++mi)                                                \
      _Pragma("unroll")                                                           \
      for (int n = 0; n < 4; ++n)                                                 \
        acc[mi][n] = __builtin_amdgcn_mfma_f32_16x16x32_f16(                      \
            af[mi], bfr[n], acc[mi][n], 0, 0, 0);                                 \
    __builtin_amdgcn_s_setprio(0);                                                \
  } while (0)

  // prologue: full tile 0 -> S0 (8 loads/thread outstanding)
  stageA(0, 0, 0); stageA(0, 0, 1); stageB(0, 0, 0); stageB(0, 0, 1);

  for (int i = 0; i < NI; ++i) {
    const int b = 2 * i + 1;
    const int c = (2 * i + 2 < NT) ? 2 * i + 2 : 0;   // tail: harmless re-stage
    PH(0, 0, 1, stageA(b, 1, 0); stageA(b, 1, 1));
    PH(0, 1, 0, stageB(b, 1, 0); stageB(b, 1, 1));
    PH(1, 0, 1, stageA(c, 0, 0); stageA(c, 0, 1));
    PH(1, 1, 0, stageB(c, 0, 0); stageB(c, 0, 1));
  }
  asm volatile("s_waitcnt vmcnt(0)" ::: "memory");

#undef PH

  // epilogue: C/D layout col=lane&15, row=(lane>>4)*4+reg
  const int crow0 = bm * 256 + wm + (lane >> 4) * 4;
  const int ccol0 = bn * 256 + wn + lr;
#pragma unroll
  for (int n = 0; n < 4; n++) {
    const int col = ccol0 + n * 16;
    const float bv = bias[col];
#pragma unroll
    for (int m = 0; m < 8; m++) {
#pragma unroll
      for (int r = 0; r < 4; r++) {
        float v = acc[m][n][r] + bv;
        const long row = crow0 + m * 16 + r;
        if (EPI == 0) {
          v = (v >= 0.f) ? v : 0.01f * v;
          _Float16 hi, lo; split_f16(v, hi, lo);
          _Float16* C = (_Float16*)Cout;
          C[row * (long)(2 * N) + col] = hi;
          if (WLO) C[row * (long)(2 * N) + N + col] = lo;
        } else {
          ((float*)Cout)[row * (long)N + col] = v;
        }
      }
    }
  }
}

// ---------------- 128² 4-phase split-f16 GEMM — R9 discipline, 2 blocks/CU ----------------
// (R14-verified.) Used for L4 (N=256): 512 blocks = 1 co-resident round.
// Kept at full 3 planes: L4's output q is directly normalized (worst-quat
// amplification ~60x) — precision budget reserved here.
template<int EPI>
__global__ __launch_bounds__(256, 2)
void gemm128p(const _Float16* __restrict__ Ag, const _Float16* __restrict__ Bt,
              const float* __restrict__ bias, void* __restrict__ Cout,
              int M, int N, int Kp)
{
  __shared__ __align__(16) _Float16 As[2][128 * 64];
  __shared__ __align__(16) _Float16 Bs[2][128 * 64];
  const int lda = 2 * Kp;
  const int T  = Kp >> 6;
  const int NT = 3 * T;
  const int NI = NT >> 1;
  const int tiles_n = N >> 7;
  const int cpx  = gridDim.x >> 3;
  const int virt = (blockIdx.x & 7) * cpx + (blockIdx.x >> 3);
  const int bm = virt / tiles_n;
  const int bn = virt % tiles_n;
  const int tid  = threadIdx.x;
  const int wave = tid >> 6;
  const int lane = tid & 63;

  const long abase = (long)bm * 128;
  const long bbase = (long)bn * 128;
  const int wm = (wave >> 1) * 64;
  const int wn = (wave & 1) * 64;
  const int lr = lane & 15;

  f32x4 acc[4][4] = {};

  auto stageA = [&](int t, int s) {
    const int ph = t / T, u = t - ph * T;
    const long ko = ((ph == 2) ? (long)Kp : 0) + u * 64;
#pragma unroll
    for (int L = 0; L < 4; ++L) {
      const int idx = tid + L * 256;
      const int row = idx >> 3, ck = idx & 7;
      const _Float16* src = Ag + (abase + row) * (long)lda + ko + (ck ^ (row & 7)) * 8;
      __builtin_amdgcn_global_load_lds(
          (const __attribute__((address_space(1))) void*)src,
          (__attribute__((address_space(3))) void*)&As[s][idx * 8], 16, 0, 0);
    }
  };
  auto stageB = [&](int t, int s) {
    const int ph = t / T, u = t - ph * T;
    const long ko = ((ph == 1) ? (long)Kp : 0) + u * 64;
#pragma unroll
    for (int L = 0; L < 4; ++L) {
      const int idx = tid + L * 256;
      const int row = idx >> 3, ck = idx & 7;
      const _Float16* src = Bt + (bbase + row) * (long)lda + ko + (ck ^ (row & 7)) * 8;
      __builtin_amdgcn_global_load_lds(
          (const __attribute__((address_space(1))) void*)src,
          (__attribute__((address_space(3))) void*)&Bs[s][idx * 8], 16, 0, 0);
    }
  };

  // phase: stage(4) -> [vmcnt(4)] -> barrier -> 8 ds_reads -> 16 MFMA
#define PH(slot, ks, WAITV, ...)                                                  \
  do {                                                                            \
    __VA_ARGS__;                                                                  \
    if (WAITV) asm volatile("s_waitcnt vmcnt(4)" ::: "memory");                   \
    __builtin_amdgcn_s_barrier();                                                 \
    const int ch = (((ks) * 4 + (lane >> 4)) ^ (lane & 7)) * 8;                   \
    f16x8 af[4], bfr[4];                                                          \
    _Pragma("unroll")                                                             \
    for (int mi = 0; mi < 4; ++mi)                                                \
      af[mi] = *(const f16x8*)&As[slot][(wm + mi * 16 + lr) * 64 + ch];           \
    _Pragma("unroll")                                                             \
    for (int n = 0; n < 4; ++n)                                                   \
      bfr[n] = *(const f16x8*)&Bs[slot][(wn + n * 16 + lr) * 64 + ch];            \
    __builtin_amdgcn_s_setprio(1);                                                \
    _Pragma("unroll")                                                             \
    for (int mi = 0; mi < 4; ++mi)                                                \
      _Pragma("unroll")                                                           \
      for (int n = 0; n < 4; ++n)                                                 \
        acc[mi][n] = __builtin_amdgcn_mfma_f32_16x16x32_f16(                      \
            af[mi], bfr[n], acc[mi][n], 0, 0, 0);                                 \
    __builtin_amdgcn_s_setprio(0);                                                \
  } while (0)

  // prologue: tile 0 -> S0 (8 loads/thread outstanding)
  stageA(0, 0); stageB(0, 0);

  for (int i = 0; i < NI; ++i) {
    const int b = 2 * i + 1;
    const int c = (2 * i + 2 < NT) ? 2 * i + 2 : 0;   // tail: harmless re-stage
    PH(0, 0, 1, stageA(b, 1));
    PH(0, 1, 0, stageB(b, 1));
    PH(1, 0, 1, stageA(c, 0));
    PH(1, 1, 0, stageB(c, 0));
  }
  asm volatile("s_waitcnt vmcnt(0)" ::: "memory");

#undef PH

  // epilogue: C/D layout col=lane&15, row=(lane>>4)*4+reg
  const int crow0 = bm * 128 + wm + (lane >> 4) * 4;
  const int ccol0 = bn * 128 + wn + lr;
#pragma unroll
  for (int n = 0; n < 4; n++) {
    const int col = ccol0 + n * 16;
    const float bv = bias[col];
#pragma unroll
    for (int m = 0; m < 4; m++) {
#pragma unroll
      for (int r = 0; r < 4; r++) {
        float v = acc[m][n][r] + bv;
        const long row = crow0 + m * 16 + r;
        if (EPI == 0) {
          v = (v >= 0.f) ? v : 0.01f * v;
          _Float16 hi, lo; split_f16(v, hi, lo);
          _Float16* C = (_Float16*)Cout;
          C[row * (long)(2 * N) + col]     = hi;
          C[row * (long)(2 * N) + N + col] = lo;
        } else {
          ((float*)Cout)[row * (long)N + col] = v;
        }
      }
    }
  }
}

// ---------------- fused quat->rotmat + forward kinematics ----------------
struct FkParams { int par[JN]; unsigned long long childmask; };

__global__ __launch_bounds__(256)
void quat_fk_kernel(const float* __restrict__ q, const float* __restrict__ offs,
                    float* __restrict__ rot, float* __restrict__ Gt,
                    float* __restrict__ pose, FkParams P)
{
  __shared__ float qs[256][65];                 // 66,560 B
  const int tid = threadIdx.x;
  const int s0  = blockIdx.x * 256;
  const int s   = s0 + tid;

  float G[12];

  for (int c = 0; c < 4; ++c) {
    __syncthreads();                            // prev chunk fully consumed
    for (int idx = tid; idx < 256 * 64; idx += 256) {
      const int r = idx >> 6, col = idx & 63;
      qs[r][col] = q[(long)(s0 + r) * QSTR + c * 64 + col];
    }
    __syncthreads();
    const int jlo = c * 16;
    const int jhi = (c == 3) ? JN : jlo + 16;
    for (int j = jlo; j < jhi; ++j) {
      const int cb = j * 4 - c * 64;
      float qw = qs[tid][cb + 0], qx = qs[tid][cb + 1];
      float qy = qs[tid][cb + 2], qz = qs[tid][cb + 3];
      float n = sqrtf(qw * qw + qx * qx + qy * qy + qz * qz);
      n = fmaxf(n, 1e-8f);
      const float inv = 1.f / n;
      qw *= inv; qx *= inv; qy *= inv; qz *= inv;
      const float xx = qx * qx, yy = qy * qy, zz = qz * qz;
      const float xy = qx * qy, xz = qx * qz, yz = qy * qz;
      const float xw = qx * qw, yw = qy * qw, zw = qz * qw;
      float L[12];
      L[0] = 1.f - 2.f * (yy + zz); L[1] = 2.f * (xy - zw); L[2]  = 2.f * (xz + yw);
      L[4] = 2.f * (xy + zw); L[5] = 1.f - 2.f * (xx + zz); L[6]  = 2.f * (yz - xw);
      L[8] = 2.f * (xz - yw); L[9] = 2.f * (yz + xw); L[10] = 1.f - 2.f * (xx + yy);

      float4* ro = (float4*)(rot + ((long)s * JN + j) * 16);
      ro[0] = make_float4(L[0], L[1], L[2],  0.f);
      ro[1] = make_float4(L[4], L[5], L[6],  0.f);
      ro[2] = make_float4(L[8], L[9], L[10], 0.f);
      ro[3] = make_float4(0.f, 0.f, 0.f, 1.f);

      L[3]  = offs[j * 3 + 0];
      L[7]  = offs[j * 3 + 1];
      L[11] = offs[j * 3 + 2];

      if (j == 0) {
#pragma unroll
        for (int e = 0; e < 12; e++) G[e] = L[e];
      } else {
        const int p = P.par[j];                 // scalar -> uniform branch
        float Pm[12];
        if (p == j - 1) {
#pragma unroll
          for (int e = 0; e < 12; e++) Pm[e] = G[e];
        } else {
#pragma unroll
          for (int e = 0; e < 12; e++) Pm[e] = Gt[((long)p * 12 + e) * B_ + s];
        }
#pragma unroll
        for (int r = 0; r < 3; r++) {
#pragma unroll
          for (int cc = 0; cc < 4; cc++) {
            float v = Pm[r * 4 + 0] * L[0 * 4 + cc] + Pm[r * 4 + 1] * L[1 * 4 + cc]
                    + Pm[r * 4 + 2] * L[2 * 4 + cc];
            if (cc == 3) v += Pm[r * 4 + 3];
            G[r * 4 + cc] = v;
          }
        }
      }
      if ((P.childmask >> j) & 1ull) {
#pragma unroll
        for (int e = 0; e < 12; e++) Gt[((long)j * 12 + e) * B_ + s] = G[e];
      }
      pose[(long)s * (JN * 3) + j * 3 + 0] = G[3];
      pose[(long)s * (JN * 3) + j * 3 + 1] = G[7];
      pose[(long)s * (JN * 3) + j * 3 + 2] = G[11];
    }
  }
}

// ---------------- host: replicate np.random.default_rng(7) parents ----------------
static void compute_parents(int* par, unsigned long long* childmask)
{
  uint32_t pool[4];
  uint32_t hc = 0x43b0d7e5u;                       // INIT_A
  auto hashmix = [&hc](uint32_t v) {
    v ^= hc; hc *= 0x931e8875u; v *= hc; v ^= v >> 16; return v;
  };
  auto mix = [](uint32_t x, uint32_t y) {
    uint32_t r = 0xca01f9ddu * x - 0x4973f715u * y;
    r ^= r >> 16;
    return r;
  };
  const uint32_t entropy[1] = {7u};
  for (int i = 0; i < 4; i++) pool[i] = hashmix(i < 1 ? entropy[i] : 0u);
  for (int si = 0; si < 4; si++)
    for (int di = 0; di < 4; di++)
      if (si != di) pool[di] = mix(pool[di], hashmix(pool[si]));
  uint32_t gs[8];
  uint32_t hb = 0x8b51f9ddu;                       // INIT_B
  for (int i = 0; i < 8; i++) {
    uint32_t dv = pool[i & 3];
    dv ^= hb; hb *= 0x58f38dedu; dv *= hb; dv ^= dv >> 16;
    gs[i] = dv;
  }
  uint64_t sw0 = (uint64_t)gs[0] | ((uint64_t)gs[1] << 32);
  uint64_t sw1 = (uint64_t)gs[2] | ((uint64_t)gs[3] << 32);
  uint64_t iw0 = (uint64_t)gs[4] | ((uint64_t)gs[5] << 32);
  uint64_t iw1 = (uint64_t)gs[6] | ((uint64_t)gs[7] << 32);
  const __uint128_t MULT = (((__uint128_t)0x2360ed051fc65da4ULL) << 64) | 0x4385df649fccf645ULL;
  __uint128_t inc = ((((__uint128_t)iw0 << 64) | iw1) << 1) | 1;
  __uint128_t state = 0;
  state = state * MULT + inc;
  state += (((__uint128_t)sw0) << 64) | sw1;
  state = state * MULT + inc;
  bool has32 = false; uint32_t buf32 = 0;
  auto next64 = [&]() {
    state = state * MULT + inc;
    uint64_t hi = (uint64_t)(state >> 64), lo = (uint64_t)state;
    uint32_t rot = (uint32_t)(state >> 122);
    uint64_t x = hi ^ lo;
    return (x >> rot) | (x << ((64u - rot) & 63u));
  };
  auto next32 = [&]() -> uint32_t {
    if (has32) { has32 = false; return buf32; }
    uint64_t v = next64();
    has32 = true; buf32 = (uint32_t)(v >> 32);
    return (uint32_t)v;
  };
  par[0] = -1;
  for (int j = 1; j < JN; j++) {
    uint32_t rng = (uint32_t)(j - 1);
    if (rng == 0) { par[j] = 0; continue; }
    uint32_t rng_excl = rng + 1;
    uint64_t m = (uint64_t)next32() * (uint64_t)rng_excl;
    uint32_t leftover = (uint32_t)m;
    if (leftover < rng_excl) {
      uint32_t threshold = (uint32_t)((0x100000000ULL - rng_excl) % rng_excl);
      while (leftover < threshold) {
        m = (uint64_t)next32() * (uint64_t)rng_excl;
        leftover = (uint32_t)m;
      }
    }
    par[j] = (int)(m >> 32);
  }
  unsigned long long cm = 0;
  for (int j = 1; j < JN; j++) cm |= 1ull << par[j];
  *childmask = cm;
}

// ---------------- launch ----------------
extern "C" void kernel_launch(void* const* d_in, const int* in_sizes, int n_in,
                              void* d_out, int out_size, void* d_ws, size_t ws_size,
                              hipStream_t stream)
{
  const float* in_seq = (const float*)d_in[0];
  const float* w1 = (const float*)d_in[1];
  const float* b1 = (const float*)d_in[2];
  const float* w2 = (const float*)d_in[3];
  const float* b2 = (const float*)d_in[4];
  const float* w3 = (const float*)d_in[5];
  const float* b3 = (const float*)d_in[6];
  const float* w4 = (const float*)d_in[7];
  const float* b4 = (const float*)d_in[8];
  const float* offs = (const float*)d_in[9];

  char* pR1 = (char*)d_ws;
  char* pR2 = pR1 + 35390464;
  char* pR3 = pR2 + 134217728;
  _Float16* x2  = (_Float16*)pR1;
  _Float16* w1f = (_Float16*)(pR1 + 25165824);
  _Float16* w2f = (_Float16*)(pR1 + 25165824 + 786432);
  _Float16* w3f = (_Float16*)(pR1 + 25165824 + 786432 + 4194304);
  _Float16* w4f = (_Float16*)(pR1 + 25165824 + 786432 + 2 * 4194304);
  float*    b4p = (float*)(pR1 + 25165824 + 786432 + 2 * 4194304 + 1048576);
  float*    q   = (float*)pR1;            // overwrites x2/w1f/w2f/w3f only
  _Float16* h1  = (_Float16*)pR2;
  _Float16* h3  = (_Float16*)pR2;
  float*    Gt  = (float*)pR2;            // h1/h3 dead after L4
  _Float16* h2  = (_Float16*)pR3;

  float* pose = (float*)d_out;                        // [B_,57,3]
  float* rot  = (float*)d_out + (long)B_ * JN * 3;    // [B_,57,4,4]

  // prep
  prep_x2_kernel<<<(B_ * 192) / 256, 256, 0, stream>>>(in_seq, x2);
  prep_w2_kernel<<<(1024 * 192) / 256, 256, 0, stream>>>(w1, w1f, 171, 192, 1024);
  prep_w2_kernel<<<(1024 * 1024) / 256, 256, 0, stream>>>(w2, w2f, 1024, 1024, 1024);
  prep_w2_kernel<<<(1024 * 1024) / 256, 256, 0, stream>>>(w3, w3f, 1024, 1024, 1024);
  prep_w2_kernel<<<(256 * 1024) / 256, 256, 0, stream>>>(w4, w4f, 1024, 1024, 228);
  prep_b4_kernel<<<1, 256, 0, stream>>>(b4, b4p);

  // MLP: L1 3-plane (skip dead lo-out), L2 2-plane (skip dead lo-out),
  // L3 2-plane (lo-out kept — L4 is 3-plane and reads Al), L4 3-plane.
  gemm_hl<0, 0><<<(B_ / 128) * (1024 / 128), 256, 0, stream>>>(x2, w1f, b1, h1, B_, 1024, 192);
  gemm256<0, 2, 0><<<(B_ / 256) * (1024 / 256), 512, 0, stream>>>(h1, w2f, b2, h2, B_, 1024, 1024);
  gemm256<0, 2, 1><<<(B_ / 256) * (1024 / 256), 512, 0, stream>>>(h2, w3f, b3, h3, B_, 1024, 1024);
  gemm128p<1><<<(B_ / 128) * (QSTR / 128), 256, 0, stream>>>(h3, w4f, b4p, q, B_, QSTR, 1024);

  // fused epilogue (quat->rot + FK), no Lf round-trip
  FkParams P;
  compute_parents(P.par, &P.childmask);
  quat_fk_kernel<<<B_ / 256, 256, 0, stream>>>(q, offs, rot, Gt, pose, P);
}

// Round 20
// 504.991 us; speedup vs baseline: 1.6467x; 1.0845x over previous
//
#include <hip/hip_runtime.h>
#include <hip/hip_bf16.h>
#include <stdint.h>

#define B_   32768
#define JN   57
#define QSTR 256      // q row stride (228 padded to 256)

typedef _Float16 f16x8 __attribute__((ext_vector_type(8)));
typedef float    f32x4 __attribute__((ext_vector_type(4)));

__device__ __forceinline__ void split_f16(float v, _Float16& hi, _Float16& lo) {
  hi = (_Float16)v;
  lo = (_Float16)(v - (float)hi);
}

// ---------------- prep kernels ----------------
__global__ void prep_x2_kernel(const float* __restrict__ x, _Float16* __restrict__ xp) {
  long i = (long)blockIdx.x * 256 + threadIdx.x;   // over B_*192
  int row = (int)(i / 192), col = (int)(i % 192);
  float v = (col < 171) ? x[(long)row * 171 + col] : 0.f;
  _Float16 hi, lo; split_f16(v, hi, lo);
  xp[(long)row * 384 + col]       = hi;
  xp[(long)row * 384 + 192 + col] = lo;
}

__global__ void prep_w2_kernel(const float* __restrict__ w, _Float16* __restrict__ wf,
                               int Ksrc, int Kpad, int Nsrc) {
  long i = (long)blockIdx.x * 256 + threadIdx.x;   // over Ndst*Kpad
  int n = (int)(i / Kpad), k = (int)(i % Kpad);
  float v = (k < Ksrc && n < Nsrc) ? w[(long)k * Nsrc + n] : 0.f;
  _Float16 hi, lo; split_f16(v, hi, lo);
  wf[(long)n * (2 * Kpad) + k]        = hi;
  wf[(long)n * (2 * Kpad) + Kpad + k] = lo;
}

__global__ void prep_b4_kernel(const float* __restrict__ b, float* __restrict__ bp) {
  int i = threadIdx.x;  // 256 threads
  bp[i] = (i < 228) ? b[i] : 0.f;
}

// ---------------- 128² split-f16 GEMM (m97 structure) — layer 1 only ----------------
// WLO=0: lo-output plane dead (consumer reads A-hi only) -> skip those stores.
template<int EPI, int WLO>
__global__ __launch_bounds__(256)
void gemm_hl(const _Float16* __restrict__ A, const _Float16* __restrict__ Bt,
             const float* __restrict__ bias, void* __restrict__ Cout,
             int M, int N, int Kp)
{
  __shared__ __align__(16) _Float16 As[128 * 64];
  __shared__ __align__(16) _Float16 Bs[128 * 64];
  const int lda = 2 * Kp;
  const int T = Kp >> 6;
  const int tiles_n = N >> 7;
  const int cpx  = gridDim.x >> 3;
  const int virt = (blockIdx.x & 7) * cpx + (blockIdx.x >> 3);
  const int bm = virt / tiles_n;
  const int bn = virt % tiles_n;
  const int tid  = threadIdx.x;
  const int wave = tid >> 6;
  const int lane = tid & 63;

  const int srow = wave * 8 + (lane >> 3);
  const int scol = (((lane & 7) ^ (lane >> 3)) * 8);
  const long abase = (long)bm * 128;
  const long bbase = (long)bn * 128;

  f32x4 acc[4][4] = {};

  const int wm = (wave >> 1) * 64;
  const int wn = (wave & 1) * 64;
  const int lr = lane & 15;
  const int ch0 = (((lane >> 4) ^ (lane & 7)) * 8);
  const int ch1 = (((4 + (lane >> 4)) ^ (lane & 7)) * 8);

  for (int ph = 0; ph < 3; ++ph) {
    const int aoff = (ph == 2) ? Kp : 0;
    const int boff = (ph == 1) ? Kp : 0;
    for (int u = 0; u < T; ++u) {
#pragma unroll
      for (int i = 0; i < 4; i++) {
        const _Float16* asrc = A  + (abase + i * 32 + srow) * (long)lda + (aoff + u * 64 + scol);
        const _Float16* bsrc = Bt + (bbase + i * 32 + srow) * (long)lda + (boff + u * 64 + scol);
        __builtin_amdgcn_global_load_lds(
            (const __attribute__((address_space(1))) void*)asrc,
            (__attribute__((address_space(3))) void*)(As + (i * 256 + wave * 64) * 8),
            16, 0, 0);
        __builtin_amdgcn_global_load_lds(
            (const __attribute__((address_space(1))) void*)bsrc,
            (__attribute__((address_space(3))) void*)(Bs + (i * 256 + wave * 64) * 8),
            16, 0, 0);
      }
      __syncthreads();

#pragma unroll
      for (int ks = 0; ks < 2; ks++) {
        const int ch = ks ? ch1 : ch0;
        f16x8 af[4], bfr[4];
#pragma unroll
        for (int m = 0; m < 4; m++)
          af[m] = *(const f16x8*)(As + (wm + m * 16 + lr) * 64 + ch);
#pragma unroll
        for (int n = 0; n < 4; n++)
          bfr[n] = *(const f16x8*)(Bs + (wn + n * 16 + lr) * 64 + ch);
#pragma unroll
        for (int m = 0; m < 4; m++)
#pragma unroll
          for (int n = 0; n < 4; n++)
            acc[m][n] = __builtin_amdgcn_mfma_f32_16x16x32_f16(af[m], bfr[n], acc[m][n], 0, 0, 0);
      }
      __syncthreads();
    }
  }

  const int crow0 = bm * 128 + wm + (lane >> 4) * 4;
  const int ccol0 = bn * 128 + wn + lr;
#pragma unroll
  for (int n = 0; n < 4; n++) {
    const int col = ccol0 + n * 16;
    const float bv = bias[col];
#pragma unroll
    for (int m = 0; m < 4; m++) {
#pragma unroll
      for (int r = 0; r < 4; r++) {
        float v = acc[m][n][r] + bv;
        const long row = crow0 + m * 16 + r;
        if (EPI == 0) {
          v = (v >= 0.f) ? v : 0.01f * v;
          _Float16 hi, lo; split_f16(v, hi, lo);
          _Float16* C = (_Float16*)Cout;
          C[row * (long)(2 * N) + col] = hi;
          if (WLO) C[row * (long)(2 * N) + N + col] = lo;
        } else {
          ((float*)Cout)[row * (long)N + col] = v;
        }
      }
    }
  }
}

// ---------------- 256² 4-phase split-f16 GEMM — B-dedup schedule (best measured) ----------------
// 512 thr = 8 waves (2M x 4N), per-wave 128x64 out. BK=64, 2 LDS slots (128KB).
// acc[8][4] f32x4 = 128 AGPRs/lane -> REQUIRES the 256-reg budget of
// __launch_bounds__(512,2); min-waves=4 spills the accumulator (R11). Do not raise.
// PLANES=2 drops AlBh -> activations effectively f16, weights split-exact.
// WLO=0 skips dead lo-output stores.
template<int EPI, int PLANES, int WLO>
__global__ __launch_bounds__(512, 2)
void gemm256(const _Float16* __restrict__ Ag, const _Float16* __restrict__ Bt,
             const float* __restrict__ bias, void* __restrict__ Cout,
             int M, int N, int Kp)
{
  __shared__ __align__(16) _Float16 As[2][256 * 64];
  __shared__ __align__(16) _Float16 Bs[2][256 * 64];
  const int lda = 2 * Kp;
  const int T  = Kp >> 6;
  const int NT = PLANES * T;
  const int NI = NT >> 1;
  const int tiles_n = N >> 8;
  const int cpx  = gridDim.x >> 3;
  const int virt = (blockIdx.x & 7) * cpx + (blockIdx.x >> 3);
  const int bm = virt / tiles_n;
  const int bn = virt % tiles_n;
  const int tid  = threadIdx.x;
  const int wid  = tid >> 6;
  const int lane = tid & 63;

  const long abase = (long)bm * 256;
  const long bbase = (long)bn * 256;
  const int scol = (((lane & 7) ^ ((tid >> 3) & 7)) * 8);

  const int wm = (wid >> 2) * 128;
  const int wn = (wid & 3) * 64;
  const int lr = lane & 15;

  f32x4 acc[8][4] = {};

  auto stageA = [&](int t, int s, int h) {
    const int ph = t / T, u = t - ph * T;
    const long ko = ((ph == 2) ? (long)Kp : 0) + u * 64 + scol;
    const _Float16* src = Ag + (abase + h * 128 + (tid >> 3)) * (long)lda + ko;
    const _Float16* dst = &As[s][h * 8192 + tid * 8];
    __builtin_amdgcn_global_load_lds(
        (const __attribute__((address_space(1))) void*)src,
        (__attribute__((address_space(3))) void*)dst, 16, 0, 0);
    __builtin_amdgcn_global_load_lds(
        (const __attribute__((address_space(1))) void*)(src + 64 * (long)lda),
        (__attribute__((address_space(3))) void*)(dst + 4096), 16, 0, 0);
  };
  auto stageB = [&](int t, int s, int h) {
    const int ph = t / T, u = t - ph * T;
    const long ko = ((ph == 1) ? (long)Kp : 0) + u * 64 + scol;
    const _Float16* src = Bt + (bbase + h * 128 + (tid >> 3)) * (long)lda + ko;
    const _Float16* dst = &Bs[s][h * 8192 + tid * 8];
    __builtin_amdgcn_global_load_lds(
        (const __attribute__((address_space(1))) void*)src,
        (__attribute__((address_space(3))) void*)dst, 16, 0, 0);
    __builtin_amdgcn_global_load_lds(
        (const __attribute__((address_space(1))) void*)(src + 64 * (long)lda),
        (__attribute__((address_space(3))) void*)(dst + 4096), 16, 0, 0);
  };

  // phase: stage -> [vmcnt(4)] -> barrier -> 12 ds_reads -> 32 MFMA
#define PH(slot, ks, WAITV, ...)                                                  \
  do {                                                                            \
    __VA_ARGS__;                                                                  \
    if (WAITV) asm volatile("s_waitcnt vmcnt(4)" ::: "memory");                   \
    __builtin_amdgcn_s_barrier();                                                 \
    const int ch = (((ks) * 4 + (lane >> 4)) ^ (lane & 7)) * 8;                   \
    f16x8 af[8], bfr[4];                                                          \
    _Pragma("unroll")                                                             \
    for (int mi = 0; mi < 8; ++mi)                                                \
      af[mi] = *(const f16x8*)&As[slot][(wm + mi * 16 + lr) * 64 + ch];           \
    _Pragma("unroll")                                                             \
    for (int n = 0; n < 4; ++n)                                                   \
      bfr[n] = *(const f16x8*)&Bs[slot][(wn + n * 16 + lr) * 64 + ch];            \
    __builtin_amdgcn_s_setprio(1);                                                \
    _Pragma("unroll")                                                             \
    for (int mi = 0; mi < 8; ++mi)                                                \
      _Pragma("unroll")                                                           \
      for (int n = 0; n < 4; ++n)                                                 \
        acc[mi][n] = __builtin_amdgcn_mfma_f32_16x16x32_f16(                      \
            af[mi], bfr[n], acc[mi][n], 0, 0, 0);                                 \
    __builtin_amdgcn_s_setprio(0);                                                \
  } while (0)

  // prologue: full tile 0 -> S0 (8 loads/thread outstanding)
  stageA(0, 0, 0); stageA(0, 0, 1); stageB(0, 0, 0); stageB(0, 0, 1);

  for (int i = 0; i < NI; ++i) {
    const int b = 2 * i + 1;
    const int c = (2 * i + 2 < NT) ? 2 * i + 2 : 0;   // tail: harmless re-stage
    PH(0, 0, 1, stageA(b, 1, 0); stageA(b, 1, 1));
    PH(0, 1, 0, stageB(b, 1, 0); stageB(b, 1, 1));
    PH(1, 0, 1, stageA(c, 0, 0); stageA(c, 0, 1));
    PH(1, 1, 0, stageB(c, 0, 0); stageB(c, 0, 1));
  }
  asm volatile("s_waitcnt vmcnt(0)" ::: "memory");

#undef PH

  // epilogue: C/D layout col=lane&15, row=(lane>>4)*4+reg
  const int crow0 = bm * 256 + wm + (lane >> 4) * 4;
  const int ccol0 = bn * 256 + wn + lr;
#pragma unroll
  for (int n = 0; n < 4; n++) {
    const int col = ccol0 + n * 16;
    const float bv = bias[col];
#pragma unroll
    for (int m = 0; m < 8; m++) {
#pragma unroll
      for (int r = 0; r < 4; r++) {
        float v = acc[m][n][r] + bv;
        const long row = crow0 + m * 16 + r;
        if (EPI == 0) {
          v = (v >= 0.f) ? v : 0.01f * v;
          _Float16 hi, lo; split_f16(v, hi, lo);
          _Float16* C = (_Float16*)Cout;
          C[row * (long)(2 * N) + col] = hi;
          if (WLO) C[row * (long)(2 * N) + N + col] = lo;
        } else {
          ((float*)Cout)[row * (long)N + col] = v;
        }
      }
    }
  }
}

// ---------------- 128² 4-phase split-f16 GEMM — R9 discipline, 2 blocks/CU ----------------
// (R14-verified.) Used for L4 (N=256): 512 blocks = 1 co-resident round.
// PLANES=2: reads h3-hi only (weights stay split) — third precision source,
// budgeted against measured 0.0156 with threshold 0.0264.
template<int EPI, int PLANES>
__global__ __launch_bounds__(256, 2)
void gemm128p(const _Float16* __restrict__ Ag, const _Float16* __restrict__ Bt,
              const float* __restrict__ bias, void* __restrict__ Cout,
              int M, int N, int Kp)
{
  __shared__ __align__(16) _Float16 As[2][128 * 64];
  __shared__ __align__(16) _Float16 Bs[2][128 * 64];
  const int lda = 2 * Kp;
  const int T  = Kp >> 6;
  const int NT = PLANES * T;
  const int NI = NT >> 1;
  const int tiles_n = N >> 7;
  const int cpx  = gridDim.x >> 3;
  const int virt = (blockIdx.x & 7) * cpx + (blockIdx.x >> 3);
  const int bm = virt / tiles_n;
  const int bn = virt % tiles_n;
  const int tid  = threadIdx.x;
  const int wave = tid >> 6;
  const int lane = tid & 63;

  const long abase = (long)bm * 128;
  const long bbase = (long)bn * 128;
  const int wm = (wave >> 1) * 64;
  const int wn = (wave & 1) * 64;
  const int lr = lane & 15;

  f32x4 acc[4][4] = {};

  auto stageA = [&](int t, int s) {
    const int ph = t / T, u = t - ph * T;
    const long ko = ((ph == 2) ? (long)Kp : 0) + u * 64;
#pragma unroll
    for (int L = 0; L < 4; ++L) {
      const int idx = tid + L * 256;
      const int row = idx >> 3, ck = idx & 7;
      const _Float16* src = Ag + (abase + row) * (long)lda + ko + (ck ^ (row & 7)) * 8;
      __builtin_amdgcn_global_load_lds(
          (const __attribute__((address_space(1))) void*)src,
          (__attribute__((address_space(3))) void*)&As[s][idx * 8], 16, 0, 0);
    }
  };
  auto stageB = [&](int t, int s) {
    const int ph = t / T, u = t - ph * T;
    const long ko = ((ph == 1) ? (long)Kp : 0) + u * 64;
#pragma unroll
    for (int L = 0; L < 4; ++L) {
      const int idx = tid + L * 256;
      const int row = idx >> 3, ck = idx & 7;
      const _Float16* src = Bt + (bbase + row) * (long)lda + ko + (ck ^ (row & 7)) * 8;
      __builtin_amdgcn_global_load_lds(
          (const __attribute__((address_space(1))) void*)src,
          (__attribute__((address_space(3))) void*)&Bs[s][idx * 8], 16, 0, 0);
    }
  };

  // phase: stage(4) -> [vmcnt(4)] -> barrier -> 8 ds_reads -> 16 MFMA
#define PH(slot, ks, WAITV, ...)                                                  \
  do {                                                                            \
    __VA_ARGS__;                                                                  \
    if (WAITV) asm volatile("s_waitcnt vmcnt(4)" ::: "memory");                   \
    __builtin_amdgcn_s_barrier();                                                 \
    const int ch = (((ks) * 4 + (lane >> 4)) ^ (lane & 7)) * 8;                   \
    f16x8 af[4], bfr[4];                                                          \
    _Pragma("unroll")                                                             \
    for (int mi = 0; mi < 4; ++mi)                                                \
      af[mi] = *(const f16x8*)&As[slot][(wm + mi * 16 + lr) * 64 + ch];           \
    _Pragma("unroll")                                                             \
    for (int n = 0; n < 4; ++n)                                                   \
      bfr[n] = *(const f16x8*)&Bs[slot][(wn + n * 16 + lr) * 64 + ch];            \
    __builtin_amdgcn_s_setprio(1);                                                \
    _Pragma("unroll")                                                             \
    for (int mi = 0; mi < 4; ++mi)                                                \
      _Pragma("unroll")                                                           \
      for (int n = 0; n < 4; ++n)                                                 \
        acc[mi][n] = __builtin_amdgcn_mfma_f32_16x16x32_f16(                      \
            af[mi], bfr[n], acc[mi][n], 0, 0, 0);                                 \
    __builtin_amdgcn_s_setprio(0);                                                \
  } while (0)

  // prologue: tile 0 -> S0 (8 loads/thread outstanding)
  stageA(0, 0); stageB(0, 0);

  for (int i = 0; i < NI; ++i) {
    const int b = 2 * i + 1;
    const int c = (2 * i + 2 < NT) ? 2 * i + 2 : 0;   // tail: harmless re-stage
    PH(0, 0, 1, stageA(b, 1));
    PH(0, 1, 0, stageB(b, 1));
    PH(1, 0, 1, stageA(c, 0));
    PH(1, 1, 0, stageB(c, 0));
  }
  asm volatile("s_waitcnt vmcnt(0)" ::: "memory");

#undef PH

  // epilogue: C/D layout col=lane&15, row=(lane>>4)*4+reg
  const int crow0 = bm * 128 + wm + (lane >> 4) * 4;
  const int ccol0 = bn * 128 + wn + lr;
#pragma unroll
  for (int n = 0; n < 4; n++) {
    const int col = ccol0 + n * 16;
    const float bv = bias[col];
#pragma unroll
    for (int m = 0; m < 4; m++) {
#pragma unroll
      for (int r = 0; r < 4; r++) {
        float v = acc[m][n][r] + bv;
        const long row = crow0 + m * 16 + r;
        if (EPI == 0) {
          v = (v >= 0.f) ? v : 0.01f * v;
          _Float16 hi, lo; split_f16(v, hi, lo);
          _Float16* C = (_Float16*)Cout;
          C[row * (long)(2 * N) + col]     = hi;
          C[row * (long)(2 * N) + N + col] = lo;
        } else {
          ((float*)Cout)[row * (long)N + col] = v;
        }
      }
    }
  }
}

// ---------------- fused quat->rotmat + forward kinematics ----------------
struct FkParams { int par[JN]; unsigned long long childmask; };

__global__ __launch_bounds__(256)
void quat_fk_kernel(const float* __restrict__ q, const float* __restrict__ offs,
                    float* __restrict__ rot, float* __restrict__ Gt,
                    float* __restrict__ pose, FkParams P)
{
  __shared__ float qs[256][65];                 // 66,560 B
  const int tid = threadIdx.x;
  const int s0  = blockIdx.x * 256;
  const int s   = s0 + tid;

  float G[12];

  for (int c = 0; c < 4; ++c) {
    __syncthreads();                            // prev chunk fully consumed
    for (int idx = tid; idx < 256 * 64; idx += 256) {
      const int r = idx >> 6, col = idx & 63;
      qs[r][col] = q[(long)(s0 + r) * QSTR + c * 64 + col];
    }
    __syncthreads();
    const int jlo = c * 16;
    const int jhi = (c == 3) ? JN : jlo + 16;
    for (int j = jlo; j < jhi; ++j) {
      const int cb = j * 4 - c * 64;
      float qw = qs[tid][cb + 0], qx = qs[tid][cb + 1];
      float qy = qs[tid][cb + 2], qz = qs[tid][cb + 3];
      float n = sqrtf(qw * qw + qx * qx + qy * qy + qz * qz);
      n = fmaxf(n, 1e-8f);
      const float inv = 1.f / n;
      qw *= inv; qx *= inv; qy *= inv; qz *= inv;
      const float xx = qx * qx, yy = qy * qy, zz = qz * qz;
      const float xy = qx * qy, xz = qx * qz, yz = qy * qz;
      const float xw = qx * qw, yw = qy * qw, zw = qz * qw;
      float L[12];
      L[0] = 1.f - 2.f * (yy + zz); L[1] = 2.f * (xy - zw); L[2]  = 2.f * (xz + yw);
      L[4] = 2.f * (xy + zw); L[5] = 1.f - 2.f * (xx + zz); L[6]  = 2.f * (yz - xw);
      L[8] = 2.f * (xz - yw); L[9] = 2.f * (yz + xw); L[10] = 1.f - 2.f * (xx + yy);

      float4* ro = (float4*)(rot + ((long)s * JN + j) * 16);
      ro[0] = make_float4(L[0], L[1], L[2],  0.f);
      ro[1] = make_float4(L[4], L[5], L[6],  0.f);
      ro[2] = make_float4(L[8], L[9], L[10], 0.f);
      ro[3] = make_float4(0.f, 0.f, 0.f, 1.f);

      L[3]  = offs[j * 3 + 0];
      L[7]  = offs[j * 3 + 1];
      L[11] = offs[j * 3 + 2];

      if (j == 0) {
#pragma unroll
        for (int e = 0; e < 12; e++) G[e] = L[e];
      } else {
        const int p = P.par[j];                 // scalar -> uniform branch
        float Pm[12];
        if (p == j - 1) {
#pragma unroll
          for (int e = 0; e < 12; e++) Pm[e] = G[e];
        } else {
#pragma unroll
          for (int e = 0; e < 12; e++) Pm[e] = Gt[((long)p * 12 + e) * B_ + s];
        }
#pragma unroll
        for (int r = 0; r < 3; r++) {
#pragma unroll
          for (int cc = 0; cc < 4; cc++) {
            float v = Pm[r * 4 + 0] * L[0 * 4 + cc] + Pm[r * 4 + 1] * L[1 * 4 + cc]
                    + Pm[r * 4 + 2] * L[2 * 4 + cc];
            if (cc == 3) v += Pm[r * 4 + 3];
            G[r * 4 + cc] = v;
          }
        }
      }
      if ((P.childmask >> j) & 1ull) {
#pragma unroll
        for (int e = 0; e < 12; e++) Gt[((long)j * 12 + e) * B_ + s] = G[e];
      }
      pose[(long)s * (JN * 3) + j * 3 + 0] = G[3];
      pose[(long)s * (JN * 3) + j * 3 + 1] = G[7];
      pose[(long)s * (JN * 3) + j * 3 + 2] = G[11];
    }
  }
}

// ---------------- host: replicate np.random.default_rng(7) parents ----------------
static void compute_parents(int* par, unsigned long long* childmask)
{
  uint32_t pool[4];
  uint32_t hc = 0x43b0d7e5u;                       // INIT_A
  auto hashmix = [&hc](uint32_t v) {
    v ^= hc; hc *= 0x931e8875u; v *= hc; v ^= v >> 16; return v;
  };
  auto mix = [](uint32_t x, uint32_t y) {
    uint32_t r = 0xca01f9ddu * x - 0x4973f715u * y;
    r ^= r >> 16;
    return r;
  };
  const uint32_t entropy[1] = {7u};
  for (int i = 0; i < 4; i++) pool[i] = hashmix(i < 1 ? entropy[i] : 0u);
  for (int si = 0; si < 4; si++)
    for (int di = 0; di < 4; di++)
      if (si != di) pool[di] = mix(pool[di], hashmix(pool[si]));
  uint32_t gs[8];
  uint32_t hb = 0x8b51f9ddu;                       // INIT_B
  for (int i = 0; i < 8; i++) {
    uint32_t dv = pool[i & 3];
    dv ^= hb; hb *= 0x58f38dedu; dv *= hb; dv ^= dv >> 16;
    gs[i] = dv;
  }
  uint64_t sw0 = (uint64_t)gs[0] | ((uint64_t)gs[1] << 32);
  uint64_t sw1 = (uint64_t)gs[2] | ((uint64_t)gs[3] << 32);
  uint64_t iw0 = (uint64_t)gs[4] | ((uint64_t)gs[5] << 32);
  uint64_t iw1 = (uint64_t)gs[6] | ((uint64_t)gs[7] << 32);
  const __uint128_t MULT = (((__uint128_t)0x2360ed051fc65da4ULL) << 64) | 0x4385df649fccf645ULL;
  __uint128_t inc = ((((__uint128_t)iw0 << 64) | iw1) << 1) | 1;
  __uint128_t state = 0;
  state = state * MULT + inc;
  state += (((__uint128_t)sw0) << 64) | sw1;
  state = state * MULT + inc;
  bool has32 = false; uint32_t buf32 = 0;
  auto next64 = [&]() {
    state = state * MULT + inc;
    uint64_t hi = (uint64_t)(state >> 64), lo = (uint64_t)state;
    uint32_t rot = (uint32_t)(state >> 122);
    uint64_t x = hi ^ lo;
    return (x >> rot) | (x << ((64u - rot) & 63u));
  };
  auto next32 = [&]() -> uint32_t {
    if (has32) { has32 = false; return buf32; }
    uint64_t v = next64();
    has32 = true; buf32 = (uint32_t)(v >> 32);
    return (uint32_t)v;
  };
  par[0] = -1;
  for (int j = 1; j < JN; j++) {
    uint32_t rng = (uint32_t)(j - 1);
    if (rng == 0) { par[j] = 0; continue; }
    uint32_t rng_excl = rng + 1;
    uint64_t m = (uint64_t)next32() * (uint64_t)rng_excl;
    uint32_t leftover = (uint32_t)m;
    if (leftover < rng_excl) {
      uint32_t threshold = (uint32_t)((0x100000000ULL - rng_excl) % rng_excl);
      while (leftover < threshold) {
        m = (uint64_t)next32() * (uint64_t)rng_excl;
        leftover = (uint32_t)m;
      }
    }
    par[j] = (int)(m >> 32);
  }
  unsigned long long cm = 0;
  for (int j = 1; j < JN; j++) cm |= 1ull << par[j];
  *childmask = cm;
}

// ---------------- launch ----------------
extern "C" void kernel_launch(void* const* d_in, const int* in_sizes, int n_in,
                              void* d_out, int out_size, void* d_ws, size_t ws_size,
                              hipStream_t stream)
{
  const float* in_seq = (const float*)d_in[0];
  const float* w1 = (const float*)d_in[1];
  const float* b1 = (const float*)d_in[2];
  const float* w2 = (const float*)d_in[3];
  const float* b2 = (const float*)d_in[4];
  const float* w3 = (const float*)d_in[5];
  const float* b3 = (const float*)d_in[6];
  const float* w4 = (const float*)d_in[7];
  const float* b4 = (const float*)d_in[8];
  const float* offs = (const float*)d_in[9];

  char* pR1 = (char*)d_ws;
  char* pR2 = pR1 + 35390464;
  char* pR3 = pR2 + 134217728;
  _Float16* x2  = (_Float16*)pR1;
  _Float16* w1f = (_Float16*)(pR1 + 25165824);
  _Float16* w2f = (_Float16*)(pR1 + 25165824 + 786432);
  _Float16* w3f = (_Float16*)(pR1 + 25165824 + 786432 + 4194304);
  _Float16* w4f = (_Float16*)(pR1 + 25165824 + 786432 + 2 * 4194304);
  float*    b4p = (float*)(pR1 + 25165824 + 786432 + 2 * 4194304 + 1048576);
  float*    q   = (float*)pR1;            // overwrites x2/w1f/w2f/w3f only
  _Float16* h1  = (_Float16*)pR2;
  _Float16* h3  = (_Float16*)pR2;
  float*    Gt  = (float*)pR2;            // h1/h3 dead after L4
  _Float16* h2  = (_Float16*)pR3;

  float* pose = (float*)d_out;                        // [B_,57,3]
  float* rot  = (float*)d_out + (long)B_ * JN * 3;    // [B_,57,4,4]

  // prep
  prep_x2_kernel<<<(B_ * 192) / 256, 256, 0, stream>>>(in_seq, x2);
  prep_w2_kernel<<<(1024 * 192) / 256, 256, 0, stream>>>(w1, w1f, 171, 192, 1024);
  prep_w2_kernel<<<(1024 * 1024) / 256, 256, 0, stream>>>(w2, w2f, 1024, 1024, 1024);
  prep_w2_kernel<<<(1024 * 1024) / 256, 256, 0, stream>>>(w3, w3f, 1024, 1024, 1024);
  prep_w2_kernel<<<(256 * 1024) / 256, 256, 0, stream>>>(w4, w4f, 1024, 1024, 228);
  prep_b4_kernel<<<1, 256, 0, stream>>>(b4, b4p);

  // MLP: L1 3-plane (skip dead lo-out), L2 2-plane (skip dead lo-out),
  // L3 2-plane (skip dead lo-out — L4 now 2-plane), L4 2-plane.
  gemm_hl<0, 0><<<(B_ / 128) * (1024 / 128), 256, 0, stream>>>(x2, w1f, b1, h1, B_, 1024, 192);
  gemm256<0, 2, 0><<<(B_ / 256) * (1024 / 256), 512, 0, stream>>>(h1, w2f, b2, h2, B_, 1024, 1024);
  gemm256<0, 2, 0><<<(B_ / 256) * (1024 / 256), 512, 0, stream>>>(h2, w3f, b3, h3, B_, 1024, 1024);
  gemm128p<1, 2><<<(B_ / 128) * (QSTR / 128), 256, 0, stream>>>(h3, w4f, b4p, q, B_, QSTR, 1024);

  // fused epilogue (quat->rot + FK), no Lf round-trip
  FkParams P;
  compute_parents(P.par, &P.childmask);
  quat_fk_kernel<<<B_ / 256, 256, 0, stream>>>(q, offs, rot, Gt, pose, P);
}

// Round 21
// 504.095 us; speedup vs baseline: 1.6497x; 1.0018x over previous
//
#include <hip/hip_runtime.h>
#include <hip/hip_bf16.h>
#include <stdint.h>

#define B_   32768
#define JN   57
#define QSTR 256      // q row stride (228 padded to 256)

typedef _Float16 f16x8 __attribute__((ext_vector_type(8)));
typedef float    f32x4 __attribute__((ext_vector_type(4)));

__device__ __forceinline__ void split_f16(float v, _Float16& hi, _Float16& lo) {
  hi = (_Float16)v;
  lo = (_Float16)(v - (float)hi);
}

// ---------------- prep kernels ----------------
__global__ void prep_x2_kernel(const float* __restrict__ x, _Float16* __restrict__ xp) {
  long i = (long)blockIdx.x * 256 + threadIdx.x;   // over B_*192
  int row = (int)(i / 192), col = (int)(i % 192);
  float v = (col < 171) ? x[(long)row * 171 + col] : 0.f;
  _Float16 hi, lo; split_f16(v, hi, lo);
  xp[(long)row * 384 + col]       = hi;
  xp[(long)row * 384 + 192 + col] = lo;
}

__global__ void prep_w2_kernel(const float* __restrict__ w, _Float16* __restrict__ wf,
                               int Ksrc, int Kpad, int Nsrc) {
  long i = (long)blockIdx.x * 256 + threadIdx.x;   // over Ndst*Kpad
  int n = (int)(i / Kpad), k = (int)(i % Kpad);
  float v = (k < Ksrc && n < Nsrc) ? w[(long)k * Nsrc + n] : 0.f;
  _Float16 hi, lo; split_f16(v, hi, lo);
  wf[(long)n * (2 * Kpad) + k]        = hi;
  wf[(long)n * (2 * Kpad) + Kpad + k] = lo;
}

__global__ void prep_b4_kernel(const float* __restrict__ b, float* __restrict__ bp) {
  int i = threadIdx.x;  // 256 threads
  bp[i] = (i < 228) ? b[i] : 0.f;
}

// ---------------- 128² split-f16 GEMM (m97 structure) — layer 1 only ----------------
// WLO=0: lo-output plane dead (consumer reads A-hi only) -> skip those stores.
template<int EPI, int WLO>
__global__ __launch_bounds__(256)
void gemm_hl(const _Float16* __restrict__ A, const _Float16* __restrict__ Bt,
             const float* __restrict__ bias, void* __restrict__ Cout,
             int M, int N, int Kp)
{
  __shared__ __align__(16) _Float16 As[128 * 64];
  __shared__ __align__(16) _Float16 Bs[128 * 64];
  const int lda = 2 * Kp;
  const int T = Kp >> 6;
  const int tiles_n = N >> 7;
  const int cpx  = gridDim.x >> 3;
  const int virt = (blockIdx.x & 7) * cpx + (blockIdx.x >> 3);
  const int bm = virt / tiles_n;
  const int bn = virt % tiles_n;
  const int tid  = threadIdx.x;
  const int wave = tid >> 6;
  const int lane = tid & 63;

  const int srow = wave * 8 + (lane >> 3);
  const int scol = (((lane & 7) ^ (lane >> 3)) * 8);
  const long abase = (long)bm * 128;
  const long bbase = (long)bn * 128;

  f32x4 acc[4][4] = {};

  const int wm = (wave >> 1) * 64;
  const int wn = (wave & 1) * 64;
  const int lr = lane & 15;
  const int ch0 = (((lane >> 4) ^ (lane & 7)) * 8);
  const int ch1 = (((4 + (lane >> 4)) ^ (lane & 7)) * 8);

  for (int ph = 0; ph < 3; ++ph) {
    const int aoff = (ph == 2) ? Kp : 0;
    const int boff = (ph == 1) ? Kp : 0;
    for (int u = 0; u < T; ++u) {
#pragma unroll
      for (int i = 0; i < 4; i++) {
        const _Float16* asrc = A  + (abase + i * 32 + srow) * (long)lda + (aoff + u * 64 + scol);
        const _Float16* bsrc = Bt + (bbase + i * 32 + srow) * (long)lda + (boff + u * 64 + scol);
        __builtin_amdgcn_global_load_lds(
            (const __attribute__((address_space(1))) void*)asrc,
            (__attribute__((address_space(3))) void*)(As + (i * 256 + wave * 64) * 8),
            16, 0, 0);
        __builtin_amdgcn_global_load_lds(
            (const __attribute__((address_space(1))) void*)bsrc,
            (__attribute__((address_space(3))) void*)(Bs + (i * 256 + wave * 64) * 8),
            16, 0, 0);
      }
      __syncthreads();

#pragma unroll
      for (int ks = 0; ks < 2; ks++) {
        const int ch = ks ? ch1 : ch0;
        f16x8 af[4], bfr[4];
#pragma unroll
        for (int m = 0; m < 4; m++)
          af[m] = *(const f16x8*)(As + (wm + m * 16 + lr) * 64 + ch);
#pragma unroll
        for (int n = 0; n < 4; n++)
          bfr[n] = *(const f16x8*)(Bs + (wn + n * 16 + lr) * 64 + ch);
#pragma unroll
        for (int m = 0; m < 4; m++)
#pragma unroll
          for (int n = 0; n < 4; n++)
            acc[m][n] = __builtin_amdgcn_mfma_f32_16x16x32_f16(af[m], bfr[n], acc[m][n], 0, 0, 0);
      }
      __syncthreads();
    }
  }

  const int crow0 = bm * 128 + wm + (lane >> 4) * 4;
  const int ccol0 = bn * 128 + wn + lr;
#pragma unroll
  for (int n = 0; n < 4; n++) {
    const int col = ccol0 + n * 16;
    const float bv = bias[col];
#pragma unroll
    for (int m = 0; m < 4; m++) {
#pragma unroll
      for (int r = 0; r < 4; r++) {
        float v = acc[m][n][r] + bv;
        const long row = crow0 + m * 16 + r;
        if (EPI == 0) {
          v = (v >= 0.f) ? v : 0.01f * v;
          _Float16 hi, lo; split_f16(v, hi, lo);
          _Float16* C = (_Float16*)Cout;
          C[row * (long)(2 * N) + col] = hi;
          if (WLO) C[row * (long)(2 * N) + N + col] = lo;
        } else {
          ((float*)Cout)[row * (long)N + col] = v;
        }
      }
    }
  }
}

// ---------------- 256² 4-phase split-f16 GEMM — B-dedup schedule (best measured) ----------------
// 512 thr = 8 waves (2M x 4N), per-wave 128x64 out. BK=64, 2 LDS slots (128KB).
// acc[8][4] f32x4 = 128 AGPRs/lane -> REQUIRES the 256-reg budget of
// __launch_bounds__(512,2); min-waves=4 spills the accumulator (R11). Do not raise.
// PLANES=2 drops AlBh -> activations effectively f16, weights split-exact.
// WLO=0 skips dead lo-output stores.
template<int EPI, int PLANES, int WLO>
__global__ __launch_bounds__(512, 2)
void gemm256(const _Float16* __restrict__ Ag, const _Float16* __restrict__ Bt,
             const float* __restrict__ bias, void* __restrict__ Cout,
             int M, int N, int Kp)
{
  __shared__ __align__(16) _Float16 As[2][256 * 64];
  __shared__ __align__(16) _Float16 Bs[2][256 * 64];
  const int lda = 2 * Kp;
  const int T  = Kp >> 6;
  const int NT = PLANES * T;
  const int NI = NT >> 1;
  const int tiles_n = N >> 8;
  const int cpx  = gridDim.x >> 3;
  const int virt = (blockIdx.x & 7) * cpx + (blockIdx.x >> 3);
  const int bm = virt / tiles_n;
  const int bn = virt % tiles_n;
  const int tid  = threadIdx.x;
  const int wid  = tid >> 6;
  const int lane = tid & 63;

  const long abase = (long)bm * 256;
  const long bbase = (long)bn * 256;
  const int scol = (((lane & 7) ^ ((tid >> 3) & 7)) * 8);

  const int wm = (wid >> 2) * 128;
  const int wn = (wid & 3) * 64;
  const int lr = lane & 15;

  f32x4 acc[8][4] = {};

  auto stageA = [&](int t, int s, int h) {
    const int ph = t / T, u = t - ph * T;
    const long ko = ((ph == 2) ? (long)Kp : 0) + u * 64 + scol;
    const _Float16* src = Ag + (abase + h * 128 + (tid >> 3)) * (long)lda + ko;
    const _Float16* dst = &As[s][h * 8192 + tid * 8];
    __builtin_amdgcn_global_load_lds(
        (const __attribute__((address_space(1))) void*)src,
        (__attribute__((address_space(3))) void*)dst, 16, 0, 0);
    __builtin_amdgcn_global_load_lds(
        (const __attribute__((address_space(1))) void*)(src + 64 * (long)lda),
        (__attribute__((address_space(3))) void*)(dst + 4096), 16, 0, 0);
  };
  auto stageB = [&](int t, int s, int h) {
    const int ph = t / T, u = t - ph * T;
    const long ko = ((ph == 1) ? (long)Kp : 0) + u * 64 + scol;
    const _Float16* src = Bt + (bbase + h * 128 + (tid >> 3)) * (long)lda + ko;
    const _Float16* dst = &Bs[s][h * 8192 + tid * 8];
    __builtin_amdgcn_global_load_lds(
        (const __attribute__((address_space(1))) void*)src,
        (__attribute__((address_space(3))) void*)dst, 16, 0, 0);
    __builtin_amdgcn_global_load_lds(
        (const __attribute__((address_space(1))) void*)(src + 64 * (long)lda),
        (__attribute__((address_space(3))) void*)(dst + 4096), 16, 0, 0);
  };

  // phase: stage -> [vmcnt(4)] -> barrier -> 12 ds_reads -> 32 MFMA
#define PH(slot, ks, WAITV, ...)                                                  \
  do {                                                                            \
    __VA_ARGS__;                                                                  \
    if (WAITV) asm volatile("s_waitcnt vmcnt(4)" ::: "memory");                   \
    __builtin_amdgcn_s_barrier();                                                 \
    const int ch = (((ks) * 4 + (lane >> 4)) ^ (lane & 7)) * 8;                   \
    f16x8 af[8], bfr[4];                                                          \
    _Pragma("unroll")                                                             \
    for (int mi = 0; mi < 8; ++mi)                                                \
      af[mi] = *(const f16x8*)&As[slot][(wm + mi * 16 + lr) * 64 + ch];           \
    _Pragma("unroll")                                                             \
    for (int n = 0; n < 4; ++n)                                                   \
      bfr[n] = *(const f16x8*)&Bs[slot][(wn + n * 16 + lr) * 64 + ch];            \
    __builtin_amdgcn_s_setprio(1);                                                \
    _Pragma("unroll")                                                             \
    for (int mi = 0; mi < 8; ++mi)                                                \
      _Pragma("unroll")                                                           \
      for (int n = 0; n < 4; ++n)                                                 \
        acc[mi][n] = __builtin_amdgcn_mfma_f32_16x16x32_f16(                      \
            af[mi], bfr[n], acc[mi][n], 0, 0, 0);                                 \
    __builtin_amdgcn_s_setprio(0);                                                \
  } while (0)

  // prologue: full tile 0 -> S0 (8 loads/thread outstanding)
  stageA(0, 0, 0); stageA(0, 0, 1); stageB(0, 0, 0); stageB(0, 0, 1);

  for (int i = 0; i < NI; ++i) {
    const int b = 2 * i + 1;
    const int c = (2 * i + 2 < NT) ? 2 * i + 2 : 0;   // tail: harmless re-stage
    PH(0, 0, 1, stageA(b, 1, 0); stageA(b, 1, 1));
    PH(0, 1, 0, stageB(b, 1, 0); stageB(b, 1, 1));
    PH(1, 0, 1, stageA(c, 0, 0); stageA(c, 0, 1));
    PH(1, 1, 0, stageB(c, 0, 0); stageB(c, 0, 1));
  }
  asm volatile("s_waitcnt vmcnt(0)" ::: "memory");

#undef PH

  // epilogue: C/D layout col=lane&15, row=(lane>>4)*4+reg
  const int crow0 = bm * 256 + wm + (lane >> 4) * 4;
  const int ccol0 = bn * 256 + wn + lr;
#pragma unroll
  for (int n = 0; n < 4; n++) {
    const int col = ccol0 + n * 16;
    const float bv = bias[col];
#pragma unroll
    for (int m = 0; m < 8; m++) {
#pragma unroll
      for (int r = 0; r < 4; r++) {
        float v = acc[m][n][r] + bv;
        const long row = crow0 + m * 16 + r;
        if (EPI == 0) {
          v = (v >= 0.f) ? v : 0.01f * v;
          _Float16 hi, lo; split_f16(v, hi, lo);
          _Float16* C = (_Float16*)Cout;
          C[row * (long)(2 * N) + col] = hi;
          if (WLO) C[row * (long)(2 * N) + N + col] = lo;
        } else {
          ((float*)Cout)[row * (long)N + col] = v;
        }
      }
    }
  }
}

// ---------------- 128² 4-phase split-f16 GEMM — R9 discipline, 2 blocks/CU ----------------
// (R14-verified.) Used for L4 (N=256): 512 blocks = 1 co-resident round.
// PLANES=2: reads h3-hi only (weights stay split) — third precision source;
// measured total absmax 0.0244 < 0.0264 threshold.
template<int EPI, int PLANES>
__global__ __launch_bounds__(256, 2)
void gemm128p(const _Float16* __restrict__ Ag, const _Float16* __restrict__ Bt,
              const float* __restrict__ bias, void* __restrict__ Cout,
              int M, int N, int Kp)
{
  __shared__ __align__(16) _Float16 As[2][128 * 64];
  __shared__ __align__(16) _Float16 Bs[2][128 * 64];
  const int lda = 2 * Kp;
  const int T  = Kp >> 6;
  const int NT = PLANES * T;
  const int NI = NT >> 1;
  const int tiles_n = N >> 7;
  const int cpx  = gridDim.x >> 3;
  const int virt = (blockIdx.x & 7) * cpx + (blockIdx.x >> 3);
  const int bm = virt / tiles_n;
  const int bn = virt % tiles_n;
  const int tid  = threadIdx.x;
  const int wave = tid >> 6;
  const int lane = tid & 63;

  const long abase = (long)bm * 128;
  const long bbase = (long)bn * 128;
  const int wm = (wave >> 1) * 64;
  const int wn = (wave & 1) * 64;
  const int lr = lane & 15;

  f32x4 acc[4][4] = {};

  auto stageA = [&](int t, int s) {
    const int ph = t / T, u = t - ph * T;
    const long ko = ((ph == 2) ? (long)Kp : 0) + u * 64;
#pragma unroll
    for (int L = 0; L < 4; ++L) {
      const int idx = tid + L * 256;
      const int row = idx >> 3, ck = idx & 7;
      const _Float16* src = Ag + (abase + row) * (long)lda + ko + (ck ^ (row & 7)) * 8;
      __builtin_amdgcn_global_load_lds(
          (const __attribute__((address_space(1))) void*)src,
          (__attribute__((address_space(3))) void*)&As[s][idx * 8], 16, 0, 0);
    }
  };
  auto stageB = [&](int t, int s) {
    const int ph = t / T, u = t - ph * T;
    const long ko = ((ph == 1) ? (long)Kp : 0) + u * 64;
#pragma unroll
    for (int L = 0; L < 4; ++L) {
      const int idx = tid + L * 256;
      const int row = idx >> 3, ck = idx & 7;
      const _Float16* src = Bt + (bbase + row) * (long)lda + ko + (ck ^ (row & 7)) * 8;
      __builtin_amdgcn_global_load_lds(
          (const __attribute__((address_space(1))) void*)src,
          (__attribute__((address_space(3))) void*)&Bs[s][idx * 8], 16, 0, 0);
    }
  };

  // phase: stage(4) -> [vmcnt(4)] -> barrier -> 8 ds_reads -> 16 MFMA
#define PH(slot, ks, WAITV, ...)                                                  \
  do {                                                                            \
    __VA_ARGS__;                                                                  \
    if (WAITV) asm volatile("s_waitcnt vmcnt(4)" ::: "memory");                   \
    __builtin_amdgcn_s_barrier();                                                 \
    const int ch = (((ks) * 4 + (lane >> 4)) ^ (lane & 7)) * 8;                   \
    f16x8 af[4], bfr[4];                                                          \
    _Pragma("unroll")                                                             \
    for (int mi = 0; mi < 4; ++mi)                                                \
      af[mi] = *(const f16x8*)&As[slot][(wm + mi * 16 + lr) * 64 + ch];           \
    _Pragma("unroll")                                                             \
    for (int n = 0; n < 4; ++n)                                                   \
      bfr[n] = *(const f16x8*)&Bs[slot][(wn + n * 16 + lr) * 64 + ch];            \
    __builtin_amdgcn_s_setprio(1);                                                \
    _Pragma("unroll")                                                             \
    for (int mi = 0; mi < 4; ++mi)                                                \
      _Pragma("unroll")                                                           \
      for (int n = 0; n < 4; ++n)                                                 \
        acc[mi][n] = __builtin_amdgcn_mfma_f32_16x16x32_f16(                      \
            af[mi], bfr[n], acc[mi][n], 0, 0, 0);                                 \
    __builtin_amdgcn_s_setprio(0);                                                \
  } while (0)

  // prologue: tile 0 -> S0 (8 loads/thread outstanding)
  stageA(0, 0); stageB(0, 0);

  for (int i = 0; i < NI; ++i) {
    const int b = 2 * i + 1;
    const int c = (2 * i + 2 < NT) ? 2 * i + 2 : 0;   // tail: harmless re-stage
    PH(0, 0, 1, stageA(b, 1));
    PH(0, 1, 0, stageB(b, 1));
    PH(1, 0, 1, stageA(c, 0));
    PH(1, 1, 0, stageB(c, 0));
  }
  asm volatile("s_waitcnt vmcnt(0)" ::: "memory");

#undef PH

  // epilogue: C/D layout col=lane&15, row=(lane>>4)*4+reg
  const int crow0 = bm * 128 + wm + (lane >> 4) * 4;
  const int ccol0 = bn * 128 + wn + lr;
#pragma unroll
  for (int n = 0; n < 4; n++) {
    const int col = ccol0 + n * 16;
    const float bv = bias[col];
#pragma unroll
    for (int m = 0; m < 4; m++) {
#pragma unroll
      for (int r = 0; r < 4; r++) {
        float v = acc[m][n][r] + bv;
        const long row = crow0 + m * 16 + r;
        if (EPI == 0) {
          v = (v >= 0.f) ? v : 0.01f * v;
          _Float16 hi, lo; split_f16(v, hi, lo);
          _Float16* C = (_Float16*)Cout;
          C[row * (long)(2 * N) + col]     = hi;
          C[row * (long)(2 * N) + N + col] = lo;
        } else {
          ((float*)Cout)[row * (long)N + col] = v;
        }
      }
    }
  }
}

// ---------------- fused quat->rotmat + forward kinematics ----------------
struct FkParams { int par[JN]; unsigned long long childmask; };

__global__ __launch_bounds__(256)
void quat_fk_kernel(const float* __restrict__ q, const float* __restrict__ offs,
                    float* __restrict__ rot, float* __restrict__ Gt,
                    float* __restrict__ pose, FkParams P)
{
  __shared__ float qs[256][65];                 // 66,560 B
  const int tid = threadIdx.x;
  const int s0  = blockIdx.x * 256;
  const int s   = s0 + tid;

  float G[12];

  for (int c = 0; c < 4; ++c) {
    __syncthreads();                            // prev chunk fully consumed
    for (int idx = tid; idx < 256 * 64; idx += 256) {
      const int r = idx >> 6, col = idx & 63;
      qs[r][col] = q[(long)(s0 + r) * QSTR + c * 64 + col];
    }
    __syncthreads();
    const int jlo = c * 16;
    const int jhi = (c == 3) ? JN : jlo + 16;
    for (int j = jlo; j < jhi; ++j) {
      const int cb = j * 4 - c * 64;
      float qw = qs[tid][cb + 0], qx = qs[tid][cb + 1];
      float qy = qs[tid][cb + 2], qz = qs[tid][cb + 3];
      float n = sqrtf(qw * qw + qx * qx + qy * qy + qz * qz);
      n = fmaxf(n, 1e-8f);
      const float inv = 1.f / n;
      qw *= inv; qx *= inv; qy *= inv; qz *= inv;
      const float xx = qx * qx, yy = qy * qy, zz = qz * qz;
      const float xy = qx * qy, xz = qx * qz, yz = qy * qz;
      const float xw = qx * qw, yw = qy * qw, zw = qz * qw;
      float L[12];
      L[0] = 1.f - 2.f * (yy + zz); L[1] = 2.f * (xy - zw); L[2]  = 2.f * (xz + yw);
      L[4] = 2.f * (xy + zw); L[5] = 1.f - 2.f * (xx + zz); L[6]  = 2.f * (yz - xw);
      L[8] = 2.f * (xz - yw); L[9] = 2.f * (yz + xw); L[10] = 1.f - 2.f * (xx + yy);

      float4* ro = (float4*)(rot + ((long)s * JN + j) * 16);
      ro[0] = make_float4(L[0], L[1], L[2],  0.f);
      ro[1] = make_float4(L[4], L[5], L[6],  0.f);
      ro[2] = make_float4(L[8], L[9], L[10], 0.f);
      ro[3] = make_float4(0.f, 0.f, 0.f, 1.f);

      L[3]  = offs[j * 3 + 0];
      L[7]  = offs[j * 3 + 1];
      L[11] = offs[j * 3 + 2];

      if (j == 0) {
#pragma unroll
        for (int e = 0; e < 12; e++) G[e] = L[e];
      } else {
        const int p = P.par[j];                 // scalar -> uniform branch
        float Pm[12];
        if (p == j - 1) {
#pragma unroll
          for (int e = 0; e < 12; e++) Pm[e] = G[e];
        } else {
#pragma unroll
          for (int e = 0; e < 12; e++) Pm[e] = Gt[((long)p * 12 + e) * B_ + s];
        }
#pragma unroll
        for (int r = 0; r < 3; r++) {
#pragma unroll
          for (int cc = 0; cc < 4; cc++) {
            float v = Pm[r * 4 + 0] * L[0 * 4 + cc] + Pm[r * 4 + 1] * L[1 * 4 + cc]
                    + Pm[r * 4 + 2] * L[2 * 4 + cc];
            if (cc == 3) v += Pm[r * 4 + 3];
            G[r * 4 + cc] = v;
          }
        }
      }
      if ((P.childmask >> j) & 1ull) {
#pragma unroll
        for (int e = 0; e < 12; e++) Gt[((long)j * 12 + e) * B_ + s] = G[e];
      }
      pose[(long)s * (JN * 3) + j * 3 + 0] = G[3];
      pose[(long)s * (JN * 3) + j * 3 + 1] = G[7];
      pose[(long)s * (JN * 3) + j * 3 + 2] = G[11];
    }
  }
}

// ---------------- host: replicate np.random.default_rng(7) parents ----------------
static void compute_parents(int* par, unsigned long long* childmask)
{
  uint32_t pool[4];
  uint32_t hc = 0x43b0d7e5u;                       // INIT_A
  auto hashmix = [&hc](uint32_t v) {
    v ^= hc; hc *= 0x931e8875u; v *= hc; v ^= v >> 16; return v;
  };
  auto mix = [](uint32_t x, uint32_t y) {
    uint32_t r = 0xca01f9ddu * x - 0x4973f715u * y;
    r ^= r >> 16;
    return r;
  };
  const uint32_t entropy[1] = {7u};
  for (int i = 0; i < 4; i++) pool[i] = hashmix(i < 1 ? entropy[i] : 0u);
  for (int si = 0; si < 4; si++)
    for (int di = 0; di < 4; di++)
      if (si != di) pool[di] = mix(pool[di], hashmix(pool[si]));
  uint32_t gs[8];
  uint32_t hb = 0x8b51f9ddu;                       // INIT_B
  for (int i = 0; i < 8; i++) {
    uint32_t dv = pool[i & 3];
    dv ^= hb; hb *= 0x58f38dedu; dv *= hb; dv ^= dv >> 16;
    gs[i] = dv;
  }
  uint64_t sw0 = (uint64_t)gs[0] | ((uint64_t)gs[1] << 32);
  uint64_t sw1 = (uint64_t)gs[2] | ((uint64_t)gs[3] << 32);
  uint64_t iw0 = (uint64_t)gs[4] | ((uint64_t)gs[5] << 32);
  uint64_t iw1 = (uint64_t)gs[6] | ((uint64_t)gs[7] << 32);
  const __uint128_t MULT = (((__uint128_t)0x2360ed051fc65da4ULL) << 64) | 0x4385df649fccf645ULL;
  __uint128_t inc = ((((__uint128_t)iw0 << 64) | iw1) << 1) | 1;
  __uint128_t state = 0;
  state = state * MULT + inc;
  state += (((__uint128_t)sw0) << 64) | sw1;
  state = state * MULT + inc;
  bool has32 = false; uint32_t buf32 = 0;
  auto next64 = [&]() {
    state = state * MULT + inc;
    uint64_t hi = (uint64_t)(state >> 64), lo = (uint64_t)state;
    uint32_t rot = (uint32_t)(state >> 122);
    uint64_t x = hi ^ lo;
    return (x >> rot) | (x << ((64u - rot) & 63u));
  };
  auto next32 = [&]() -> uint32_t {
    if (has32) { has32 = false; return buf32; }
    uint64_t v = next64();
    has32 = true; buf32 = (uint32_t)(v >> 32);
    return (uint32_t)v;
  };
  par[0] = -1;
  for (int j = 1; j < JN; j++) {
    uint32_t rng = (uint32_t)(j - 1);
    if (rng == 0) { par[j] = 0; continue; }
    uint32_t rng_excl = rng + 1;
    uint64_t m = (uint64_t)next32() * (uint64_t)rng_excl;
    uint32_t leftover = (uint32_t)m;
    if (leftover < rng_excl) {
      uint32_t threshold = (uint32_t)((0x100000000ULL - rng_excl) % rng_excl);
      while (leftover < threshold) {
        m = (uint64_t)next32() * (uint64_t)rng_excl;
        leftover = (uint32_t)m;
      }
    }
    par[j] = (int)(m >> 32);
  }
  unsigned long long cm = 0;
  for (int j = 1; j < JN; j++) cm |= 1ull << par[j];
  *childmask = cm;
}

// ---------------- launch ----------------
extern "C" void kernel_launch(void* const* d_in, const int* in_sizes, int n_in,
                              void* d_out, int out_size, void* d_ws, size_t ws_size,
                              hipStream_t stream)
{
  const float* in_seq = (const float*)d_in[0];
  const float* w1 = (const float*)d_in[1];
  const float* b1 = (const float*)d_in[2];
  const float* w2 = (const float*)d_in[3];
  const float* b2 = (const float*)d_in[4];
  const float* w3 = (const float*)d_in[5];
  const float* b3 = (const float*)d_in[6];
  const float* w4 = (const float*)d_in[7];
  const float* b4 = (const float*)d_in[8];
  const float* offs = (const float*)d_in[9];

  char* pR1 = (char*)d_ws;
  char* pR2 = pR1 + 35390464;
  char* pR3 = pR2 + 134217728;
  _Float16* x2  = (_Float16*)pR1;
  _Float16* w1f = (_Float16*)(pR1 + 25165824);
  _Float16* w2f = (_Float16*)(pR1 + 25165824 + 786432);
  _Float16* w3f = (_Float16*)(pR1 + 25165824 + 786432 + 4194304);
  _Float16* w4f = (_Float16*)(pR1 + 25165824 + 786432 + 2 * 4194304);
  float*    b4p = (float*)(pR1 + 25165824 + 786432 + 2 * 4194304 + 1048576);
  float*    q   = (float*)pR1;            // overwrites x2/w1f/w2f/w3f only
  _Float16* h1  = (_Float16*)pR2;
  _Float16* h3  = (_Float16*)pR2;
  float*    Gt  = (float*)pR2;            // h1/h3 dead after L4
  _Float16* h2  = (_Float16*)pR3;

  float* pose = (float*)d_out;                        // [B_,57,3]
  float* rot  = (float*)d_out + (long)B_ * JN * 3;    // [B_,57,4,4]

  // prep
  prep_x2_kernel<<<(B_ * 192) / 256, 256, 0, stream>>>(in_seq, x2);
  prep_w2_kernel<<<(1024 * 192) / 256, 256, 0, stream>>>(w1, w1f, 171, 192, 1024);
  prep_w2_kernel<<<(1024 * 1024) / 256, 256, 0, stream>>>(w2, w2f, 1024, 1024, 1024);
  prep_w2_kernel<<<(1024 * 1024) / 256, 256, 0, stream>>>(w3, w3f, 1024, 1024, 1024);
  prep_w2_kernel<<<(256 * 1024) / 256, 256, 0, stream>>>(w4, w4f, 1024, 1024, 228);
  prep_b4_kernel<<<1, 256, 0, stream>>>(b4, b4p);

  // MLP: L1 3-plane (skip dead lo-out), L2 2-plane (skip dead lo-out),
  // L3 2-plane (skip dead lo-out — L4 is 2-plane), L4 2-plane.
  gemm_hl<0, 0><<<(B_ / 128) * (1024 / 128), 256, 0, stream>>>(x2, w1f, b1, h1, B_, 1024, 192);
  gemm256<0, 2, 0><<<(B_ / 256) * (1024 / 256), 512, 0, stream>>>(h1, w2f, b2, h2, B_, 1024, 1024);
  gemm256<0, 2, 0><<<(B_ / 256) * (1024 / 256), 512, 0, stream>>>(h2, w3f, b3, h3, B_, 1024, 1024);
  gemm128p<1, 2><<<(B_ / 128) * (QSTR / 128), 256, 0, stream>>>(h3, w4f, b4p, q, B_, QSTR, 1024);

  // fused epilogue (quat->rot + FK), no Lf round-trip
  FkParams P;
  compute_parents(P.par, &P.childmask);
  quat_fk_kernel<<<B_ / 256, 256, 0, stream>>>(q, offs, rot, Gt, pose, P);
}